// Round 5
// baseline (806.558 us; speedup 1.0000x reference)
//
#include <hip/hip_runtime.h>
#include <cmath>

// Problem constants
static constexpr int kB   = 16;
static constexpr int kC   = 64;
static constexpr int kH   = 160;
static constexpr int kW   = 192;
static constexpr int kN   = 1000;
static constexpr int kAFC = 16;
static constexpr int kS   = 96;
static constexpr int kNC  = 2;
static constexpr int kD   = kAFC * kH;     // 2560
static constexpr int kHW  = kH * kW;       // 30720
static constexpr int kNM1 = kN - 1;        // 999
static constexpr int kM   = kB * kN;       // 16000
static constexpr int kRP  = kNC + 3 + 3 * kS; // 293
static constexpr int kK2  = 2 * kD;        // 5120
static constexpr int kNP  = 1024;          // padded N for att GEMM
static constexpr int kKS  = 4;             // split-K factor for head GEMM

// d_out layout (floats)
static constexpr size_t OFF_RP   = 0;
static constexpr size_t OFF_ATTN = (size_t)kB * kN * kRP;
static constexpr size_t OFF_FEAT = OFF_ATTN + (size_t)kB * kN * kN;

// ws layout (bytes)
static constexpr size_t WB_BAF   = 0;                                    // bf16 [16000][2560]
static constexpr size_t WB_BAFT  = WB_BAF   + (size_t)kM * kD * 2;       // bf16 [16][2560][1024]
static constexpr size_t WB_ATTF  = WB_BAFT  + (size_t)kB * kD * kNP * 2; // bf16 [16000][2560]
static constexpr size_t WB_ATTNW = WB_ATTF  + (size_t)kM * kD * 2;       // bf16 [1024][2560]
static constexpr size_t WB_WHEAD = WB_ATTNW + (size_t)kNP * kD * 2;      // bf16 [384][5120]
static constexpr size_t WB_ATTNB = WB_WHEAD + (size_t)384 * kK2 * 2;     // bf16 [16][1024][1024]
static constexpr size_t WB_SCORE = WB_ATTNB + (size_t)kB * kNP * kNP * 2;// f32  [16000][999]
// PART overlays ATTNB+SCORE (both dead by the time head GEMM runs)
static constexpr size_t WB_PART  = WB_ATTNB;                             // f32 [4][16000][384]
static constexpr size_t WB_FLAG  = WB_PART + (size_t)kKS * kM * 384 * 4; // int

typedef __attribute__((ext_vector_type(8))) short bf16x8;
typedef __attribute__((ext_vector_type(4))) float f32x4;

static __device__ inline short f2bf(float f) {
  union { float f; unsigned u; } x; x.f = f;
  unsigned r = (x.u + 0x7FFFu + ((x.u >> 16) & 1u)) >> 16;
  return (short)r;
}

#define GLOAD_LDS16(gp, lp) __builtin_amdgcn_global_load_lds( \
    (const __attribute__((address_space(1))) void*)(gp),      \
    (__attribute__((address_space(3))) void*)(lp), 16, 0, 0)

// ---------------- mask dtype detection ----------------
__global__ void k_detect(const unsigned char* __restrict__ m, int* __restrict__ flag) {
  __shared__ int c1, c2, c3;
  if (threadIdx.x == 0) { c1 = 0; c2 = 0; c3 = 0; }
  __syncthreads();
  int l1 = 0, l2 = 0, l3 = 0;
  for (int g = threadIdx.x; g < (kN * kH) / 4; g += blockDim.x) {
    l1 += (m[4 * g + 1] != 0);
    l2 += (m[4 * g + 2] != 0);
    l3 += (m[4 * g + 3] != 0);
  }
  atomicAdd(&c1, l1); atomicAdd(&c2, l2); atomicAdd(&c3, l3);
  __syncthreads();
  if (threadIdx.x == 0) {
    int f;
    if (c1 > 0)            f = 1;  // uint8 bools
    else if (c2 | c3)      f = 2;  // float32 bools
    else                   f = 0;  // int32 bools
    *flag = f;
  }
}

// ---------------- 1x1 conv (fp32, feats is an output) ----------------
__global__ __launch_bounds__(256) void k_conv(const float* __restrict__ bf,
                                              const float* __restrict__ cw,
                                              const float* __restrict__ cb,
                                              float* __restrict__ feats) {
  __shared__ float w[kAFC * kC];
  __shared__ float bsh[kAFC];
  for (int i = threadIdx.x; i < kAFC * kC; i += 256) w[i] = cw[i];
  if (threadIdx.x < kAFC) bsh[threadIdx.x] = cb[threadIdx.x];
  __syncthreads();
  int idx = blockIdx.x * 256 + threadIdx.x;
  if (idx >= kB * kHW) return;
  int b = idx / kHW, p = idx % kHW;
  float acc[kAFC];
#pragma unroll
  for (int o = 0; o < kAFC; o++) acc[o] = bsh[o];
  const float* src = bf + (size_t)b * kC * kHW + p;
#pragma unroll 4
  for (int c = 0; c < kC; c++) {
    float v = src[(size_t)c * kHW];
#pragma unroll
    for (int o = 0; o < kAFC; o++) acc[o] += v * w[o * kC + c];
  }
  float* dst = feats + (size_t)b * kAFC * kHW + p;
#pragma unroll
  for (int o = 0; o < kAFC; o++) dst[(size_t)o * kHW] = acc[o];
}

// ---------------- gather rois -> baf (bf16), XCD-batch-affinity ------------
// block i: xcd = i&7, b = (i&7) + 8*((i>>3)&1)  -> each XCD owns 2 batches,
// so its L2 holds those batches' feats slices (2 x 2MB) after first touch.
__global__ __launch_bounds__(256) void k_gather(const float* __restrict__ feats,
                                                const int* __restrict__ cut,
                                                const void* __restrict__ mask,
                                                const int* __restrict__ flag,
                                                short* __restrict__ baf) {
  int i = blockIdx.x;
  int b = (i & 15);                 // low 3 bits = XCD, bit3 = phase
  int inner = i >> 4;               // 0..624
  int r = inner * 256 + threadIdx.x;  // 0..159999 within batch
  int n = r / kH, h = r % kH;
  int f = *flag;
  bool inv;
  if (f == 0)      inv = ((const int*)mask)[r] != 0;
  else if (f == 1) inv = ((const unsigned char*)mask)[r] != 0;
  else             inv = ((const float*)mask)[r] != 0.0f;
  int x = cut[r];
  short* dst = baf + (size_t)(b * kN + n) * kD + h;
  if (inv) {
#pragma unroll
    for (int a = 0; a < kAFC; a++) dst[a * kH] = 0;
  } else {
    const float* sp = feats + (size_t)b * kAFC * kHW + (size_t)h * kW + x;
#pragma unroll
    for (int a = 0; a < kAFC; a++) dst[a * kH] = f2bf(sp[(size_t)a * kHW]);
  }
}

// ---------------- transpose baf -> bafT [b][d][n_pad] (zero-pad n>=1000) ----
__global__ __launch_bounds__(256) void k_transpose(const short* __restrict__ baf,
                                                   short* __restrict__ bafT) {
  __shared__ short t[64][66];
  int b = blockIdx.z, n0 = blockIdx.y * 64, d0 = blockIdx.x * 64;
  int c = threadIdx.x & 63, r4 = threadIdx.x >> 6;  // c: 0..63, r4: 0..3
#pragma unroll
  for (int i = 0; i < 16; i++) {
    int nl = r4 + i * 4;
    int n = n0 + nl;
    short v = (n < kN) ? baf[(size_t)(b * kN + n) * kD + d0 + c] : (short)0;
    t[nl][c] = v;
  }
  __syncthreads();
#pragma unroll
  for (int i = 0; i < 16; i++) {
    int dl = r4 + i * 4;
    bafT[((size_t)b * kD + d0 + dl) * kNP + n0 + c] = t[c][dl];
  }
}

// ---------------- convert attn_w -> bf16 [1024][2560] (pad rows) ------------
__global__ __launch_bounds__(256) void k_cvt_attnw(const float* __restrict__ w,
                                                   short* __restrict__ o) {
  int idx = blockIdx.x * 256 + threadIdx.x;
  if (idx >= kNP * kD) return;
  int j = idx / kD;
  o[idx] = (j < kNM1) ? f2bf(w[idx]) : (short)0;
}

// ---------------- build head weight bf16 [384][5120] ------------------------
__global__ __launch_bounds__(256) void k_cvt_whead(const float* __restrict__ reg_w,
                                                   const float* __restrict__ cls_w,
                                                   short* __restrict__ o) {
  int idx = blockIdx.x * 256 + threadIdx.x;
  if (idx >= 384 * kK2) return;
  int j = idx / kK2, k = idx % kK2;
  float v = 0.f;
  if (j < 3 * kS)            v = reg_w[idx];
  else if (j < 3 * kS + kNC) v = cls_w[(size_t)(j - 3 * kS) * kK2 + k];
  o[idx] = f2bf(v);
}

// ---------------- softmax: scores -> attn_mat (f32 out) + attn bf16 padded --
__global__ __launch_bounds__(256) void k_softmax(const float* __restrict__ scores,
                                                 const float* __restrict__ anchors,
                                                 float* __restrict__ attn_out,
                                                 short* __restrict__ attn_bf,
                                                 float* __restrict__ rp) {
  int m = blockIdx.x;           // 0..15999
  int b = m / kN;
  int i = m % kN;
  const float* srow = scores + (size_t)m * kNM1;
  int tid = threadIdx.x;
  __shared__ float red[4];
  float v[4];
  float mx = -INFINITY;
#pragma unroll
  for (int t = 0; t < 4; t++) {
    int j = tid + t * 256;
    v[t] = (j < kNM1) ? srow[j] : -INFINITY;
    mx = fmaxf(mx, v[t]);
  }
#pragma unroll
  for (int o = 32; o; o >>= 1) mx = fmaxf(mx, __shfl_down(mx, o));
  if ((tid & 63) == 0) red[tid >> 6] = mx;
  __syncthreads();
  mx = fmaxf(fmaxf(red[0], red[1]), fmaxf(red[2], red[3]));
  __syncthreads();
  float s = 0.f;
#pragma unroll
  for (int t = 0; t < 4; t++) {
    int j = tid + t * 256;
    v[t] = (j < kNM1) ? __expf(v[t] - mx) : 0.f;
    s += v[t];
  }
#pragma unroll
  for (int o = 32; o; o >>= 1) s += __shfl_down(s, o);
  if ((tid & 63) == 0) red[tid >> 6] = s;
  __syncthreads();
  s = red[0] + red[1] + red[2] + red[3];
  float inv = 1.0f / s;
  float* orow = attn_out + (size_t)m * kN;
  short* brow = attn_bf + ((size_t)b * kNP + i) * kNP;
#pragma unroll
  for (int t = 0; t < 4; t++) {
    int j = tid + t * 256;
    if (j < kNM1) {
      int dst = j + (j >= i);
      float p = v[t] * inv;
      orow[dst] = p;
      brow[dst] = f2bf(p);
    }
  }
  if (tid == 0) { orow[i] = 0.f; brow[i] = 0; }
  if (tid < kNP - kN) brow[kN + tid] = 0;           // pad cols 1000..1023
  if (tid < 3) rp[(size_t)m * kRP + 2 + tid] = anchors[(size_t)i * kRP + 2 + tid];
}

// ---------------- MFMA bf16 GEMM, m97 structure (128x128 tile, BK=32) -------
// 1D grid, decoded so blocks sharing data are XCD/L2-local.
// MODE 0: scores = baf @ attnw^T (+attn_b), f32 out [16000][999]
//         XCD = col-stripe -> B panel (640KB) L2-resident per XCD.
// MODE 1: attf   = attn @ bafT^T, bf16 out [16][1000][2560], batched
//         XCD owns 2 batches -> per-batch A+B (7MB) stream once per XCD.
template <int MODE>
__global__ __launch_bounds__(256) void k_mfma_gemm(
    const short* __restrict__ A,
    const short* __restrict__ Bt,
    const float* __restrict__ bias,
    void* __restrict__ Cout, int K, int lda, int ldb) {
  __shared__ short smem[8192];                 // As: 8 KB, Bs: 8 KB
  char* sA = (char*)smem;
  char* sB = (char*)smem + 8192;
  int tid = threadIdx.x, lane = tid & 63, wv = tid >> 6;
  int bid = blockIdx.x;
  int m0, n0, bz = 0;
  const short* Ap = A;
  const short* Bp = Bt;
  if (MODE == 0) {
    // col-tile = XCD: 8 col stripes, B panel L2-resident; A panels from L3
    m0 = (bid >> 3) * 128; n0 = (bid & 7) * 128;
  } else {
    // bz = (bid&15): XCD (bid&7) owns batches {k, k+8}; within a batch,
    // inner = bid>>4 walks d-tile fastest (20 share one attn m-panel)
    bz = bid & 15;
    int r = bid >> 4;               // 0..159
    m0 = (r / 20) * 128; n0 = (r % 20) * 128;
    Ap = A + (size_t)bz * kNP * kNP;
    Bp = Bt + (size_t)bz * kD * kNP;
  }
  int wm = (wv >> 1) * 64, wn = (wv & 1) * 64;
  int sRow = lane >> 2;          // 0..15 row within 16-row chunk
  int sKo  = (lane & 3) * 8;     // k element offset
  f32x4 acc[4][4] = {};

  for (int k0 = 0; k0 < K; k0 += 32) {
    const short* ga = Ap + (size_t)(m0 + 32 * wv + sRow) * lda + k0 + sKo;
    GLOAD_LDS16(ga,            sA + wv * 2048);
    GLOAD_LDS16(ga + 16 * lda, sA + wv * 2048 + 1024);
    const short* gb = Bp + (size_t)(n0 + 32 * wv + sRow) * ldb + k0 + sKo;
    GLOAD_LDS16(gb,            sB + wv * 2048);
    GLOAD_LDS16(gb + 16 * ldb, sB + wv * 2048 + 1024);
    __syncthreads();

    bf16x8 af[4], bfg[4];
#pragma unroll
    for (int i = 0; i < 4; i++)
      af[i] = *(const bf16x8*)(sA + ((size_t)(wm + i * 16 + (lane & 15))) * 64 + (lane >> 4) * 16);
#pragma unroll
    for (int j = 0; j < 4; j++)
      bfg[j] = *(const bf16x8*)(sB + ((size_t)(wn + j * 16 + (lane & 15))) * 64 + (lane >> 4) * 16);
#pragma unroll
    for (int i = 0; i < 4; i++)
#pragma unroll
      for (int j = 0; j < 4; j++)
        acc[i][j] = __builtin_amdgcn_mfma_f32_16x16x32_bf16(af[i], bfg[j], acc[i][j], 0, 0, 0);
    __syncthreads();
  }

  // epilogue
#pragma unroll
  for (int i = 0; i < 4; i++) {
#pragma unroll
    for (int j = 0; j < 4; j++) {
#pragma unroll
      for (int r = 0; r < 4; r++) {
        int row = m0 + wm + i * 16 + (lane >> 4) * 4 + r;
        int col = n0 + wn + j * 16 + (lane & 15);
        float v = acc[i][j][r];
        if (MODE == 0) {
          if (col < kNM1)
            ((float*)Cout)[(size_t)row * kNM1 + col] = v + bias[col];
        } else {
          if (row < kN)
            ((short*)Cout)[((size_t)bz * kN + row) * kD + col] = f2bf(v);
        }
      }
    }
  }
}

// ---------------- head GEMM split-K: BM=64, BN=384, 4 K-chunks --------------
// part[ks][16000][384] = [attf|baf](rows, Kchunk) @ whead^T(:, Kchunk)
__global__ __launch_bounds__(256) void k_head_sk(
    const short* __restrict__ A,   // attf [16000][2560]
    const short* __restrict__ A2,  // baf  [16000][2560]
    const short* __restrict__ Bt,  // whead [384][5120]
    float* __restrict__ part) {
  __shared__ short smem[14336];    // A 4KB + B 24KB, single buffer
  char* sA = (char*)smem;
  char* sB = (char*)smem + 4096;
  int tid = threadIdx.x, lane = tid & 63, wv = tid >> 6;
  int bid = blockIdx.x;
  int ks = bid / (kM / 64);        // K-chunk slow: m-tiles sharing a B-slice adjacent
  int mt = bid % (kM / 64);
  int m0 = mt * 64;
  int kbase = ks * (kK2 / kKS);    // 1280
  int sRow = lane >> 2, sKo = (lane & 3) * 8;
  f32x4 acc[4][6] = {};

  for (int t = 0; t < (kK2 / kKS) / 32; t++) {   // 40 steps
    int k0 = kbase + t * 32;
    const short* Abase = A; int kk = k0;
    if (k0 >= kD) { Abase = A2; kk = k0 - kD; }
    GLOAD_LDS16(Abase + (size_t)(m0 + wv * 16 + sRow) * kD + kk + sKo, sA + wv * 1024);
#pragma unroll
    for (int g = 0; g < 6; g++)
      GLOAD_LDS16(Bt + (size_t)(g * 64 + wv * 16 + sRow) * kK2 + k0 + sKo,
                  sB + g * 4096 + wv * 1024);
    __syncthreads();

    bf16x8 af[4], bfr[6];
#pragma unroll
    for (int i = 0; i < 4; i++)
      af[i] = *(const bf16x8*)(sA + (i * 16 + (lane & 15)) * 64 + (lane >> 4) * 16);
#pragma unroll
    for (int j = 0; j < 6; j++)
      bfr[j] = *(const bf16x8*)(sB + (wv * 96 + j * 16 + (lane & 15)) * 64 + (lane >> 4) * 16);
#pragma unroll
    for (int i = 0; i < 4; i++)
#pragma unroll
      for (int j = 0; j < 6; j++)
        acc[i][j] = __builtin_amdgcn_mfma_f32_16x16x32_bf16(af[i], bfr[j], acc[i][j], 0, 0, 0);
    __syncthreads();
  }

  float* pbase = part + (size_t)ks * kM * 384;
#pragma unroll
  for (int i = 0; i < 4; i++) {
#pragma unroll
    for (int j = 0; j < 6; j++) {
#pragma unroll
      for (int r = 0; r < 4; r++) {
        int row = m0 + i * 16 + (lane >> 4) * 4 + r;
        int col = wv * 96 + j * 16 + (lane & 15);
        pbase[(size_t)row * 384 + col] = acc[i][j][r];
      }
    }
  }
}

// ---------------- head reduce: sum 4 partials + epilogue -> rp --------------
__global__ __launch_bounds__(256) void k_head_reduce(
    const float* __restrict__ part,
    const float* __restrict__ reg_b, const float* __restrict__ cls_b,
    const float* __restrict__ anchors, float* __restrict__ rp) {
  int idx = blockIdx.x * 256 + threadIdx.x;
  if (idx >= kM * 384) return;
  int row = idx / 384, col = idx % 384;
  size_t stride = (size_t)kM * 384;
  float v = part[idx] + part[stride + idx] + part[2 * stride + idx] + part[3 * stride + idx];
  int n = row % kN;
  if (col < 3 * kS) {
    float tv = v + reg_b[col];
    if (col >= 2 * kS) tv = 1.0f / (1.0f + __expf(-tv));
    rp[(size_t)row * kRP + 5 + col] = anchors[(size_t)n * kRP + 5 + col] + tv;
  } else if (col < 3 * kS + kNC) {
    rp[(size_t)row * kRP + (col - 3 * kS)] = v + cls_b[col - 3 * kS];
  }
}

extern "C" void kernel_launch(void* const* d_in, const int* in_sizes, int n_in,
                              void* d_out, int out_size, void* d_ws, size_t ws_size,
                              hipStream_t stream) {
  const float* bf      = (const float*)d_in[0];
  const float* conv_w  = (const float*)d_in[1];
  const float* conv_b  = (const float*)d_in[2];
  const int*   cut     = (const int*)d_in[3];
  const void*  mask    = d_in[4];
  const float* anchors = (const float*)d_in[5];
  const float* attn_w  = (const float*)d_in[6];
  const float* attn_b  = (const float*)d_in[7];
  const float* cls_w   = (const float*)d_in[8];
  const float* cls_b   = (const float*)d_in[9];
  const float* reg_w   = (const float*)d_in[10];
  const float* reg_b   = (const float*)d_in[11];

  float* out    = (float*)d_out;
  float* rp     = out + OFF_RP;
  float* attn_o = out + OFF_ATTN;
  float* feats  = out + OFF_FEAT;

  char*  ws      = (char*)d_ws;
  short* baf     = (short*)(ws + WB_BAF);
  short* bafT    = (short*)(ws + WB_BAFT);
  short* attf    = (short*)(ws + WB_ATTF);
  short* attnw   = (short*)(ws + WB_ATTNW);
  short* whead   = (short*)(ws + WB_WHEAD);
  short* attn_bf = (short*)(ws + WB_ATTNB);
  float* scores  = (float*)(ws + WB_SCORE);
  float* part    = (float*)(ws + WB_PART);
  int*   flag    = (int*)(ws + WB_FLAG);

  k_detect<<<1, 256, 0, stream>>>((const unsigned char*)mask, flag);
  k_conv<<<(kB * kHW) / 256, 256, 0, stream>>>(bf, conv_w, conv_b, feats);
  k_gather<<<(kB * kN * kH) / 256, 256, 0, stream>>>(feats, cut, mask, flag, baf);
  {
    dim3 g(kD / 64, 16, kB);  // d-tiles, n-tiles, batch
    k_transpose<<<g, 256, 0, stream>>>(baf, bafT);
  }
  k_cvt_attnw<<<(kNP * kD + 255) / 256, 256, 0, stream>>>(attn_w, attnw);
  k_cvt_whead<<<(384 * kK2 + 255) / 256, 256, 0, stream>>>(reg_w, cls_w, whead);
  // scores GEMM: 1000 blocks (125 m-tiles x 8 col-tiles, col fastest = XCD)
  k_mfma_gemm<0><<<kM / 128 * 8, 256, 0, stream>>>(baf, attnw, attn_b, scores,
                                                   kD, kD, kD);
  k_softmax<<<kM, 256, 0, stream>>>(scores, anchors, attn_o, attn_bf, rp);
  // att GEMM: 2560 blocks; bz = bid&15 -> XCD-batch affinity
  k_mfma_gemm<1><<<kB * 8 * 20, 256, 0, stream>>>(attn_bf, bafT, nullptr, attf,
                                                  kNP, kNP, kNP);
  // head GEMM split-K + reduce
  k_head_sk<<<kKS * (kM / 64), 256, 0, stream>>>(attf, baf, whead, part);
  k_head_reduce<<<(kM * 384) / 256, 256, 0, stream>>>(part, reg_b, cls_b,
                                                      anchors, rp);
}

// Round 6
// 690.294 us; speedup vs baseline: 1.1684x; 1.1684x over previous
//
#include <hip/hip_runtime.h>
#include <cmath>

// Problem constants
static constexpr int kB   = 16;
static constexpr int kC   = 64;
static constexpr int kH   = 160;
static constexpr int kW   = 192;
static constexpr int kN   = 1000;
static constexpr int kAFC = 16;
static constexpr int kS   = 96;
static constexpr int kNC  = 2;
static constexpr int kD   = kAFC * kH;     // 2560
static constexpr int kHW  = kH * kW;       // 30720
static constexpr int kNM1 = kN - 1;        // 999
static constexpr int kM   = kB * kN;       // 16000
static constexpr int kRP  = kNC + 3 + 3 * kS; // 293
static constexpr int kK2  = 2 * kD;        // 5120
static constexpr int kNP  = 1024;          // padded N for att GEMM
static constexpr int kKS  = 4;             // split-K factor for head GEMM

// NOTE: internal feature ordering is d' = h*16 + a (h-major) — chosen so the
// gather writes 32B-contiguous chunks. All internal tensors (baf, bafT, attf)
// and repacked weights (attnw, whead) use d'; externally-visible outputs never
// expose d, so this is safe as long as the repacks apply the same permutation.

// d_out layout (floats)
static constexpr size_t OFF_RP   = 0;
static constexpr size_t OFF_ATTN = (size_t)kB * kN * kRP;
static constexpr size_t OFF_FEAT = OFF_ATTN + (size_t)kB * kN * kN;

// ws layout (bytes)
static constexpr size_t WB_BAF   = 0;                                    // bf16 [16000][2560]
static constexpr size_t WB_BAFT  = WB_BAF   + (size_t)kM * kD * 2;       // bf16 [16][2560][1024]
static constexpr size_t WB_ATTF  = WB_BAFT  + (size_t)kB * kD * kNP * 2; // bf16 [16000][2560]
static constexpr size_t WB_ATTNW = WB_ATTF  + (size_t)kM * kD * 2;       // bf16 [1024][2560]
static constexpr size_t WB_WHEAD = WB_ATTNW + (size_t)kNP * kD * 2;      // bf16 [384][5120]
static constexpr size_t WB_ATTNB = WB_WHEAD + (size_t)384 * kK2 * 2;     // bf16 [16][1024][1024]
static constexpr size_t WB_SCORE = WB_ATTNB + (size_t)kB * kNP * kNP * 2;// f32  [16000][999]
// PART overlays ATTNB+SCORE (both dead by the time head GEMM runs)
static constexpr size_t WB_PART  = WB_ATTNB;                             // f32 [4][16000][384]
static constexpr size_t WB_FLAG  = WB_PART + (size_t)kKS * kM * 384 * 4; // int

typedef __attribute__((ext_vector_type(8))) short bf16x8;
typedef __attribute__((ext_vector_type(4))) float f32x4;

static __device__ inline short f2bf(float f) {
  union { float f; unsigned u; } x; x.f = f;
  unsigned r = (x.u + 0x7FFFu + ((x.u >> 16) & 1u)) >> 16;
  return (short)r;
}

#define GLOAD_LDS16(gp, lp) __builtin_amdgcn_global_load_lds( \
    (const __attribute__((address_space(1))) void*)(gp),      \
    (__attribute__((address_space(3))) void*)(lp), 16, 0, 0)

// ---------------- mask dtype detection ----------------
__global__ void k_detect(const unsigned char* __restrict__ m, int* __restrict__ flag) {
  __shared__ int c1, c2, c3;
  if (threadIdx.x == 0) { c1 = 0; c2 = 0; c3 = 0; }
  __syncthreads();
  int l1 = 0, l2 = 0, l3 = 0;
  for (int g = threadIdx.x; g < (kN * kH) / 4; g += blockDim.x) {
    l1 += (m[4 * g + 1] != 0);
    l2 += (m[4 * g + 2] != 0);
    l3 += (m[4 * g + 3] != 0);
  }
  atomicAdd(&c1, l1); atomicAdd(&c2, l2); atomicAdd(&c3, l3);
  __syncthreads();
  if (threadIdx.x == 0) {
    int f;
    if (c1 > 0)            f = 1;  // uint8 bools
    else if (c2 | c3)      f = 2;  // float32 bools
    else                   f = 0;  // int32 bools
    *flag = f;
  }
}

// ---------------- 1x1 conv (fp32, feats is an output) ----------------
__global__ __launch_bounds__(256) void k_conv(const float* __restrict__ bf,
                                              const float* __restrict__ cw,
                                              const float* __restrict__ cb,
                                              float* __restrict__ feats) {
  __shared__ float w[kAFC * kC];
  __shared__ float bsh[kAFC];
  for (int i = threadIdx.x; i < kAFC * kC; i += 256) w[i] = cw[i];
  if (threadIdx.x < kAFC) bsh[threadIdx.x] = cb[threadIdx.x];
  __syncthreads();
  int idx = blockIdx.x * 256 + threadIdx.x;
  if (idx >= kB * kHW) return;
  int b = idx / kHW, p = idx % kHW;
  float acc[kAFC];
#pragma unroll
  for (int o = 0; o < kAFC; o++) acc[o] = bsh[o];
  const float* src = bf + (size_t)b * kC * kHW + p;
#pragma unroll 4
  for (int c = 0; c < kC; c++) {
    float v = src[(size_t)c * kHW];
#pragma unroll
    for (int o = 0; o < kAFC; o++) acc[o] += v * w[o * kC + c];
  }
  float* dst = feats + (size_t)b * kAFC * kHW + p;
#pragma unroll
  for (int o = 0; o < kAFC; o++) dst[(size_t)o * kHW] = acc[o];
}

// ---------------- gather rois -> baf (bf16, d'=h*16+a layout) ---------------
// Block = (b,h): stage feats[b][:,h,:] (16x192 f32) in LDS once (coalesced,
// each feats element read exactly once), then loop n: pick x, write 32B chunk.
__global__ __launch_bounds__(256) void k_gather(const float* __restrict__ feats,
                                                const int* __restrict__ cut,
                                                const void* __restrict__ mask,
                                                const int* __restrict__ flag,
                                                short* __restrict__ baf) {
  __shared__ float lf[kAFC * 193];   // pad 192->193 to rotate banks per a
  int bid = blockIdx.x;
  int b = bid & 15, h = bid >> 4;
  const float* fbase = feats + (size_t)b * kAFC * kHW + (size_t)h * kW;
  for (int i = threadIdx.x; i < kAFC * kW; i += 256) {
    int a = i / kW, x = i % kW;
    lf[a * 193 + x] = fbase[(size_t)a * kHW + x];
  }
  __syncthreads();
  int f = *flag;
  for (int n = threadIdx.x; n < kN; n += 256) {
    int r = n * kH + h;
    bool inv;
    if (f == 0)      inv = ((const int*)mask)[r] != 0;
    else if (f == 1) inv = ((const unsigned char*)mask)[r] != 0;
    else             inv = ((const float*)mask)[r] != 0.0f;
    bf16x8 v0 = {}, v1 = {};
    if (!inv) {
      int x = cut[r];
#pragma unroll
      for (int a = 0; a < 8; a++)  v0[a] = f2bf(lf[a * 193 + x]);
#pragma unroll
      for (int a = 0; a < 8; a++)  v1[a] = f2bf(lf[(a + 8) * 193 + x]);
    }
    short* dst = baf + (size_t)(b * kN + n) * kD + h * kAFC;
    *(bf16x8*)dst = v0;
    *(bf16x8*)(dst + 8) = v1;
  }
}

// ---------------- transpose baf -> bafT [b][d][n_pad] (zero-pad n>=1000) ----
__global__ __launch_bounds__(256) void k_transpose(const short* __restrict__ baf,
                                                   short* __restrict__ bafT) {
  __shared__ short t[64][66];
  int b = blockIdx.z, n0 = blockIdx.y * 64, d0 = blockIdx.x * 64;
  int c = threadIdx.x & 63, r4 = threadIdx.x >> 6;  // c: 0..63, r4: 0..3
#pragma unroll
  for (int i = 0; i < 16; i++) {
    int nl = r4 + i * 4;
    int n = n0 + nl;
    short v = (n < kN) ? baf[(size_t)(b * kN + n) * kD + d0 + c] : (short)0;
    t[nl][c] = v;
  }
  __syncthreads();
#pragma unroll
  for (int i = 0; i < 16; i++) {
    int dl = r4 + i * 4;
    bafT[((size_t)b * kD + d0 + dl) * kNP + n0 + c] = t[c][dl];
  }
}

// ---- convert attn_w -> bf16 [1024][2560] in d' order (per-row transpose) ---
__global__ __launch_bounds__(256) void k_cvt_attnw(const float* __restrict__ w,
                                                   short* __restrict__ o) {
  __shared__ float lw[kAFC * (kH + 1)];   // 16x161
  int j = blockIdx.x;                      // 0..1023
  short* dst = o + (size_t)j * kD;
  if (j < kNM1) {
    const float* src = w + (size_t)j * kD;
    for (int i = threadIdx.x; i < kD; i += 256) {
      int a = i / kH, h = i % kH;
      lw[a * (kH + 1) + h] = src[i];
    }
    __syncthreads();
    for (int dp = threadIdx.x; dp < kD; dp += 256) {
      int h = dp >> 4, a = dp & 15;
      dst[dp] = f2bf(lw[a * (kH + 1) + h]);
    }
  } else {
    for (int dp = threadIdx.x; dp < kD; dp += 256) dst[dp] = 0;
  }
}

// ---- build head weight bf16 [384][5120], both K-halves in d' order ---------
__global__ __launch_bounds__(256) void k_cvt_whead(const float* __restrict__ reg_w,
                                                   const float* __restrict__ cls_w,
                                                   short* __restrict__ o) {
  __shared__ float lw[2 * kAFC * (kH + 1)];  // 2 x 16 x 161
  int j = blockIdx.x;                        // 0..383
  const float* src = nullptr;
  if (j < 3 * kS)                 src = reg_w + (size_t)j * kK2;
  else if (j < 3 * kS + kNC)      src = cls_w + (size_t)(j - 3 * kS) * kK2;
  short* dst = o + (size_t)j * kK2;
  if (src) {
    for (int i = threadIdx.x; i < kK2; i += 256) {
      int half = i / kD, t = i % kD;
      int a = t / kH, h = t % kH;
      lw[(half * kAFC + a) * (kH + 1) + h] = src[i];
    }
    __syncthreads();
    for (int kp = threadIdx.x; kp < kK2; kp += 256) {
      int half = kp / kD, t = kp % kD;
      int h = t >> 4, a = t & 15;
      dst[kp] = f2bf(lw[(half * kAFC + a) * (kH + 1) + h]);
    }
  } else {
    for (int kp = threadIdx.x; kp < kK2; kp += 256) dst[kp] = 0;
  }
}

// ---------------- softmax: scores -> attn_mat (f32 out) + attn bf16 padded --
__global__ __launch_bounds__(256) void k_softmax(const float* __restrict__ scores,
                                                 const float* __restrict__ anchors,
                                                 float* __restrict__ attn_out,
                                                 short* __restrict__ attn_bf,
                                                 float* __restrict__ rp) {
  int m = blockIdx.x;           // 0..15999
  int b = m / kN;
  int i = m % kN;
  const float* srow = scores + (size_t)m * kNM1;
  int tid = threadIdx.x;
  __shared__ float red[4];
  float v[4];
  float mx = -INFINITY;
#pragma unroll
  for (int t = 0; t < 4; t++) {
    int j = tid + t * 256;
    v[t] = (j < kNM1) ? srow[j] : -INFINITY;
    mx = fmaxf(mx, v[t]);
  }
#pragma unroll
  for (int o = 32; o; o >>= 1) mx = fmaxf(mx, __shfl_down(mx, o));
  if ((tid & 63) == 0) red[tid >> 6] = mx;
  __syncthreads();
  mx = fmaxf(fmaxf(red[0], red[1]), fmaxf(red[2], red[3]));
  __syncthreads();
  float s = 0.f;
#pragma unroll
  for (int t = 0; t < 4; t++) {
    int j = tid + t * 256;
    v[t] = (j < kNM1) ? __expf(v[t] - mx) : 0.f;
    s += v[t];
  }
#pragma unroll
  for (int o = 32; o; o >>= 1) s += __shfl_down(s, o);
  if ((tid & 63) == 0) red[tid >> 6] = s;
  __syncthreads();
  s = red[0] + red[1] + red[2] + red[3];
  float inv = 1.0f / s;
  float* orow = attn_out + (size_t)m * kN;
  short* brow = attn_bf + ((size_t)b * kNP + i) * kNP;
#pragma unroll
  for (int t = 0; t < 4; t++) {
    int j = tid + t * 256;
    if (j < kNM1) {
      int dst = j + (j >= i);
      float p = v[t] * inv;
      orow[dst] = p;
      brow[dst] = f2bf(p);
    }
  }
  if (tid == 0) { orow[i] = 0.f; brow[i] = 0; }
  if (tid < kNP - kN) brow[kN + tid] = 0;           // pad cols 1000..1023
  if (tid < 3) rp[(size_t)m * kRP + 2 + tid] = anchors[(size_t)i * kRP + 2 + tid];
}

// ---------------- MFMA bf16 GEMM, m97 structure (128x128 tile, BK=32) -------
// 1D grid, decoded so blocks sharing data are XCD/L2-local.
// MODE 0: scores = baf @ attnw^T (+attn_b), f32 out [16000][999]
// MODE 1: attf   = attn @ bafT^T, bf16 out [16][1000][2560], batched
template <int MODE>
__global__ __launch_bounds__(256) void k_mfma_gemm(
    const short* __restrict__ A,
    const short* __restrict__ Bt,
    const float* __restrict__ bias,
    void* __restrict__ Cout, int K, int lda, int ldb) {
  __shared__ short smem[8192];                 // As: 8 KB, Bs: 8 KB
  char* sA = (char*)smem;
  char* sB = (char*)smem + 8192;
  int tid = threadIdx.x, lane = tid & 63, wv = tid >> 6;
  int bid = blockIdx.x;
  int m0, n0, bz = 0;
  const short* Ap = A;
  const short* Bp = Bt;
  if (MODE == 0) {
    // col-tile = XCD: 8 col stripes, B panel L2-resident; A panels from L3
    m0 = (bid >> 3) * 128; n0 = (bid & 7) * 128;
  } else {
    // bz = (bid&15): XCD (bid&7) owns batches {k, k+8}
    bz = bid & 15;
    int r = bid >> 4;               // 0..159
    m0 = (r / 20) * 128; n0 = (r % 20) * 128;
    Ap = A + (size_t)bz * kNP * kNP;
    Bp = Bt + (size_t)bz * kD * kNP;
  }
  int wm = (wv >> 1) * 64, wn = (wv & 1) * 64;
  int sRow = lane >> 2;          // 0..15 row within 16-row chunk
  int sKo  = (lane & 3) * 8;     // k element offset
  f32x4 acc[4][4] = {};

  for (int k0 = 0; k0 < K; k0 += 32) {
    const short* ga = Ap + (size_t)(m0 + 32 * wv + sRow) * lda + k0 + sKo;
    GLOAD_LDS16(ga,            sA + wv * 2048);
    GLOAD_LDS16(ga + 16 * lda, sA + wv * 2048 + 1024);
    const short* gb = Bp + (size_t)(n0 + 32 * wv + sRow) * ldb + k0 + sKo;
    GLOAD_LDS16(gb,            sB + wv * 2048);
    GLOAD_LDS16(gb + 16 * ldb, sB + wv * 2048 + 1024);
    __syncthreads();

    bf16x8 af[4], bfg[4];
#pragma unroll
    for (int i = 0; i < 4; i++)
      af[i] = *(const bf16x8*)(sA + ((size_t)(wm + i * 16 + (lane & 15))) * 64 + (lane >> 4) * 16);
#pragma unroll
    for (int j = 0; j < 4; j++)
      bfg[j] = *(const bf16x8*)(sB + ((size_t)(wn + j * 16 + (lane & 15))) * 64 + (lane >> 4) * 16);
#pragma unroll
    for (int i = 0; i < 4; i++)
#pragma unroll
      for (int j = 0; j < 4; j++)
        acc[i][j] = __builtin_amdgcn_mfma_f32_16x16x32_bf16(af[i], bfg[j], acc[i][j], 0, 0, 0);
    __syncthreads();
  }

  // epilogue
#pragma unroll
  for (int i = 0; i < 4; i++) {
#pragma unroll
    for (int j = 0; j < 4; j++) {
#pragma unroll
      for (int r = 0; r < 4; r++) {
        int row = m0 + wm + i * 16 + (lane >> 4) * 4 + r;
        int col = n0 + wn + j * 16 + (lane & 15);
        float v = acc[i][j][r];
        if (MODE == 0) {
          if (col < kNM1)
            ((float*)Cout)[(size_t)row * kNM1 + col] = v + bias[col];
        } else {
          if (row < kN)
            ((short*)Cout)[((size_t)bz * kN + row) * kD + col] = f2bf(v);
        }
      }
    }
  }
}

// ---------------- head GEMM split-K: BM=64, BN=384, 4 K-chunks --------------
// part[ks][16000][384] = [attf|baf](rows, Kchunk) @ whead^T(:, Kchunk)
__global__ __launch_bounds__(256) void k_head_sk(
    const short* __restrict__ A,   // attf [16000][2560]
    const short* __restrict__ A2,  // baf  [16000][2560]
    const short* __restrict__ Bt,  // whead [384][5120]
    float* __restrict__ part) {
  __shared__ short smem[14336];    // A 4KB + B 24KB, single buffer
  char* sA = (char*)smem;
  char* sB = (char*)smem + 4096;
  int tid = threadIdx.x, lane = tid & 63, wv = tid >> 6;
  int bid = blockIdx.x;
  int ks = bid / (kM / 64);        // K-chunk slow: m-tiles sharing a B-slice adjacent
  int mt = bid % (kM / 64);
  int m0 = mt * 64;
  int kbase = ks * (kK2 / kKS);    // 1280
  int sRow = lane >> 2, sKo = (lane & 3) * 8;
  f32x4 acc[4][6] = {};

  for (int t = 0; t < (kK2 / kKS) / 32; t++) {   // 40 steps
    int k0 = kbase + t * 32;
    const short* Abase = A; int kk = k0;
    if (k0 >= kD) { Abase = A2; kk = k0 - kD; }
    GLOAD_LDS16(Abase + (size_t)(m0 + wv * 16 + sRow) * kD + kk + sKo, sA + wv * 1024);
#pragma unroll
    for (int g = 0; g < 6; g++)
      GLOAD_LDS16(Bt + (size_t)(g * 64 + wv * 16 + sRow) * kK2 + k0 + sKo,
                  sB + g * 4096 + wv * 1024);
    __syncthreads();

    bf16x8 af[4], bfr[6];
#pragma unroll
    for (int i = 0; i < 4; i++)
      af[i] = *(const bf16x8*)(sA + (i * 16 + (lane & 15)) * 64 + (lane >> 4) * 16);
#pragma unroll
    for (int j = 0; j < 6; j++)
      bfr[j] = *(const bf16x8*)(sB + (wv * 96 + j * 16 + (lane & 15)) * 64 + (lane >> 4) * 16);
#pragma unroll
    for (int i = 0; i < 4; i++)
#pragma unroll
      for (int j = 0; j < 6; j++)
        acc[i][j] = __builtin_amdgcn_mfma_f32_16x16x32_bf16(af[i], bfr[j], acc[i][j], 0, 0, 0);
    __syncthreads();
  }

  float* pbase = part + (size_t)ks * kM * 384;
#pragma unroll
  for (int i = 0; i < 4; i++) {
#pragma unroll
    for (int j = 0; j < 6; j++) {
#pragma unroll
      for (int r = 0; r < 4; r++) {
        int row = m0 + i * 16 + (lane >> 4) * 4 + r;
        int col = wv * 96 + j * 16 + (lane & 15);
        pbase[(size_t)row * 384 + col] = acc[i][j][r];
      }
    }
  }
}

// ---------------- head reduce: sum 4 partials + epilogue -> rp --------------
__global__ __launch_bounds__(256) void k_head_reduce(
    const float* __restrict__ part,
    const float* __restrict__ reg_b, const float* __restrict__ cls_b,
    const float* __restrict__ anchors, float* __restrict__ rp) {
  int idx = blockIdx.x * 256 + threadIdx.x;
  if (idx >= kM * 384) return;
  int row = idx / 384, col = idx % 384;
  size_t stride = (size_t)kM * 384;
  float v = part[idx] + part[stride + idx] + part[2 * stride + idx] + part[3 * stride + idx];
  int n = row % kN;
  if (col < 3 * kS) {
    float tv = v + reg_b[col];
    if (col >= 2 * kS) tv = 1.0f / (1.0f + __expf(-tv));
    rp[(size_t)row * kRP + 5 + col] = anchors[(size_t)n * kRP + 5 + col] + tv;
  } else if (col < 3 * kS + kNC) {
    rp[(size_t)row * kRP + (col - 3 * kS)] = v + cls_b[col - 3 * kS];
  }
}

extern "C" void kernel_launch(void* const* d_in, const int* in_sizes, int n_in,
                              void* d_out, int out_size, void* d_ws, size_t ws_size,
                              hipStream_t stream) {
  const float* bf      = (const float*)d_in[0];
  const float* conv_w  = (const float*)d_in[1];
  const float* conv_b  = (const float*)d_in[2];
  const int*   cut     = (const int*)d_in[3];
  const void*  mask    = d_in[4];
  const float* anchors = (const float*)d_in[5];
  const float* attn_w  = (const float*)d_in[6];
  const float* attn_b  = (const float*)d_in[7];
  const float* cls_w   = (const float*)d_in[8];
  const float* cls_b   = (const float*)d_in[9];
  const float* reg_w   = (const float*)d_in[10];
  const float* reg_b   = (const float*)d_in[11];

  float* out    = (float*)d_out;
  float* rp     = out + OFF_RP;
  float* attn_o = out + OFF_ATTN;
  float* feats  = out + OFF_FEAT;

  char*  ws      = (char*)d_ws;
  short* baf     = (short*)(ws + WB_BAF);
  short* bafT    = (short*)(ws + WB_BAFT);
  short* attf    = (short*)(ws + WB_ATTF);
  short* attnw   = (short*)(ws + WB_ATTNW);
  short* whead   = (short*)(ws + WB_WHEAD);
  short* attn_bf = (short*)(ws + WB_ATTNB);
  float* scores  = (float*)(ws + WB_SCORE);
  float* part    = (float*)(ws + WB_PART);
  int*   flag    = (int*)(ws + WB_FLAG);

  k_detect<<<1, 256, 0, stream>>>((const unsigned char*)mask, flag);
  k_conv<<<(kB * kHW) / 256, 256, 0, stream>>>(bf, conv_w, conv_b, feats);
  // gather: one block per (b,h); 2560 blocks
  k_gather<<<kB * kH, 256, 0, stream>>>(feats, cut, mask, flag, baf);
  {
    dim3 g(kD / 64, 16, kB);  // d-tiles, n-tiles, batch
    k_transpose<<<g, 256, 0, stream>>>(baf, bafT);
  }
  k_cvt_attnw<<<kNP, 256, 0, stream>>>(attn_w, attnw);
  k_cvt_whead<<<384, 256, 0, stream>>>(reg_w, cls_w, whead);
  // scores GEMM: 1000 blocks (125 m-tiles x 8 col-tiles, col fastest = XCD)
  k_mfma_gemm<0><<<kM / 128 * 8, 256, 0, stream>>>(baf, attnw, attn_b, scores,
                                                   kD, kD, kD);
  k_softmax<<<kM, 256, 0, stream>>>(scores, anchors, attn_o, attn_bf, rp);
  // att GEMM: 2560 blocks; bz = bid&15 -> XCD-batch affinity
  k_mfma_gemm<1><<<kB * 8 * 20, 256, 0, stream>>>(attn_bf, bafT, nullptr, attf,
                                                  kNP, kNP, kNP);
  // head GEMM split-K + reduce
  k_head_sk<<<kKS * (kM / 64), 256, 0, stream>>>(attf, baf, whead, part);
  k_head_reduce<<<(kM * 384) / 256, 256, 0, stream>>>(part, reg_b, cls_b,
                                                      anchors, rp);
}

// Round 7
// 680.885 us; speedup vs baseline: 1.1846x; 1.0138x over previous
//
#include <hip/hip_runtime.h>
#include <cmath>

// Problem constants
static constexpr int kB   = 16;
static constexpr int kC   = 64;
static constexpr int kH   = 160;
static constexpr int kW   = 192;
static constexpr int kN   = 1000;
static constexpr int kAFC = 16;
static constexpr int kS   = 96;
static constexpr int kNC  = 2;
static constexpr int kD   = kAFC * kH;     // 2560
static constexpr int kHW  = kH * kW;       // 30720
static constexpr int kNM1 = kN - 1;        // 999
static constexpr int kM   = kB * kN;       // 16000
static constexpr int kRP  = kNC + 3 + 3 * kS; // 293
static constexpr int kK2  = 2 * kD;        // 5120
static constexpr int kNP  = 1024;          // padded N for att GEMM
static constexpr int kKS  = 4;             // split-K factor for head GEMM

// NOTE: internal feature ordering is d' = h*16 + a (h-major) — chosen so the
// gather writes 32B-contiguous chunks. All internal tensors (baf, bafT, attf)
// and repacked weights (attnw, whead) use d'; externally-visible outputs never
// expose d, so this is safe as long as the repacks apply the same permutation.

// d_out layout (floats)
static constexpr size_t OFF_RP   = 0;
static constexpr size_t OFF_ATTN = (size_t)kB * kN * kRP;
static constexpr size_t OFF_FEAT = OFF_ATTN + (size_t)kB * kN * kN;

// ws layout (bytes)
static constexpr size_t WB_BAF   = 0;                                    // bf16 [16000][2560]
static constexpr size_t WB_BAFT  = WB_BAF   + (size_t)kM * kD * 2;       // bf16 [16][2560][1024]
static constexpr size_t WB_ATTF  = WB_BAFT  + (size_t)kB * kD * kNP * 2; // bf16 [16000][2560]
static constexpr size_t WB_ATTNW = WB_ATTF  + (size_t)kM * kD * 2;       // bf16 [1024][2560]
static constexpr size_t WB_WHEAD = WB_ATTNW + (size_t)kNP * kD * 2;      // bf16 [384][5120]
static constexpr size_t WB_ATTNB = WB_WHEAD + (size_t)384 * kK2 * 2;     // bf16 [16][1024][1024]
static constexpr size_t WB_SCORE = WB_ATTNB + (size_t)kB * kNP * kNP * 2;// f32  [16000][999]
// PART overlays ATTNB+SCORE (both dead by the time head GEMM runs)
static constexpr size_t WB_PART  = WB_ATTNB;                             // f32 [4][16000][384]
static constexpr size_t WB_FLAG  = WB_PART + (size_t)kKS * kM * 384 * 4; // int

typedef __attribute__((ext_vector_type(8))) short bf16x8;
typedef __attribute__((ext_vector_type(4))) float f32x4;

static __device__ inline short f2bf(float f) {
  union { float f; unsigned u; } x; x.f = f;
  unsigned r = (x.u + 0x7FFFu + ((x.u >> 16) & 1u)) >> 16;
  return (short)r;
}

#define GLOAD_LDS16(gp, lp) __builtin_amdgcn_global_load_lds( \
    (const __attribute__((address_space(1))) void*)(gp),      \
    (__attribute__((address_space(3))) void*)(lp), 16, 0, 0)

// ---------------- mask dtype detection ----------------
__global__ void k_detect(const unsigned char* __restrict__ m, int* __restrict__ flag) {
  __shared__ int c1, c2, c3;
  if (threadIdx.x == 0) { c1 = 0; c2 = 0; c3 = 0; }
  __syncthreads();
  int l1 = 0, l2 = 0, l3 = 0;
  for (int g = threadIdx.x; g < (kN * kH) / 4; g += blockDim.x) {
    l1 += (m[4 * g + 1] != 0);
    l2 += (m[4 * g + 2] != 0);
    l3 += (m[4 * g + 3] != 0);
  }
  atomicAdd(&c1, l1); atomicAdd(&c2, l2); atomicAdd(&c3, l3);
  __syncthreads();
  if (threadIdx.x == 0) {
    int f;
    if (c1 > 0)            f = 1;  // uint8 bools
    else if (c2 | c3)      f = 2;  // float32 bools
    else                   f = 0;  // int32 bools
    *flag = f;
  }
}

// ---------------- 1x1 conv (fp32, feats is an output) ----------------
__global__ __launch_bounds__(256) void k_conv(const float* __restrict__ bf,
                                              const float* __restrict__ cw,
                                              const float* __restrict__ cb,
                                              float* __restrict__ feats) {
  __shared__ float w[kAFC * kC];
  __shared__ float bsh[kAFC];
  for (int i = threadIdx.x; i < kAFC * kC; i += 256) w[i] = cw[i];
  if (threadIdx.x < kAFC) bsh[threadIdx.x] = cb[threadIdx.x];
  __syncthreads();
  int idx = blockIdx.x * 256 + threadIdx.x;
  if (idx >= kB * kHW) return;
  int b = idx / kHW, p = idx % kHW;
  float acc[kAFC];
#pragma unroll
  for (int o = 0; o < kAFC; o++) acc[o] = bsh[o];
  const float* src = bf + (size_t)b * kC * kHW + p;
#pragma unroll 4
  for (int c = 0; c < kC; c++) {
    float v = src[(size_t)c * kHW];
#pragma unroll
    for (int o = 0; o < kAFC; o++) acc[o] += v * w[o * kC + c];
  }
  float* dst = feats + (size_t)b * kAFC * kHW + p;
#pragma unroll
  for (int o = 0; o < kAFC; o++) dst[(size_t)o * kHW] = acc[o];
}

// ---------------- gather rois -> baf (bf16, d'=h*16+a layout) ---------------
__global__ __launch_bounds__(256) void k_gather(const float* __restrict__ feats,
                                                const int* __restrict__ cut,
                                                const void* __restrict__ mask,
                                                const int* __restrict__ flag,
                                                short* __restrict__ baf) {
  __shared__ float lf[kAFC * 193];   // pad 192->193 to rotate banks per a
  int bid = blockIdx.x;
  int b = bid & 15, h = bid >> 4;
  const float* fbase = feats + (size_t)b * kAFC * kHW + (size_t)h * kW;
  for (int i = threadIdx.x; i < kAFC * kW; i += 256) {
    int a = i / kW, x = i % kW;
    lf[a * 193 + x] = fbase[(size_t)a * kHW + x];
  }
  __syncthreads();
  int f = *flag;
  for (int n = threadIdx.x; n < kN; n += 256) {
    int r = n * kH + h;
    bool inv;
    if (f == 0)      inv = ((const int*)mask)[r] != 0;
    else if (f == 1) inv = ((const unsigned char*)mask)[r] != 0;
    else             inv = ((const float*)mask)[r] != 0.0f;
    bf16x8 v0 = {}, v1 = {};
    if (!inv) {
      int x = cut[r];
#pragma unroll
      for (int a = 0; a < 8; a++)  v0[a] = f2bf(lf[a * 193 + x]);
#pragma unroll
      for (int a = 0; a < 8; a++)  v1[a] = f2bf(lf[(a + 8) * 193 + x]);
    }
    short* dst = baf + (size_t)(b * kN + n) * kD + h * kAFC;
    *(bf16x8*)dst = v0;
    *(bf16x8*)(dst + 8) = v1;
  }
}

// ---------------- transpose baf -> bafT [b][d][n_pad] (zero-pad n>=1000) ----
__global__ __launch_bounds__(256) void k_transpose(const short* __restrict__ baf,
                                                   short* __restrict__ bafT) {
  __shared__ short t[64][66];
  int b = blockIdx.z, n0 = blockIdx.y * 64, d0 = blockIdx.x * 64;
  int c = threadIdx.x & 63, r4 = threadIdx.x >> 6;  // c: 0..63, r4: 0..3
#pragma unroll
  for (int i = 0; i < 16; i++) {
    int nl = r4 + i * 4;
    int n = n0 + nl;
    short v = (n < kN) ? baf[(size_t)(b * kN + n) * kD + d0 + c] : (short)0;
    t[nl][c] = v;
  }
  __syncthreads();
#pragma unroll
  for (int i = 0; i < 16; i++) {
    int dl = r4 + i * 4;
    bafT[((size_t)b * kD + d0 + dl) * kNP + n0 + c] = t[c][dl];
  }
}

// ---- convert attn_w -> bf16 [1024][2560] in d' order (per-row transpose) ---
__global__ __launch_bounds__(256) void k_cvt_attnw(const float* __restrict__ w,
                                                   short* __restrict__ o) {
  __shared__ float lw[kAFC * (kH + 1)];   // 16x161
  int j = blockIdx.x;                      // 0..1023
  short* dst = o + (size_t)j * kD;
  if (j < kNM1) {
    const float* src = w + (size_t)j * kD;
    for (int i = threadIdx.x; i < kD; i += 256) {
      int a = i / kH, h = i % kH;
      lw[a * (kH + 1) + h] = src[i];
    }
    __syncthreads();
    for (int dp = threadIdx.x; dp < kD; dp += 256) {
      int h = dp >> 4, a = dp & 15;
      dst[dp] = f2bf(lw[a * (kH + 1) + h]);
    }
  } else {
    for (int dp = threadIdx.x; dp < kD; dp += 256) dst[dp] = 0;
  }
}

// ---- build head weight bf16 [384][5120], both K-halves in d' order ---------
__global__ __launch_bounds__(256) void k_cvt_whead(const float* __restrict__ reg_w,
                                                   const float* __restrict__ cls_w,
                                                   short* __restrict__ o) {
  __shared__ float lw[2 * kAFC * (kH + 1)];  // 2 x 16 x 161
  int j = blockIdx.x;                        // 0..383
  const float* src = nullptr;
  if (j < 3 * kS)                 src = reg_w + (size_t)j * kK2;
  else if (j < 3 * kS + kNC)      src = cls_w + (size_t)(j - 3 * kS) * kK2;
  short* dst = o + (size_t)j * kK2;
  if (src) {
    for (int i = threadIdx.x; i < kK2; i += 256) {
      int half = i / kD, t = i % kD;
      int a = t / kH, h = t % kH;
      lw[(half * kAFC + a) * (kH + 1) + h] = src[i];
    }
    __syncthreads();
    for (int kp = threadIdx.x; kp < kK2; kp += 256) {
      int half = kp / kD, t = kp % kD;
      int h = t >> 4, a = t & 15;
      dst[kp] = f2bf(lw[(half * kAFC + a) * (kH + 1) + h]);
    }
  } else {
    for (int kp = threadIdx.x; kp < kK2; kp += 256) dst[kp] = 0;
  }
}

// ---------------- softmax: scores -> attn_mat (f32 out) + attn bf16 padded --
__global__ __launch_bounds__(256) void k_softmax(const float* __restrict__ scores,
                                                 const float* __restrict__ anchors,
                                                 float* __restrict__ attn_out,
                                                 short* __restrict__ attn_bf,
                                                 float* __restrict__ rp) {
  int m = blockIdx.x;           // 0..15999
  int b = m / kN;
  int i = m % kN;
  const float* srow = scores + (size_t)m * kNM1;
  int tid = threadIdx.x;
  __shared__ float red[4];
  float v[4];
  float mx = -INFINITY;
#pragma unroll
  for (int t = 0; t < 4; t++) {
    int j = tid + t * 256;
    v[t] = (j < kNM1) ? srow[j] : -INFINITY;
    mx = fmaxf(mx, v[t]);
  }
#pragma unroll
  for (int o = 32; o; o >>= 1) mx = fmaxf(mx, __shfl_down(mx, o));
  if ((tid & 63) == 0) red[tid >> 6] = mx;
  __syncthreads();
  mx = fmaxf(fmaxf(red[0], red[1]), fmaxf(red[2], red[3]));
  __syncthreads();
  float s = 0.f;
#pragma unroll
  for (int t = 0; t < 4; t++) {
    int j = tid + t * 256;
    v[t] = (j < kNM1) ? __expf(v[t] - mx) : 0.f;
    s += v[t];
  }
#pragma unroll
  for (int o = 32; o; o >>= 1) s += __shfl_down(s, o);
  if ((tid & 63) == 0) red[tid >> 6] = s;
  __syncthreads();
  s = red[0] + red[1] + red[2] + red[3];
  float inv = 1.0f / s;
  float* orow = attn_out + (size_t)m * kN;
  short* brow = attn_bf + ((size_t)b * kNP + i) * kNP;
#pragma unroll
  for (int t = 0; t < 4; t++) {
    int j = tid + t * 256;
    if (j < kNM1) {
      int dst = j + (j >= i);
      float p = v[t] * inv;
      orow[dst] = p;
      brow[dst] = f2bf(p);
    }
  }
  if (tid == 0) { orow[i] = 0.f; brow[i] = 0; }
  if (tid < kNP - kN) brow[kN + tid] = 0;           // pad cols 1000..1023
  if (tid < 3) rp[(size_t)m * kRP + 2 + tid] = anchors[(size_t)i * kRP + 2 + tid];
}

// ---------------- MFMA bf16 GEMM, m97 structure (128x128 tile, BK=32) -------
// 1D grid, decoded so each XCD's HBM traffic is a disjoint partition.
// MODE 0: scores = baf @ attnw^T (+attn_b), f32 out [16000][999]
//   Chunked XCD swizzle (bijective: 1000 = 8*125): XCD x owns wgid in
//   [125x,125(x+1)) = a ~16-m-tile row stripe of A (streamed once from HBM by
//   exactly one XCD); col fastest inside -> B set (5.2MB) ~L2-resident.
// MODE 1: attf = attn @ bafT^T, bf16 out [16][1000][2560], batched
//   Two passes: blocks [0,1280) = batches 0-7 (XCD=batch), [1280,2560) =
//   batches 8-15. Within a batch m fastest: bafT panel (256KB) hot for 8
//   blocks, attn panel (2MB) L2-resident. Per-XCD working set ~2.3MB.
template <int MODE>
__global__ __launch_bounds__(256) void k_mfma_gemm(
    const short* __restrict__ A,
    const short* __restrict__ Bt,
    const float* __restrict__ bias,
    void* __restrict__ Cout, int K, int lda, int ldb) {
  __shared__ short smem[8192];                 // As: 8 KB, Bs: 8 KB
  char* sA = (char*)smem;
  char* sB = (char*)smem + 8192;
  int tid = threadIdx.x, lane = tid & 63, wv = tid >> 6;
  int bid = blockIdx.x;
  int m0, n0, bz = 0;
  const short* Ap = A;
  const short* Bp = Bt;
  if (MODE == 0) {
    int wgid = (bid & 7) * 125 + (bid >> 3);   // chunked: XCD -> contiguous range
    m0 = (wgid >> 3) * 128; n0 = (wgid & 7) * 128;
  } else {
    int half = bid / 1280;
    int rem  = bid - half * 1280;
    bz = (rem & 7) + 8 * half;                 // XCD = rem&7 = batch (per pass)
    int inner = rem >> 3;                      // 0..159, sequential per XCD
    m0 = (inner & 7) * 128;                    // m fastest
    n0 = (inner >> 3) * 128;                   // d slow
    Ap = A + (size_t)bz * kNP * kNP;
    Bp = Bt + (size_t)bz * kD * kNP;
  }
  int wm = (wv >> 1) * 64, wn = (wv & 1) * 64;
  int sRow = lane >> 2;          // 0..15 row within 16-row chunk
  int sKo  = (lane & 3) * 8;     // k element offset
  f32x4 acc[4][4] = {};

  for (int k0 = 0; k0 < K; k0 += 32) {
    const short* ga = Ap + (size_t)(m0 + 32 * wv + sRow) * lda + k0 + sKo;
    GLOAD_LDS16(ga,            sA + wv * 2048);
    GLOAD_LDS16(ga + 16 * lda, sA + wv * 2048 + 1024);
    const short* gb = Bp + (size_t)(n0 + 32 * wv + sRow) * ldb + k0 + sKo;
    GLOAD_LDS16(gb,            sB + wv * 2048);
    GLOAD_LDS16(gb + 16 * ldb, sB + wv * 2048 + 1024);
    __syncthreads();

    bf16x8 af[4], bfg[4];
#pragma unroll
    for (int i = 0; i < 4; i++)
      af[i] = *(const bf16x8*)(sA + ((size_t)(wm + i * 16 + (lane & 15))) * 64 + (lane >> 4) * 16);
#pragma unroll
    for (int j = 0; j < 4; j++)
      bfg[j] = *(const bf16x8*)(sB + ((size_t)(wn + j * 16 + (lane & 15))) * 64 + (lane >> 4) * 16);
#pragma unroll
    for (int i = 0; i < 4; i++)
#pragma unroll
      for (int j = 0; j < 4; j++)
        acc[i][j] = __builtin_amdgcn_mfma_f32_16x16x32_bf16(af[i], bfg[j], acc[i][j], 0, 0, 0);
    __syncthreads();
  }

  // epilogue
#pragma unroll
  for (int i = 0; i < 4; i++) {
#pragma unroll
    for (int j = 0; j < 4; j++) {
#pragma unroll
      for (int r = 0; r < 4; r++) {
        int row = m0 + wm + i * 16 + (lane >> 4) * 4 + r;
        int col = n0 + wn + j * 16 + (lane & 15);
        float v = acc[i][j][r];
        if (MODE == 0) {
          if (col < kNM1)
            ((float*)Cout)[(size_t)row * kNM1 + col] = v + bias[col];
        } else {
          if (row < kN)
            ((short*)Cout)[((size_t)bz * kN + row) * kD + col] = f2bf(v);
        }
      }
    }
  }
}

// ---------------- head GEMM split-K: BM=64, BN=384, 4 K-chunks --------------
// part[ks][16000][384] = [attf|baf](rows, Kchunk) @ whead^T(:, Kchunk)
__global__ __launch_bounds__(256) void k_head_sk(
    const short* __restrict__ A,   // attf [16000][2560]
    const short* __restrict__ A2,  // baf  [16000][2560]
    const short* __restrict__ Bt,  // whead [384][5120]
    float* __restrict__ part) {
  __shared__ short smem[14336];    // A 4KB + B 24KB, single buffer
  char* sA = (char*)smem;
  char* sB = (char*)smem + 4096;
  int tid = threadIdx.x, lane = tid & 63, wv = tid >> 6;
  int bid = blockIdx.x;
  int ks = bid / (kM / 64);        // K-chunk slow: m-tiles sharing a B-slice adjacent
  int mt = bid % (kM / 64);
  int m0 = mt * 64;
  int kbase = ks * (kK2 / kKS);    // 1280
  int sRow = lane >> 2, sKo = (lane & 3) * 8;
  f32x4 acc[4][6] = {};

  for (int t = 0; t < (kK2 / kKS) / 32; t++) {   // 40 steps
    int k0 = kbase + t * 32;
    const short* Abase = A; int kk = k0;
    if (k0 >= kD) { Abase = A2; kk = k0 - kD; }
    GLOAD_LDS16(Abase + (size_t)(m0 + wv * 16 + sRow) * kD + kk + sKo, sA + wv * 1024);
#pragma unroll
    for (int g = 0; g < 6; g++)
      GLOAD_LDS16(Bt + (size_t)(g * 64 + wv * 16 + sRow) * kK2 + k0 + sKo,
                  sB + g * 4096 + wv * 1024);
    __syncthreads();

    bf16x8 af[4], bfr[6];
#pragma unroll
    for (int i = 0; i < 4; i++)
      af[i] = *(const bf16x8*)(sA + (i * 16 + (lane & 15)) * 64 + (lane >> 4) * 16);
#pragma unroll
    for (int j = 0; j < 6; j++)
      bfr[j] = *(const bf16x8*)(sB + (wv * 96 + j * 16 + (lane & 15)) * 64 + (lane >> 4) * 16);
#pragma unroll
    for (int i = 0; i < 4; i++)
#pragma unroll
      for (int j = 0; j < 6; j++)
        acc[i][j] = __builtin_amdgcn_mfma_f32_16x16x32_bf16(af[i], bfr[j], acc[i][j], 0, 0, 0);
    __syncthreads();
  }

  float* pbase = part + (size_t)ks * kM * 384;
#pragma unroll
  for (int i = 0; i < 4; i++) {
#pragma unroll
    for (int j = 0; j < 6; j++) {
#pragma unroll
      for (int r = 0; r < 4; r++) {
        int row = m0 + i * 16 + (lane >> 4) * 4 + r;
        int col = wv * 96 + j * 16 + (lane & 15);
        pbase[(size_t)row * 384 + col] = acc[i][j][r];
      }
    }
  }
}

// ---------------- head reduce: sum 4 partials + epilogue -> rp --------------
__global__ __launch_bounds__(256) void k_head_reduce(
    const float* __restrict__ part,
    const float* __restrict__ reg_b, const float* __restrict__ cls_b,
    const float* __restrict__ anchors, float* __restrict__ rp) {
  int idx = blockIdx.x * 256 + threadIdx.x;
  if (idx >= kM * 384) return;
  int row = idx / 384, col = idx % 384;
  size_t stride = (size_t)kM * 384;
  float v = part[idx] + part[stride + idx] + part[2 * stride + idx] + part[3 * stride + idx];
  int n = row % kN;
  if (col < 3 * kS) {
    float tv = v + reg_b[col];
    if (col >= 2 * kS) tv = 1.0f / (1.0f + __expf(-tv));
    rp[(size_t)row * kRP + 5 + col] = anchors[(size_t)n * kRP + 5 + col] + tv;
  } else if (col < 3 * kS + kNC) {
    rp[(size_t)row * kRP + (col - 3 * kS)] = v + cls_b[col - 3 * kS];
  }
}

extern "C" void kernel_launch(void* const* d_in, const int* in_sizes, int n_in,
                              void* d_out, int out_size, void* d_ws, size_t ws_size,
                              hipStream_t stream) {
  const float* bf      = (const float*)d_in[0];
  const float* conv_w  = (const float*)d_in[1];
  const float* conv_b  = (const float*)d_in[2];
  const int*   cut     = (const int*)d_in[3];
  const void*  mask    = d_in[4];
  const float* anchors = (const float*)d_in[5];
  const float* attn_w  = (const float*)d_in[6];
  const float* attn_b  = (const float*)d_in[7];
  const float* cls_w   = (const float*)d_in[8];
  const float* cls_b   = (const float*)d_in[9];
  const float* reg_w   = (const float*)d_in[10];
  const float* reg_b   = (const float*)d_in[11];

  float* out    = (float*)d_out;
  float* rp     = out + OFF_RP;
  float* attn_o = out + OFF_ATTN;
  float* feats  = out + OFF_FEAT;

  char*  ws      = (char*)d_ws;
  short* baf     = (short*)(ws + WB_BAF);
  short* bafT    = (short*)(ws + WB_BAFT);
  short* attf    = (short*)(ws + WB_ATTF);
  short* attnw   = (short*)(ws + WB_ATTNW);
  short* whead   = (short*)(ws + WB_WHEAD);
  short* attn_bf = (short*)(ws + WB_ATTNB);
  float* scores  = (float*)(ws + WB_SCORE);
  float* part    = (float*)(ws + WB_PART);
  int*   flag    = (int*)(ws + WB_FLAG);

  k_detect<<<1, 256, 0, stream>>>((const unsigned char*)mask, flag);
  k_conv<<<(kB * kHW) / 256, 256, 0, stream>>>(bf, conv_w, conv_b, feats);
  // gather: one block per (b,h); 2560 blocks
  k_gather<<<kB * kH, 256, 0, stream>>>(feats, cut, mask, flag, baf);
  {
    dim3 g(kD / 64, 16, kB);  // d-tiles, n-tiles, batch
    k_transpose<<<g, 256, 0, stream>>>(baf, bafT);
  }
  k_cvt_attnw<<<kNP, 256, 0, stream>>>(attn_w, attnw);
  k_cvt_whead<<<384, 256, 0, stream>>>(reg_w, cls_w, whead);
  // scores GEMM: 1000 blocks, chunked XCD swizzle (row-stripe per XCD)
  k_mfma_gemm<0><<<kM / 128 * 8, 256, 0, stream>>>(baf, attnw, attn_b, scores,
                                                   kD, kD, kD);
  k_softmax<<<kM, 256, 0, stream>>>(scores, anchors, attn_o, attn_bf, rp);
  // att GEMM: 2560 blocks; two passes of 8 batches, XCD=batch, m fastest
  k_mfma_gemm<1><<<kB * 8 * 20, 256, 0, stream>>>(attn_bf, bafT, nullptr, attf,
                                                  kNP, kNP, kNP);
  // head GEMM split-K + reduce
  k_head_sk<<<kKS * (kM / 64), 256, 0, stream>>>(attf, baf, whead, part);
  k_head_reduce<<<(kM * 384) / 256, 256, 0, stream>>>(part, reg_b, cls_b,
                                                      anchors, rp);
}

// Round 8
// 630.531 us; speedup vs baseline: 1.2792x; 1.0799x over previous
//
#include <hip/hip_runtime.h>
#include <cmath>

// Problem constants
static constexpr int kB   = 16;
static constexpr int kC   = 64;
static constexpr int kH   = 160;
static constexpr int kW   = 192;
static constexpr int kN   = 1000;
static constexpr int kAFC = 16;
static constexpr int kS   = 96;
static constexpr int kNC  = 2;
static constexpr int kD   = kAFC * kH;     // 2560
static constexpr int kHW  = kH * kW;       // 30720
static constexpr int kNM1 = kN - 1;        // 999
static constexpr int kM   = kB * kN;       // 16000
static constexpr int kRP  = kNC + 3 + 3 * kS; // 293
static constexpr int kK2  = 2 * kD;        // 5120
static constexpr int kNP  = 1024;          // padded N for att GEMM
static constexpr int kKS  = 4;             // split-K factor for head GEMM

// NOTE: internal feature ordering is d' = h*16 + a (h-major) — chosen so the
// gather writes 32B-contiguous chunks. All internal tensors (baf, bafT, attf)
// and repacked weights (attnw, whead) use d'; externally-visible outputs never
// expose d, so this is safe as long as the repacks apply the same permutation.

// d_out layout (floats)
static constexpr size_t OFF_RP   = 0;
static constexpr size_t OFF_ATTN = (size_t)kB * kN * kRP;
static constexpr size_t OFF_FEAT = OFF_ATTN + (size_t)kB * kN * kN;

// ws layout (bytes)
static constexpr size_t WB_BAF   = 0;                                    // bf16 [16000][2560]
static constexpr size_t WB_BAFT  = WB_BAF   + (size_t)kM * kD * 2;       // bf16 [16][2560][1024]
static constexpr size_t WB_ATTF  = WB_BAFT  + (size_t)kB * kD * kNP * 2; // bf16 [16000][2560]
static constexpr size_t WB_ATTNW = WB_ATTF  + (size_t)kM * kD * 2;       // bf16 [1024][2560]
static constexpr size_t WB_WHEAD = WB_ATTNW + (size_t)kNP * kD * 2;      // bf16 [384][5120]
static constexpr size_t WB_ATTNB = WB_WHEAD + (size_t)384 * kK2 * 2;     // bf16 [16][1024][1024]
static constexpr size_t WB_SCORE = WB_ATTNB + (size_t)kB * kNP * kNP * 2;// f32  [16000][999]
// PART overlays ATTNB+SCORE (both dead by the time head GEMM runs)
static constexpr size_t WB_PART  = WB_ATTNB;                             // bf16 [4][16000][384]
static constexpr size_t WB_FLAG  = WB_PART + (size_t)kKS * kM * 384 * 2; // int

typedef __attribute__((ext_vector_type(8))) short bf16x8;
typedef __attribute__((ext_vector_type(4))) float f32x4;

static __device__ inline short f2bf(float f) {
  union { float f; unsigned u; } x; x.f = f;
  unsigned r = (x.u + 0x7FFFu + ((x.u >> 16) & 1u)) >> 16;
  return (short)r;
}
static __device__ inline float bf2f(short s) {
  union { unsigned u; float f; } x; x.u = ((unsigned)(unsigned short)s) << 16;
  return x.f;
}

#define GLOAD_LDS16(gp, lp) __builtin_amdgcn_global_load_lds( \
    (const __attribute__((address_space(1))) void*)(gp),      \
    (__attribute__((address_space(3))) void*)(lp), 16, 0, 0)

// ---------------- mask dtype detection ----------------
__global__ void k_detect(const unsigned char* __restrict__ m, int* __restrict__ flag) {
  __shared__ int c1, c2, c3;
  if (threadIdx.x == 0) { c1 = 0; c2 = 0; c3 = 0; }
  __syncthreads();
  int l1 = 0, l2 = 0, l3 = 0;
  for (int g = threadIdx.x; g < (kN * kH) / 4; g += blockDim.x) {
    l1 += (m[4 * g + 1] != 0);
    l2 += (m[4 * g + 2] != 0);
    l3 += (m[4 * g + 3] != 0);
  }
  atomicAdd(&c1, l1); atomicAdd(&c2, l2); atomicAdd(&c3, l3);
  __syncthreads();
  if (threadIdx.x == 0) {
    int f;
    if (c1 > 0)            f = 1;  // uint8 bools
    else if (c2 | c3)      f = 2;  // float32 bools
    else                   f = 0;  // int32 bools
    *flag = f;
  }
}

// ---------------- 1x1 conv (fp32, feats is an output) ----------------
__global__ __launch_bounds__(256) void k_conv(const float* __restrict__ bf,
                                              const float* __restrict__ cw,
                                              const float* __restrict__ cb,
                                              float* __restrict__ feats) {
  __shared__ float w[kAFC * kC];
  __shared__ float bsh[kAFC];
  for (int i = threadIdx.x; i < kAFC * kC; i += 256) w[i] = cw[i];
  if (threadIdx.x < kAFC) bsh[threadIdx.x] = cb[threadIdx.x];
  __syncthreads();
  int idx = blockIdx.x * 256 + threadIdx.x;
  if (idx >= kB * kHW) return;
  int b = idx / kHW, p = idx % kHW;
  float acc[kAFC];
#pragma unroll
  for (int o = 0; o < kAFC; o++) acc[o] = bsh[o];
  const float* src = bf + (size_t)b * kC * kHW + p;
#pragma unroll 4
  for (int c = 0; c < kC; c++) {
    float v = src[(size_t)c * kHW];
#pragma unroll
    for (int o = 0; o < kAFC; o++) acc[o] += v * w[o * kC + c];
  }
  float* dst = feats + (size_t)b * kAFC * kHW + p;
#pragma unroll
  for (int o = 0; o < kAFC; o++) dst[(size_t)o * kHW] = acc[o];
}

// ---------------- gather rois -> baf (bf16, d'=h*16+a layout) ---------------
__global__ __launch_bounds__(256) void k_gather(const float* __restrict__ feats,
                                                const int* __restrict__ cut,
                                                const void* __restrict__ mask,
                                                const int* __restrict__ flag,
                                                short* __restrict__ baf) {
  __shared__ float lf[kAFC * 193];   // pad 192->193 to rotate banks per a
  int bid = blockIdx.x;
  int b = bid & 15, h = bid >> 4;
  const float* fbase = feats + (size_t)b * kAFC * kHW + (size_t)h * kW;
  for (int i = threadIdx.x; i < kAFC * kW; i += 256) {
    int a = i / kW, x = i % kW;
    lf[a * 193 + x] = fbase[(size_t)a * kHW + x];
  }
  __syncthreads();
  int f = *flag;
  for (int n = threadIdx.x; n < kN; n += 256) {
    int r = n * kH + h;
    bool inv;
    if (f == 0)      inv = ((const int*)mask)[r] != 0;
    else if (f == 1) inv = ((const unsigned char*)mask)[r] != 0;
    else             inv = ((const float*)mask)[r] != 0.0f;
    bf16x8 v0 = {}, v1 = {};
    if (!inv) {
      int x = cut[r];
#pragma unroll
      for (int a = 0; a < 8; a++)  v0[a] = f2bf(lf[a * 193 + x]);
#pragma unroll
      for (int a = 0; a < 8; a++)  v1[a] = f2bf(lf[(a + 8) * 193 + x]);
    }
    short* dst = baf + (size_t)(b * kN + n) * kD + h * kAFC;
    *(bf16x8*)dst = v0;
    *(bf16x8*)(dst + 8) = v1;
  }
}

// ---------------- transpose baf -> bafT [b][d][n_pad] (zero-pad n>=1000) ----
__global__ __launch_bounds__(256) void k_transpose(const short* __restrict__ baf,
                                                   short* __restrict__ bafT) {
  __shared__ short t[64][66];
  int b = blockIdx.z, n0 = blockIdx.y * 64, d0 = blockIdx.x * 64;
  int c = threadIdx.x & 63, r4 = threadIdx.x >> 6;  // c: 0..63, r4: 0..3
#pragma unroll
  for (int i = 0; i < 16; i++) {
    int nl = r4 + i * 4;
    int n = n0 + nl;
    short v = (n < kN) ? baf[(size_t)(b * kN + n) * kD + d0 + c] : (short)0;
    t[nl][c] = v;
  }
  __syncthreads();
#pragma unroll
  for (int i = 0; i < 16; i++) {
    int dl = r4 + i * 4;
    bafT[((size_t)b * kD + d0 + dl) * kNP + n0 + c] = t[c][dl];
  }
}

// ---- convert attn_w -> bf16 [1024][2560] in d' order (per-row transpose) ---
__global__ __launch_bounds__(256) void k_cvt_attnw(const float* __restrict__ w,
                                                   short* __restrict__ o) {
  __shared__ float lw[kAFC * (kH + 1)];   // 16x161
  int j = blockIdx.x;                      // 0..1023
  short* dst = o + (size_t)j * kD;
  if (j < kNM1) {
    const float* src = w + (size_t)j * kD;
    for (int i = threadIdx.x; i < kD; i += 256) {
      int a = i / kH, h = i % kH;
      lw[a * (kH + 1) + h] = src[i];
    }
    __syncthreads();
    for (int dp = threadIdx.x; dp < kD; dp += 256) {
      int h = dp >> 4, a = dp & 15;
      dst[dp] = f2bf(lw[a * (kH + 1) + h]);
    }
  } else {
    for (int dp = threadIdx.x; dp < kD; dp += 256) dst[dp] = 0;
  }
}

// ---- build head weight bf16 [384][5120], both K-halves in d' order ---------
__global__ __launch_bounds__(256) void k_cvt_whead(const float* __restrict__ reg_w,
                                                   const float* __restrict__ cls_w,
                                                   short* __restrict__ o) {
  __shared__ float lw[2 * kAFC * (kH + 1)];  // 2 x 16 x 161
  int j = blockIdx.x;                        // 0..383
  const float* src = nullptr;
  if (j < 3 * kS)                 src = reg_w + (size_t)j * kK2;
  else if (j < 3 * kS + kNC)      src = cls_w + (size_t)(j - 3 * kS) * kK2;
  short* dst = o + (size_t)j * kK2;
  if (src) {
    for (int i = threadIdx.x; i < kK2; i += 256) {
      int half = i / kD, t = i % kD;
      int a = t / kH, h = t % kH;
      lw[(half * kAFC + a) * (kH + 1) + h] = src[i];
    }
    __syncthreads();
    for (int kp = threadIdx.x; kp < kK2; kp += 256) {
      int half = kp / kD, t = kp % kD;
      int h = t >> 4, a = t & 15;
      dst[kp] = f2bf(lw[(half * kAFC + a) * (kH + 1) + h]);
    }
  } else {
    for (int kp = threadIdx.x; kp < kK2; kp += 256) dst[kp] = 0;
  }
}

// ---------------- softmax: scores -> attn_mat (f32 out) + attn bf16 padded --
__global__ __launch_bounds__(256) void k_softmax(const float* __restrict__ scores,
                                                 const float* __restrict__ anchors,
                                                 float* __restrict__ attn_out,
                                                 short* __restrict__ attn_bf,
                                                 float* __restrict__ rp) {
  int m = blockIdx.x;           // 0..15999
  int b = m / kN;
  int i = m % kN;
  const float* srow = scores + (size_t)m * kNM1;
  int tid = threadIdx.x;
  __shared__ float red[4];
  float v[4];
  float mx = -INFINITY;
#pragma unroll
  for (int t = 0; t < 4; t++) {
    int j = tid + t * 256;
    v[t] = (j < kNM1) ? srow[j] : -INFINITY;
    mx = fmaxf(mx, v[t]);
  }
#pragma unroll
  for (int o = 32; o; o >>= 1) mx = fmaxf(mx, __shfl_down(mx, o));
  if ((tid & 63) == 0) red[tid >> 6] = mx;
  __syncthreads();
  mx = fmaxf(fmaxf(red[0], red[1]), fmaxf(red[2], red[3]));
  __syncthreads();
  float s = 0.f;
#pragma unroll
  for (int t = 0; t < 4; t++) {
    int j = tid + t * 256;
    v[t] = (j < kNM1) ? __expf(v[t] - mx) : 0.f;
    s += v[t];
  }
#pragma unroll
  for (int o = 32; o; o >>= 1) s += __shfl_down(s, o);
  if ((tid & 63) == 0) red[tid >> 6] = s;
  __syncthreads();
  s = red[0] + red[1] + red[2] + red[3];
  float inv = 1.0f / s;
  float* orow = attn_out + (size_t)m * kN;
  short* brow = attn_bf + ((size_t)b * kNP + i) * kNP;
#pragma unroll
  for (int t = 0; t < 4; t++) {
    int j = tid + t * 256;
    if (j < kNM1) {
      int dst = j + (j >= i);
      float p = v[t] * inv;
      orow[dst] = p;
      brow[dst] = f2bf(p);
    }
  }
  if (tid == 0) { orow[i] = 0.f; brow[i] = 0; }
  if (tid < kNP - kN) brow[kN + tid] = 0;           // pad cols 1000..1023
  if (tid < 3) rp[(size_t)m * kRP + 2 + tid] = anchors[(size_t)i * kRP + 2 + tid];
}

// ---------------- MFMA bf16 GEMM, 128x128 tile, BK=32, 2-phase dbuf ---------
// T3-minimum pipeline: STAGE(t+1) issued BEFORE compute(t); single
// __syncthreads per K-step (its vmcnt(0) drain covers t+1's loads with t's
// compute). Manually unrolled x2 so buffer offsets are compile-time.
// MODE 0: scores = baf @ attnw^T (+attn_b), f32 out [16000][999]
//   Chunked XCD swizzle: XCD owns a row stripe of A (read once from HBM).
// MODE 1: attf = attn @ bafT^T, bf16 out [16][1000][2560], batched
//   Two passes of 8 batches: XCD = batch, m fastest inside.
template <int MODE>
__global__ __launch_bounds__(256) void k_mfma_gemm(
    const short* __restrict__ A,
    const short* __restrict__ Bt,
    const float* __restrict__ bias,
    void* __restrict__ Cout, int K, int lda, int ldb) {
  __shared__ short smem[16384];                // 2 bufs x (A 8KB + B 8KB) = 32 KB
  char* base = (char*)smem;
  int tid = threadIdx.x, lane = tid & 63, wv = tid >> 6;
  int bid = blockIdx.x;
  int m0, n0, bz = 0;
  const short* Ap = A;
  const short* Bp = Bt;
  if (MODE == 0) {
    int wgid = (bid & 7) * 125 + (bid >> 3);   // chunked: XCD -> contiguous range
    m0 = (wgid >> 3) * 128; n0 = (wgid & 7) * 128;
  } else {
    int half = bid / 1280;
    int rem  = bid - half * 1280;
    bz = (rem & 7) + 8 * half;                 // XCD = rem&7 = batch (per pass)
    int inner = rem >> 3;                      // 0..159, sequential per XCD
    m0 = (inner & 7) * 128;                    // m fastest
    n0 = (inner >> 3) * 128;                   // d slow
    Ap = A + (size_t)bz * kNP * kNP;
    Bp = Bt + (size_t)bz * kD * kNP;
  }
  int wm = (wv >> 1) * 64, wn = (wv & 1) * 64;
  int sRow = lane >> 2;          // 0..15 row within 16-row chunk
  int sKo  = (lane & 3) * 8;     // k element offset
  f32x4 acc[4][4] = {};

  const short* gaBase = Ap + (size_t)(m0 + 32 * wv + sRow) * lda + sKo;
  const short* gbBase = Bp + (size_t)(n0 + 32 * wv + sRow) * ldb + sKo;

  auto STAGE = [&](int k0, char* bA, char* bB) {
    const short* ga = gaBase + k0;
    GLOAD_LDS16(ga,            bA + wv * 2048);
    GLOAD_LDS16(ga + 16 * lda, bA + wv * 2048 + 1024);
    const short* gb = gbBase + k0;
    GLOAD_LDS16(gb,            bB + wv * 2048);
    GLOAD_LDS16(gb + 16 * ldb, bB + wv * 2048 + 1024);
  };
  auto COMPUTE = [&](const char* bA, const char* bB) {
    bf16x8 af[4], bfg[4];
#pragma unroll
    for (int i = 0; i < 4; i++)
      af[i] = *(const bf16x8*)(bA + ((size_t)(wm + i * 16 + (lane & 15))) * 64 + (lane >> 4) * 16);
#pragma unroll
    for (int j = 0; j < 4; j++)
      bfg[j] = *(const bf16x8*)(bB + ((size_t)(wn + j * 16 + (lane & 15))) * 64 + (lane >> 4) * 16);
#pragma unroll
    for (int i = 0; i < 4; i++)
#pragma unroll
      for (int j = 0; j < 4; j++)
        acc[i][j] = __builtin_amdgcn_mfma_f32_16x16x32_bf16(af[i], bfg[j], acc[i][j], 0, 0, 0);
  };

  char* A0 = base;          char* B0 = base + 8192;
  char* A1 = base + 16384;  char* B1 = base + 24576;

  STAGE(0, A0, B0);
  __syncthreads();
  int NT = K / 32;                 // 80 (MODE0) / 32 (MODE1) — always even
  for (int t = 0; t < NT; t += 2) {
    if (t + 1 < NT) STAGE((t + 1) * 32, A1, B1);
    COMPUTE(A0, B0);
    __syncthreads();
    if (t + 2 < NT) STAGE((t + 2) * 32, A0, B0);
    COMPUTE(A1, B1);
    __syncthreads();
  }

  // epilogue
#pragma unroll
  for (int i = 0; i < 4; i++) {
#pragma unroll
    for (int j = 0; j < 4; j++) {
#pragma unroll
      for (int r = 0; r < 4; r++) {
        int row = m0 + wm + i * 16 + (lane >> 4) * 4 + r;
        int col = n0 + wn + j * 16 + (lane & 15);
        float v = acc[i][j][r];
        if (MODE == 0) {
          if (col < kNM1)
            ((float*)Cout)[(size_t)row * kNM1 + col] = v + bias[col];
        } else {
          if (row < kN)
            ((short*)Cout)[((size_t)bz * kN + row) * kD + col] = f2bf(v);
        }
      }
    }
  }
}

// ---------------- head GEMM split-K: BM=64, BN=384, 4 K-chunks --------------
// part[ks][16000][384] (bf16) = [attf|baf](rows, Kchunk) @ whead^T(:, Kchunk)
__global__ __launch_bounds__(256) void k_head_sk(
    const short* __restrict__ A,   // attf [16000][2560]
    const short* __restrict__ A2,  // baf  [16000][2560]
    const short* __restrict__ Bt,  // whead [384][5120]
    short* __restrict__ part) {
  __shared__ short smem[14336];    // A 4KB + B 24KB, single buffer
  char* sA = (char*)smem;
  char* sB = (char*)smem + 4096;
  int tid = threadIdx.x, lane = tid & 63, wv = tid >> 6;
  int bid = blockIdx.x;
  int ks = bid / (kM / 64);        // K-chunk slow: m-tiles sharing a B-slice adjacent
  int mt = bid % (kM / 64);
  int m0 = mt * 64;
  int kbase = ks * (kK2 / kKS);    // 1280
  int sRow = lane >> 2, sKo = (lane & 3) * 8;
  f32x4 acc[4][6] = {};

  for (int t = 0; t < (kK2 / kKS) / 32; t++) {   // 40 steps
    int k0 = kbase + t * 32;
    const short* Abase = A; int kk = k0;
    if (k0 >= kD) { Abase = A2; kk = k0 - kD; }
    GLOAD_LDS16(Abase + (size_t)(m0 + wv * 16 + sRow) * kD + kk + sKo, sA + wv * 1024);
#pragma unroll
    for (int g = 0; g < 6; g++)
      GLOAD_LDS16(Bt + (size_t)(g * 64 + wv * 16 + sRow) * kK2 + k0 + sKo,
                  sB + g * 4096 + wv * 1024);
    __syncthreads();

    bf16x8 af[4], bfr[6];
#pragma unroll
    for (int i = 0; i < 4; i++)
      af[i] = *(const bf16x8*)(sA + (i * 16 + (lane & 15)) * 64 + (lane >> 4) * 16);
#pragma unroll
    for (int j = 0; j < 6; j++)
      bfr[j] = *(const bf16x8*)(sB + (wv * 96 + j * 16 + (lane & 15)) * 64 + (lane >> 4) * 16);
#pragma unroll
    for (int i = 0; i < 4; i++)
#pragma unroll
      for (int j = 0; j < 6; j++)
        acc[i][j] = __builtin_amdgcn_mfma_f32_16x16x32_bf16(af[i], bfr[j], acc[i][j], 0, 0, 0);
    __syncthreads();
  }

  short* pbase = part + (size_t)ks * kM * 384;
#pragma unroll
  for (int i = 0; i < 4; i++) {
#pragma unroll
    for (int j = 0; j < 6; j++) {
#pragma unroll
      for (int r = 0; r < 4; r++) {
        int row = m0 + i * 16 + (lane >> 4) * 4 + r;
        int col = wv * 96 + j * 16 + (lane & 15);
        pbase[(size_t)row * 384 + col] = f2bf(acc[i][j][r]);
      }
    }
  }
}

// ---------------- head reduce: sum 4 bf16 partials + epilogue -> rp ---------
__global__ __launch_bounds__(256) void k_head_reduce(
    const short* __restrict__ part,
    const float* __restrict__ reg_b, const float* __restrict__ cls_b,
    const float* __restrict__ anchors, float* __restrict__ rp) {
  int idx = blockIdx.x * 256 + threadIdx.x;
  if (idx >= kM * 384) return;
  int row = idx / 384, col = idx % 384;
  size_t stride = (size_t)kM * 384;
  float v = bf2f(part[idx]) + bf2f(part[stride + idx]) +
            bf2f(part[2 * stride + idx]) + bf2f(part[3 * stride + idx]);
  int n = row % kN;
  if (col < 3 * kS) {
    float tv = v + reg_b[col];
    if (col >= 2 * kS) tv = 1.0f / (1.0f + __expf(-tv));
    rp[(size_t)row * kRP + 5 + col] = anchors[(size_t)n * kRP + 5 + col] + tv;
  } else if (col < 3 * kS + kNC) {
    rp[(size_t)row * kRP + (col - 3 * kS)] = v + cls_b[col - 3 * kS];
  }
}

extern "C" void kernel_launch(void* const* d_in, const int* in_sizes, int n_in,
                              void* d_out, int out_size, void* d_ws, size_t ws_size,
                              hipStream_t stream) {
  const float* bf      = (const float*)d_in[0];
  const float* conv_w  = (const float*)d_in[1];
  const float* conv_b  = (const float*)d_in[2];
  const int*   cut     = (const int*)d_in[3];
  const void*  mask    = d_in[4];
  const float* anchors = (const float*)d_in[5];
  const float* attn_w  = (const float*)d_in[6];
  const float* attn_b  = (const float*)d_in[7];
  const float* cls_w   = (const float*)d_in[8];
  const float* cls_b   = (const float*)d_in[9];
  const float* reg_w   = (const float*)d_in[10];
  const float* reg_b   = (const float*)d_in[11];

  float* out    = (float*)d_out;
  float* rp     = out + OFF_RP;
  float* attn_o = out + OFF_ATTN;
  float* feats  = out + OFF_FEAT;

  char*  ws      = (char*)d_ws;
  short* baf     = (short*)(ws + WB_BAF);
  short* bafT    = (short*)(ws + WB_BAFT);
  short* attf    = (short*)(ws + WB_ATTF);
  short* attnw   = (short*)(ws + WB_ATTNW);
  short* whead   = (short*)(ws + WB_WHEAD);
  short* attn_bf = (short*)(ws + WB_ATTNB);
  float* scores  = (float*)(ws + WB_SCORE);
  short* part    = (short*)(ws + WB_PART);
  int*   flag    = (int*)(ws + WB_FLAG);

  k_detect<<<1, 256, 0, stream>>>((const unsigned char*)mask, flag);
  k_conv<<<(kB * kHW) / 256, 256, 0, stream>>>(bf, conv_w, conv_b, feats);
  // gather: one block per (b,h); 2560 blocks
  k_gather<<<kB * kH, 256, 0, stream>>>(feats, cut, mask, flag, baf);
  {
    dim3 g(kD / 64, 16, kB);  // d-tiles, n-tiles, batch
    k_transpose<<<g, 256, 0, stream>>>(baf, bafT);
  }
  k_cvt_attnw<<<kNP, 256, 0, stream>>>(attn_w, attnw);
  k_cvt_whead<<<384, 256, 0, stream>>>(reg_w, cls_w, whead);
  // scores GEMM: 1000 blocks, chunked XCD swizzle (row-stripe per XCD)
  k_mfma_gemm<0><<<kM / 128 * 8, 256, 0, stream>>>(baf, attnw, attn_b, scores,
                                                   kD, kD, kD);
  k_softmax<<<kM, 256, 0, stream>>>(scores, anchors, attn_o, attn_bf, rp);
  // att GEMM: 2560 blocks; two passes of 8 batches, XCD=batch, m fastest
  k_mfma_gemm<1><<<kB * 8 * 20, 256, 0, stream>>>(attn_bf, bafT, nullptr, attf,
                                                  kNP, kNP, kNP);
  // head GEMM split-K + reduce (bf16 partials)
  k_head_sk<<<kKS * (kM / 64), 256, 0, stream>>>(attf, baf, whead, part);
  k_head_reduce<<<(kM * 384) / 256, 256, 0, stream>>>(part, reg_b, cls_b,
                                                      anchors, rp);
}

// Round 9
// 599.232 us; speedup vs baseline: 1.3460x; 1.0522x over previous
//
#include <hip/hip_runtime.h>
#include <cmath>

// Problem constants
static constexpr int kB   = 16;
static constexpr int kC   = 64;
static constexpr int kH   = 160;
static constexpr int kW   = 192;
static constexpr int kN   = 1000;
static constexpr int kAFC = 16;
static constexpr int kS   = 96;
static constexpr int kNC  = 2;
static constexpr int kD   = kAFC * kH;     // 2560
static constexpr int kHW  = kH * kW;       // 30720
static constexpr int kNM1 = kN - 1;        // 999
static constexpr int kM   = kB * kN;       // 16000
static constexpr int kRP  = kNC + 3 + 3 * kS; // 293
static constexpr int kK2  = 2 * kD;        // 5120
static constexpr int kNP  = 1024;          // padded N for att GEMM
static constexpr int kKS  = 4;             // split-K factor for head GEMM

// Internal feature ordering is d' = h*16 + a (h-major); all internal tensors
// and repacked weights use d' consistently.

// d_out layout (floats)
static constexpr size_t OFF_RP   = 0;
static constexpr size_t OFF_ATTN = (size_t)kB * kN * kRP;
static constexpr size_t OFF_FEAT = OFF_ATTN + (size_t)kB * kN * kN;

// ws layout (bytes)
static constexpr size_t WB_BAF   = 0;                                    // bf16 [16000][2560]
static constexpr size_t WB_BAFT  = WB_BAF   + (size_t)kM * kD * 2;       // bf16 [16][2560][1024]
static constexpr size_t WB_ATTF  = WB_BAFT  + (size_t)kB * kD * kNP * 2; // bf16 [16000][2560]
static constexpr size_t WB_ATTNW = WB_ATTF  + (size_t)kM * kD * 2;       // bf16 [1024][2560]
static constexpr size_t WB_WHEAD = WB_ATTNW + (size_t)kNP * kD * 2;      // bf16 [384][5120]
static constexpr size_t WB_ATTNB = WB_WHEAD + (size_t)384 * kK2 * 2;     // bf16 [16][1024][1024]
static constexpr size_t WB_SCORE = WB_ATTNB + (size_t)kB * kNP * kNP * 2;// f32  [16000][999]
// PART overlays ATTNB+SCORE (both dead by the time head GEMM runs)
static constexpr size_t WB_PART  = WB_ATTNB;                             // bf16 [4][16000][384]
static constexpr size_t WB_FLAG  = WB_PART + (size_t)kKS * kM * 384 * 2; // int

typedef __attribute__((ext_vector_type(8))) short bf16x8;
typedef __attribute__((ext_vector_type(4))) float f32x4;

static __device__ inline short f2bf(float f) {
  union { float f; unsigned u; } x; x.f = f;
  unsigned r = (x.u + 0x7FFFu + ((x.u >> 16) & 1u)) >> 16;
  return (short)r;
}
static __device__ inline float bf2f(short s) {
  union { unsigned u; float f; } x; x.u = ((unsigned)(unsigned short)s) << 16;
  return x.f;
}

#define GLOAD_LDS16(gp, lp) __builtin_amdgcn_global_load_lds( \
    (const __attribute__((address_space(1))) void*)(gp),      \
    (__attribute__((address_space(3))) void*)(lp), 16, 0, 0)

// ---------------- mask dtype detection ----------------
__global__ void k_detect(const unsigned char* __restrict__ m, int* __restrict__ flag) {
  __shared__ int c1, c2, c3;
  if (threadIdx.x == 0) { c1 = 0; c2 = 0; c3 = 0; }
  __syncthreads();
  int l1 = 0, l2 = 0, l3 = 0;
  for (int g = threadIdx.x; g < (kN * kH) / 4; g += blockDim.x) {
    l1 += (m[4 * g + 1] != 0);
    l2 += (m[4 * g + 2] != 0);
    l3 += (m[4 * g + 3] != 0);
  }
  atomicAdd(&c1, l1); atomicAdd(&c2, l2); atomicAdd(&c3, l3);
  __syncthreads();
  if (threadIdx.x == 0) {
    int f;
    if (c1 > 0)            f = 1;  // uint8 bools
    else if (c2 | c3)      f = 2;  // float32 bools
    else                   f = 0;  // int32 bools
    *flag = f;
  }
}

// ---------------- 1x1 conv (fp32, feats is an output) ----------------
__global__ __launch_bounds__(256) void k_conv(const float* __restrict__ bf,
                                              const float* __restrict__ cw,
                                              const float* __restrict__ cb,
                                              float* __restrict__ feats) {
  __shared__ float w[kAFC * kC];
  __shared__ float bsh[kAFC];
  for (int i = threadIdx.x; i < kAFC * kC; i += 256) w[i] = cw[i];
  if (threadIdx.x < kAFC) bsh[threadIdx.x] = cb[threadIdx.x];
  __syncthreads();
  int idx = blockIdx.x * 256 + threadIdx.x;
  if (idx >= kB * kHW) return;
  int b = idx / kHW, p = idx % kHW;
  float acc[kAFC];
#pragma unroll
  for (int o = 0; o < kAFC; o++) acc[o] = bsh[o];
  const float* src = bf + (size_t)b * kC * kHW + p;
#pragma unroll 4
  for (int c = 0; c < kC; c++) {
    float v = src[(size_t)c * kHW];
#pragma unroll
    for (int o = 0; o < kAFC; o++) acc[o] += v * w[o * kC + c];
  }
  float* dst = feats + (size_t)b * kAFC * kHW + p;
#pragma unroll
  for (int o = 0; o < kAFC; o++) dst[(size_t)o * kHW] = acc[o];
}

// ---------------- gather rois -> baf (bf16, d'=h*16+a layout) ---------------
__global__ __launch_bounds__(256) void k_gather(const float* __restrict__ feats,
                                                const int* __restrict__ cut,
                                                const void* __restrict__ mask,
                                                const int* __restrict__ flag,
                                                short* __restrict__ baf) {
  __shared__ float lf[kAFC * 193];   // pad 192->193 to rotate banks per a
  int bid = blockIdx.x;
  int b = bid & 15, h = bid >> 4;
  const float* fbase = feats + (size_t)b * kAFC * kHW + (size_t)h * kW;
  for (int i = threadIdx.x; i < kAFC * kW; i += 256) {
    int a = i / kW, x = i % kW;
    lf[a * 193 + x] = fbase[(size_t)a * kHW + x];
  }
  __syncthreads();
  int f = *flag;
  for (int n = threadIdx.x; n < kN; n += 256) {
    int r = n * kH + h;
    bool inv;
    if (f == 0)      inv = ((const int*)mask)[r] != 0;
    else if (f == 1) inv = ((const unsigned char*)mask)[r] != 0;
    else             inv = ((const float*)mask)[r] != 0.0f;
    bf16x8 v0 = {}, v1 = {};
    if (!inv) {
      int x = cut[r];
#pragma unroll
      for (int a = 0; a < 8; a++)  v0[a] = f2bf(lf[a * 193 + x]);
#pragma unroll
      for (int a = 0; a < 8; a++)  v1[a] = f2bf(lf[(a + 8) * 193 + x]);
    }
    short* dst = baf + (size_t)(b * kN + n) * kD + h * kAFC;
    *(bf16x8*)dst = v0;
    *(bf16x8*)(dst + 8) = v1;
  }
}

// ---------------- transpose baf -> bafT [b][d][n_pad] (zero-pad n>=1000) ----
__global__ __launch_bounds__(256) void k_transpose(const short* __restrict__ baf,
                                                   short* __restrict__ bafT) {
  __shared__ short t[64][66];
  int b = blockIdx.z, n0 = blockIdx.y * 64, d0 = blockIdx.x * 64;
  int c = threadIdx.x & 63, r4 = threadIdx.x >> 6;  // c: 0..63, r4: 0..3
#pragma unroll
  for (int i = 0; i < 16; i++) {
    int nl = r4 + i * 4;
    int n = n0 + nl;
    short v = (n < kN) ? baf[(size_t)(b * kN + n) * kD + d0 + c] : (short)0;
    t[nl][c] = v;
  }
  __syncthreads();
#pragma unroll
  for (int i = 0; i < 16; i++) {
    int dl = r4 + i * 4;
    bafT[((size_t)b * kD + d0 + dl) * kNP + n0 + c] = t[c][dl];
  }
}

// ---- convert attn_w -> bf16 [1024][2560] in d' order (per-row transpose) ---
__global__ __launch_bounds__(256) void k_cvt_attnw(const float* __restrict__ w,
                                                   short* __restrict__ o) {
  __shared__ float lw[kAFC * (kH + 1)];   // 16x161
  int j = blockIdx.x;                      // 0..1023
  short* dst = o + (size_t)j * kD;
  if (j < kNM1) {
    const float* src = w + (size_t)j * kD;
    for (int i = threadIdx.x; i < kD; i += 256) {
      int a = i / kH, h = i % kH;
      lw[a * (kH + 1) + h] = src[i];
    }
    __syncthreads();
    for (int dp = threadIdx.x; dp < kD; dp += 256) {
      int h = dp >> 4, a = dp & 15;
      dst[dp] = f2bf(lw[a * (kH + 1) + h]);
    }
  } else {
    for (int dp = threadIdx.x; dp < kD; dp += 256) dst[dp] = 0;
  }
}

// ---- build head weight bf16 [384][5120], both K-halves in d' order ---------
__global__ __launch_bounds__(256) void k_cvt_whead(const float* __restrict__ reg_w,
                                                   const float* __restrict__ cls_w,
                                                   short* __restrict__ o) {
  __shared__ float lw[2 * kAFC * (kH + 1)];  // 2 x 16 x 161
  int j = blockIdx.x;                        // 0..383
  const float* src = nullptr;
  if (j < 3 * kS)                 src = reg_w + (size_t)j * kK2;
  else if (j < 3 * kS + kNC)      src = cls_w + (size_t)(j - 3 * kS) * kK2;
  short* dst = o + (size_t)j * kK2;
  if (src) {
    for (int i = threadIdx.x; i < kK2; i += 256) {
      int half = i / kD, t = i % kD;
      int a = t / kH, h = t % kH;
      lw[(half * kAFC + a) * (kH + 1) + h] = src[i];
    }
    __syncthreads();
    for (int kp = threadIdx.x; kp < kK2; kp += 256) {
      int half = kp / kD, t = kp % kD;
      int h = t >> 4, a = t & 15;
      dst[kp] = f2bf(lw[(half * kAFC + a) * (kH + 1) + h]);
    }
  } else {
    for (int kp = threadIdx.x; kp < kK2; kp += 256) dst[kp] = 0;
  }
}

// ---------------- softmax: scores -> attn_mat (f32 out) + attn bf16 padded --
__global__ __launch_bounds__(256) void k_softmax(const float* __restrict__ scores,
                                                 const float* __restrict__ anchors,
                                                 float* __restrict__ attn_out,
                                                 short* __restrict__ attn_bf,
                                                 float* __restrict__ rp) {
  int m = blockIdx.x;           // 0..15999
  int b = m / kN;
  int i = m % kN;
  const float* srow = scores + (size_t)m * kNM1;
  int tid = threadIdx.x;
  __shared__ float red[4];
  float v[4];
  float mx = -INFINITY;
#pragma unroll
  for (int t = 0; t < 4; t++) {
    int j = tid + t * 256;
    v[t] = (j < kNM1) ? srow[j] : -INFINITY;
    mx = fmaxf(mx, v[t]);
  }
#pragma unroll
  for (int o = 32; o; o >>= 1) mx = fmaxf(mx, __shfl_down(mx, o));
  if ((tid & 63) == 0) red[tid >> 6] = mx;
  __syncthreads();
  mx = fmaxf(fmaxf(red[0], red[1]), fmaxf(red[2], red[3]));
  __syncthreads();
  float s = 0.f;
#pragma unroll
  for (int t = 0; t < 4; t++) {
    int j = tid + t * 256;
    v[t] = (j < kNM1) ? __expf(v[t] - mx) : 0.f;
    s += v[t];
  }
#pragma unroll
  for (int o = 32; o; o >>= 1) s += __shfl_down(s, o);
  if ((tid & 63) == 0) red[tid >> 6] = s;
  __syncthreads();
  s = red[0] + red[1] + red[2] + red[3];
  float inv = 1.0f / s;
  float* orow = attn_out + (size_t)m * kN;
  short* brow = attn_bf + ((size_t)b * kNP + i) * kNP;
#pragma unroll
  for (int t = 0; t < 4; t++) {
    int j = tid + t * 256;
    if (j < kNM1) {
      int dst = j + (j >= i);
      float p = v[t] * inv;
      orow[dst] = p;
      brow[dst] = f2bf(p);
    }
  }
  if (tid == 0) { orow[i] = 0.f; brow[i] = 0; }
  if (tid < kNP - kN) brow[kN + tid] = 0;           // pad cols 1000..1023
  if (tid < 3) rp[(size_t)m * kRP + 2 + tid] = anchors[(size_t)i * kRP + 2 + tid];
}

// ---------------- MFMA bf16 GEMM: 256x256 tile, BK=32, 8 waves --------------
// Counted-vmcnt ring pipeline (T3/T4): 4-deep LDS ring (4 x 32KB), one raw
// s_barrier per K-step, vmcnt(8) in steady state (stage t landed; t+1,t+2
// in flight; 4 gloads/thread/stage). Hazards: (a) "buf t ready" = each wave's
// vmcnt precedes its barrier; (b) STAGE(t+3) overwrites buf[(t-1)&3], whose
// ds_reads were consumed by MFMAs before the barrier. sched_barrier(0) after
// the barrier pins both (rule 18-adjacent: no hoisting across raw s_barrier).
// MODE 0: scores = baf @ attnw^T (+attn_b), f32 out [16000][999]
//   grid 256: xcd=bid&7 owns m-tiles [8x,8x+8) exclusively; M padded to 16384
//   via per-lane source clamp + epilogue guard.
// MODE 1: attf = attn_bf @ bafT^T, bf16 out [16][1000][2560]
//   grid 640: XCD = batch (two passes of 8), m fastest inside.
template <int MODE>
__global__ __launch_bounds__(512, 2) void k_gemm8(
    const short* __restrict__ A,
    const short* __restrict__ Bt,
    const float* __restrict__ bias,
    void* __restrict__ Cout) {
  extern __shared__ char dls[];                // 128 KB: 4 bufs x (A 16K + B 16K)
  constexpr int K   = (MODE == 0) ? kD : kNP;  // 2560 / 1024
  constexpr int NT  = K / 32;                  // 80 / 32
  constexpr int lda = (MODE == 0) ? kD : kNP;
  constexpr int ldb = (MODE == 0) ? kD : kNP;
  int tid = threadIdx.x, lane = tid & 63, wv = tid >> 6;
  int bid = blockIdx.x;
  int m0, n0, bz = 0;
  const short* Ap = A;
  const short* Bp = Bt;
  if (MODE == 0) {
    int xcd = bid & 7, s = bid >> 3;
    m0 = (xcd * 8 + (s & 7)) * 256;            // 0..16128
    n0 = (s >> 3) * 256;                       // 0..768
  } else {
    int half = bid / 320, rem = bid % 320;
    bz = (rem & 7) + 8 * half;
    int inner = rem >> 3;                      // 0..39
    m0 = (inner & 3) * 256;                    // m fastest
    n0 = (inner >> 2) * 256;
    Ap = A + (size_t)bz * kNP * kNP;
    Bp = Bt + (size_t)bz * kD * kNP;
  }
  int wm = (wv & 1) * 128, wn = (wv >> 1) * 64;
  f32x4 acc[8][4] = {};

  // per-thread staging geometry: chunk ci in [0,1024) per operand, 2 per thread
  int r0  = tid >> 2;            // ci row for g=0 (ci = tid)
  int r1  = (512 + tid) >> 2;    // row for g=1
  int ko  = (tid & 3) * 8;       // k element offset within BK=32
  int ar0 = (MODE == 0) ? min(m0 + r0, kM - 1) : (m0 + r0);
  int ar1 = (MODE == 0) ? min(m0 + r1, kM - 1) : (m0 + r1);
  const short* gA0 = Ap + (size_t)ar0 * lda + ko;
  const short* gA1 = Ap + (size_t)ar1 * lda + ko;
  const short* gB0 = Bp + (size_t)(n0 + r0) * ldb + ko;
  const short* gB1 = Bp + (size_t)(n0 + r1) * ldb + ko;

  auto STAGE = [&](int tt) {
    char* buf = dls + (size_t)(tt & 3) * 32768;
    int k0 = tt * 32;
    GLOAD_LDS16(gA0 + k0, buf + wv * 1024);
    GLOAD_LDS16(gA1 + k0, buf + 8192 + wv * 1024);
    GLOAD_LDS16(gB0 + k0, buf + 16384 + wv * 1024);
    GLOAD_LDS16(gB1 + k0, buf + 24576 + wv * 1024);
  };

  STAGE(0); STAGE(1); STAGE(2);
  for (int t = 0; t < NT; t++) {
    if (t < NT - 2)       asm volatile("s_waitcnt vmcnt(8)" ::: "memory");
    else if (t == NT - 2) asm volatile("s_waitcnt vmcnt(4)" ::: "memory");
    else                  asm volatile("s_waitcnt vmcnt(0)" ::: "memory");
    __builtin_amdgcn_s_barrier();
    __builtin_amdgcn_sched_barrier(0);
    if (t + 3 < NT) STAGE(t + 3);
    const char* bufA = dls + (size_t)(t & 3) * 32768;
    const char* bufB = bufA + 16384;
    bf16x8 af[8], bg[4];
#pragma unroll
    for (int i = 0; i < 8; i++)
      af[i] = *(const bf16x8*)(bufA + (wm + i * 16 + (lane & 15)) * 64 + (lane >> 4) * 16);
#pragma unroll
    for (int j = 0; j < 4; j++)
      bg[j] = *(const bf16x8*)(bufB + (wn + j * 16 + (lane & 15)) * 64 + (lane >> 4) * 16);
#pragma unroll
    for (int i = 0; i < 8; i++)
#pragma unroll
      for (int j = 0; j < 4; j++)
        acc[i][j] = __builtin_amdgcn_mfma_f32_16x16x32_bf16(af[i], bg[j], acc[i][j], 0, 0, 0);
  }

  // epilogue
#pragma unroll
  for (int i = 0; i < 8; i++) {
#pragma unroll
    for (int j = 0; j < 4; j++) {
#pragma unroll
      for (int r = 0; r < 4; r++) {
        int row = m0 + wm + i * 16 + (lane >> 4) * 4 + r;
        int col = n0 + wn + j * 16 + (lane & 15);
        float v = acc[i][j][r];
        if (MODE == 0) {
          if (row < kM && col < kNM1)
            ((float*)Cout)[(size_t)row * kNM1 + col] = v + bias[col];
        } else {
          if (row < kN)
            ((short*)Cout)[((size_t)bz * kN + row) * kD + col] = f2bf(v);
        }
      }
    }
  }
}

// ---------------- head GEMM split-K: BM=64, BN=384, 4 K-chunks --------------
// part[ks][16000][384] (bf16) = [attf|baf](rows, Kchunk) @ whead^T(:, Kchunk)
__global__ __launch_bounds__(256) void k_head_sk(
    const short* __restrict__ A,   // attf [16000][2560]
    const short* __restrict__ A2,  // baf  [16000][2560]
    const short* __restrict__ Bt,  // whead [384][5120]
    short* __restrict__ part) {
  __shared__ short smem[14336];    // A 4KB + B 24KB, single buffer
  char* sA = (char*)smem;
  char* sB = (char*)smem + 4096;
  int tid = threadIdx.x, lane = tid & 63, wv = tid >> 6;
  int bid = blockIdx.x;
  int ks = bid / (kM / 64);        // K-chunk slow: m-tiles sharing a B-slice adjacent
  int mt = bid % (kM / 64);
  int m0 = mt * 64;
  int kbase = ks * (kK2 / kKS);    // 1280
  int sRow = lane >> 2, sKo = (lane & 3) * 8;
  f32x4 acc[4][6] = {};

  for (int t = 0; t < (kK2 / kKS) / 32; t++) {   // 40 steps
    int k0 = kbase + t * 32;
    const short* Abase = A; int kk = k0;
    if (k0 >= kD) { Abase = A2; kk = k0 - kD; }
    GLOAD_LDS16(Abase + (size_t)(m0 + wv * 16 + sRow) * kD + kk + sKo, sA + wv * 1024);
#pragma unroll
    for (int g = 0; g < 6; g++)
      GLOAD_LDS16(Bt + (size_t)(g * 64 + wv * 16 + sRow) * kK2 + k0 + sKo,
                  sB + g * 4096 + wv * 1024);
    __syncthreads();

    bf16x8 af[4], bfr[6];
#pragma unroll
    for (int i = 0; i < 4; i++)
      af[i] = *(const bf16x8*)(sA + (i * 16 + (lane & 15)) * 64 + (lane >> 4) * 16);
#pragma unroll
    for (int j = 0; j < 6; j++)
      bfr[j] = *(const bf16x8*)(sB + (wv * 96 + j * 16 + (lane & 15)) * 64 + (lane >> 4) * 16);
#pragma unroll
    for (int i = 0; i < 4; i++)
#pragma unroll
      for (int j = 0; j < 6; j++)
        acc[i][j] = __builtin_amdgcn_mfma_f32_16x16x32_bf16(af[i], bfr[j], acc[i][j], 0, 0, 0);
    __syncthreads();
  }

  short* pbase = part + (size_t)ks * kM * 384;
#pragma unroll
  for (int i = 0; i < 4; i++) {
#pragma unroll
    for (int j = 0; j < 6; j++) {
#pragma unroll
      for (int r = 0; r < 4; r++) {
        int row = m0 + i * 16 + (lane >> 4) * 4 + r;
        int col = wv * 96 + j * 16 + (lane & 15);
        pbase[(size_t)row * 384 + col] = f2bf(acc[i][j][r]);
      }
    }
  }
}

// ---------------- head reduce: sum 4 bf16 partials + epilogue -> rp ---------
__global__ __launch_bounds__(256) void k_head_reduce(
    const short* __restrict__ part,
    const float* __restrict__ reg_b, const float* __restrict__ cls_b,
    const float* __restrict__ anchors, float* __restrict__ rp) {
  int idx = blockIdx.x * 256 + threadIdx.x;
  if (idx >= kM * 384) return;
  int row = idx / 384, col = idx % 384;
  size_t stride = (size_t)kM * 384;
  float v = bf2f(part[idx]) + bf2f(part[stride + idx]) +
            bf2f(part[2 * stride + idx]) + bf2f(part[3 * stride + idx]);
  int n = row % kN;
  if (col < 3 * kS) {
    float tv = v + reg_b[col];
    if (col >= 2 * kS) tv = 1.0f / (1.0f + __expf(-tv));
    rp[(size_t)row * kRP + 5 + col] = anchors[(size_t)n * kRP + 5 + col] + tv;
  } else if (col < 3 * kS + kNC) {
    rp[(size_t)row * kRP + (col - 3 * kS)] = v + cls_b[col - 3 * kS];
  }
}

extern "C" void kernel_launch(void* const* d_in, const int* in_sizes, int n_in,
                              void* d_out, int out_size, void* d_ws, size_t ws_size,
                              hipStream_t stream) {
  const float* bf      = (const float*)d_in[0];
  const float* conv_w  = (const float*)d_in[1];
  const float* conv_b  = (const float*)d_in[2];
  const int*   cut     = (const int*)d_in[3];
  const void*  mask    = d_in[4];
  const float* anchors = (const float*)d_in[5];
  const float* attn_w  = (const float*)d_in[6];
  const float* attn_b  = (const float*)d_in[7];
  const float* cls_w   = (const float*)d_in[8];
  const float* cls_b   = (const float*)d_in[9];
  const float* reg_w   = (const float*)d_in[10];
  const float* reg_b   = (const float*)d_in[11];

  float* out    = (float*)d_out;
  float* rp     = out + OFF_RP;
  float* attn_o = out + OFF_ATTN;
  float* feats  = out + OFF_FEAT;

  char*  ws      = (char*)d_ws;
  short* baf     = (short*)(ws + WB_BAF);
  short* bafT    = (short*)(ws + WB_BAFT);
  short* attf    = (short*)(ws + WB_ATTF);
  short* attnw   = (short*)(ws + WB_ATTNW);
  short* whead   = (short*)(ws + WB_WHEAD);
  short* attn_bf = (short*)(ws + WB_ATTNB);
  float* scores  = (float*)(ws + WB_SCORE);
  short* part    = (short*)(ws + WB_PART);
  int*   flag    = (int*)(ws + WB_FLAG);

  k_detect<<<1, 256, 0, stream>>>((const unsigned char*)mask, flag);
  k_conv<<<(kB * kHW) / 256, 256, 0, stream>>>(bf, conv_w, conv_b, feats);
  // gather: one block per (b,h); 2560 blocks
  k_gather<<<kB * kH, 256, 0, stream>>>(feats, cut, mask, flag, baf);
  {
    dim3 g(kD / 64, 16, kB);  // d-tiles, n-tiles, batch
    k_transpose<<<g, 256, 0, stream>>>(baf, bafT);
  }
  k_cvt_attnw<<<kNP, 256, 0, stream>>>(attn_w, attnw);
  k_cvt_whead<<<384, 256, 0, stream>>>(reg_w, cls_w, whead);
  // scores GEMM: 256 blocks (64 m-tiles x 4 n-tiles, XCD owns 8 m-tiles)
  k_gemm8<0><<<256, 512, 131072, stream>>>(baf, attnw, attn_b, scores);
  k_softmax<<<kM, 256, 0, stream>>>(scores, anchors, attn_o, attn_bf, rp);
  // att GEMM: 640 blocks (16 b x 4 m x 10 n; XCD = batch, two passes)
  k_gemm8<1><<<640, 512, 131072, stream>>>(attn_bf, bafT, nullptr, attf);
  // head GEMM split-K + reduce (bf16 partials)
  k_head_sk<<<kKS * (kM / 64), 256, 0, stream>>>(attf, baf, whead, part);
  k_head_reduce<<<(kM * 384) / 256, 256, 0, stream>>>(part, reg_b, cls_b,
                                                      anchors, rp);
}

// Round 10
// 573.134 us; speedup vs baseline: 1.4073x; 1.0455x over previous
//
#include <hip/hip_runtime.h>
#include <cmath>

// Problem constants
static constexpr int kB   = 16;
static constexpr int kC   = 64;
static constexpr int kH   = 160;
static constexpr int kW   = 192;
static constexpr int kN   = 1000;
static constexpr int kAFC = 16;
static constexpr int kS   = 96;
static constexpr int kNC  = 2;
static constexpr int kD   = kAFC * kH;     // 2560
static constexpr int kHW  = kH * kW;       // 30720
static constexpr int kNM1 = kN - 1;        // 999
static constexpr int kM   = kB * kN;       // 16000
static constexpr int kRP  = kNC + 3 + 3 * kS; // 293
static constexpr int kK2  = 2 * kD;        // 5120
static constexpr int kNP  = 1024;          // padded N for att GEMM
static constexpr int kKS  = 4;             // split-K factor for head GEMM

// Internal feature ordering is d' = h*16 + a (h-major); all internal tensors
// and repacked weights use d' consistently.

// d_out layout (floats)
static constexpr size_t OFF_RP   = 0;
static constexpr size_t OFF_ATTN = (size_t)kB * kN * kRP;
static constexpr size_t OFF_FEAT = OFF_ATTN + (size_t)kB * kN * kN;

// ws layout (bytes)
static constexpr size_t WB_BAF   = 0;                                    // bf16 [16000][2560]
static constexpr size_t WB_BAFT  = WB_BAF   + (size_t)kM * kD * 2;       // bf16 [16][2560][1024]
static constexpr size_t WB_ATTF  = WB_BAFT  + (size_t)kB * kD * kNP * 2; // bf16 [16000][2560]
static constexpr size_t WB_ATTNW = WB_ATTF  + (size_t)kM * kD * 2;       // bf16 [1024][2560]
static constexpr size_t WB_WHEAD = WB_ATTNW + (size_t)kNP * kD * 2;      // bf16 [384][5120]
static constexpr size_t WB_ATTNB = WB_WHEAD + (size_t)384 * kK2 * 2;     // bf16 [16][1024][1024]
static constexpr size_t WB_SCORE = WB_ATTNB + (size_t)kB * kNP * kNP * 2;// f32  [16000][999]
// PART overlays ATTNB+SCORE (both dead by the time head GEMM runs)
static constexpr size_t WB_PART  = WB_ATTNB;                             // bf16 [4][16000][384]
static constexpr size_t WB_FLAG  = WB_PART + (size_t)kKS * kM * 384 * 2; // int

typedef __attribute__((ext_vector_type(8))) short bf16x8;
typedef __attribute__((ext_vector_type(4))) float f32x4;

static __device__ inline short f2bf(float f) {
  union { float f; unsigned u; } x; x.f = f;
  unsigned r = (x.u + 0x7FFFu + ((x.u >> 16) & 1u)) >> 16;
  return (short)r;
}
static __device__ inline float bf2f(short s) {
  union { unsigned u; float f; } x; x.u = ((unsigned)(unsigned short)s) << 16;
  return x.f;
}

#define GLOAD_LDS16(gp, lp) __builtin_amdgcn_global_load_lds( \
    (const __attribute__((address_space(1))) void*)(gp),      \
    (__attribute__((address_space(3))) void*)(lp), 16, 0, 0)

// ---------------- mask dtype detection ----------------
__global__ void k_detect(const unsigned char* __restrict__ m, int* __restrict__ flag) {
  __shared__ int c1, c2, c3;
  if (threadIdx.x == 0) { c1 = 0; c2 = 0; c3 = 0; }
  __syncthreads();
  int l1 = 0, l2 = 0, l3 = 0;
  for (int g = threadIdx.x; g < (kN * kH) / 4; g += blockDim.x) {
    l1 += (m[4 * g + 1] != 0);
    l2 += (m[4 * g + 2] != 0);
    l3 += (m[4 * g + 3] != 0);
  }
  atomicAdd(&c1, l1); atomicAdd(&c2, l2); atomicAdd(&c3, l3);
  __syncthreads();
  if (threadIdx.x == 0) {
    int f;
    if (c1 > 0)            f = 1;  // uint8 bools
    else if (c2 | c3)      f = 2;  // float32 bools
    else                   f = 0;  // int32 bools
    *flag = f;
  }
}

// ---------------- 1x1 conv (fp32, feats is an output) ----------------
__global__ __launch_bounds__(256) void k_conv(const float* __restrict__ bf,
                                              const float* __restrict__ cw,
                                              const float* __restrict__ cb,
                                              float* __restrict__ feats) {
  __shared__ float w[kAFC * kC];
  __shared__ float bsh[kAFC];
  for (int i = threadIdx.x; i < kAFC * kC; i += 256) w[i] = cw[i];
  if (threadIdx.x < kAFC) bsh[threadIdx.x] = cb[threadIdx.x];
  __syncthreads();
  int idx = blockIdx.x * 256 + threadIdx.x;
  if (idx >= kB * kHW) return;
  int b = idx / kHW, p = idx % kHW;
  float acc[kAFC];
#pragma unroll
  for (int o = 0; o < kAFC; o++) acc[o] = bsh[o];
  const float* src = bf + (size_t)b * kC * kHW + p;
#pragma unroll 4
  for (int c = 0; c < kC; c++) {
    float v = src[(size_t)c * kHW];
#pragma unroll
    for (int o = 0; o < kAFC; o++) acc[o] += v * w[o * kC + c];
  }
  float* dst = feats + (size_t)b * kAFC * kHW + p;
#pragma unroll
  for (int o = 0; o < kAFC; o++) dst[(size_t)o * kHW] = acc[o];
}

// ---------------- gather rois -> baf (bf16, d'=h*16+a layout) ---------------
__global__ __launch_bounds__(256) void k_gather(const float* __restrict__ feats,
                                                const int* __restrict__ cut,
                                                const void* __restrict__ mask,
                                                const int* __restrict__ flag,
                                                short* __restrict__ baf) {
  __shared__ float lf[kAFC * 193];   // pad 192->193 to rotate banks per a
  int bid = blockIdx.x;
  int b = bid & 15, h = bid >> 4;
  const float* fbase = feats + (size_t)b * kAFC * kHW + (size_t)h * kW;
  for (int i = threadIdx.x; i < kAFC * kW; i += 256) {
    int a = i / kW, x = i % kW;
    lf[a * 193 + x] = fbase[(size_t)a * kHW + x];
  }
  __syncthreads();
  int f = *flag;
  for (int n = threadIdx.x; n < kN; n += 256) {
    int r = n * kH + h;
    bool inv;
    if (f == 0)      inv = ((const int*)mask)[r] != 0;
    else if (f == 1) inv = ((const unsigned char*)mask)[r] != 0;
    else             inv = ((const float*)mask)[r] != 0.0f;
    bf16x8 v0 = {}, v1 = {};
    if (!inv) {
      int x = cut[r];
#pragma unroll
      for (int a = 0; a < 8; a++)  v0[a] = f2bf(lf[a * 193 + x]);
#pragma unroll
      for (int a = 0; a < 8; a++)  v1[a] = f2bf(lf[(a + 8) * 193 + x]);
    }
    short* dst = baf + (size_t)(b * kN + n) * kD + h * kAFC;
    *(bf16x8*)dst = v0;
    *(bf16x8*)(dst + 8) = v1;
  }
}

// ---------------- transpose baf -> bafT [b][d][n_pad] (zero-pad n>=1000) ----
__global__ __launch_bounds__(256) void k_transpose(const short* __restrict__ baf,
                                                   short* __restrict__ bafT) {
  __shared__ short t[64][66];
  int b = blockIdx.z, n0 = blockIdx.y * 64, d0 = blockIdx.x * 64;
  int c = threadIdx.x & 63, r4 = threadIdx.x >> 6;  // c: 0..63, r4: 0..3
#pragma unroll
  for (int i = 0; i < 16; i++) {
    int nl = r4 + i * 4;
    int n = n0 + nl;
    short v = (n < kN) ? baf[(size_t)(b * kN + n) * kD + d0 + c] : (short)0;
    t[nl][c] = v;
  }
  __syncthreads();
#pragma unroll
  for (int i = 0; i < 16; i++) {
    int dl = r4 + i * 4;
    bafT[((size_t)b * kD + d0 + dl) * kNP + n0 + c] = t[c][dl];
  }
}

// ---- convert attn_w -> bf16 [1024][2560] in d' order (per-row transpose) ---
__global__ __launch_bounds__(256) void k_cvt_attnw(const float* __restrict__ w,
                                                   short* __restrict__ o) {
  __shared__ float lw[kAFC * (kH + 1)];   // 16x161
  int j = blockIdx.x;                      // 0..1023
  short* dst = o + (size_t)j * kD;
  if (j < kNM1) {
    const float* src = w + (size_t)j * kD;
    for (int i = threadIdx.x; i < kD; i += 256) {
      int a = i / kH, h = i % kH;
      lw[a * (kH + 1) + h] = src[i];
    }
    __syncthreads();
    for (int dp = threadIdx.x; dp < kD; dp += 256) {
      int h = dp >> 4, a = dp & 15;
      dst[dp] = f2bf(lw[a * (kH + 1) + h]);
    }
  } else {
    for (int dp = threadIdx.x; dp < kD; dp += 256) dst[dp] = 0;
  }
}

// ---- build head weight bf16 [384][5120], both K-halves in d' order ---------
__global__ __launch_bounds__(256) void k_cvt_whead(const float* __restrict__ reg_w,
                                                   const float* __restrict__ cls_w,
                                                   short* __restrict__ o) {
  __shared__ float lw[2 * kAFC * (kH + 1)];  // 2 x 16 x 161
  int j = blockIdx.x;                        // 0..383
  const float* src = nullptr;
  if (j < 3 * kS)                 src = reg_w + (size_t)j * kK2;
  else if (j < 3 * kS + kNC)      src = cls_w + (size_t)(j - 3 * kS) * kK2;
  short* dst = o + (size_t)j * kK2;
  if (src) {
    for (int i = threadIdx.x; i < kK2; i += 256) {
      int half = i / kD, t = i % kD;
      int a = t / kH, h = t % kH;
      lw[(half * kAFC + a) * (kH + 1) + h] = src[i];
    }
    __syncthreads();
    for (int kp = threadIdx.x; kp < kK2; kp += 256) {
      int half = kp / kD, t = kp % kD;
      int h = t >> 4, a = t & 15;
      dst[kp] = f2bf(lw[(half * kAFC + a) * (kH + 1) + h]);
    }
  } else {
    for (int kp = threadIdx.x; kp < kK2; kp += 256) dst[kp] = 0;
  }
}

// ---------------- softmax: scores -> attn_mat (f32 out) + attn bf16 padded --
__global__ __launch_bounds__(256) void k_softmax(const float* __restrict__ scores,
                                                 const float* __restrict__ anchors,
                                                 float* __restrict__ attn_out,
                                                 short* __restrict__ attn_bf,
                                                 float* __restrict__ rp) {
  int m = blockIdx.x;           // 0..15999
  int b = m / kN;
  int i = m % kN;
  const float* srow = scores + (size_t)m * kNM1;
  int tid = threadIdx.x;
  __shared__ float red[4];
  float v[4];
  float mx = -INFINITY;
#pragma unroll
  for (int t = 0; t < 4; t++) {
    int j = tid + t * 256;
    v[t] = (j < kNM1) ? srow[j] : -INFINITY;
    mx = fmaxf(mx, v[t]);
  }
#pragma unroll
  for (int o = 32; o; o >>= 1) mx = fmaxf(mx, __shfl_down(mx, o));
  if ((tid & 63) == 0) red[tid >> 6] = mx;
  __syncthreads();
  mx = fmaxf(fmaxf(red[0], red[1]), fmaxf(red[2], red[3]));
  __syncthreads();
  float s = 0.f;
#pragma unroll
  for (int t = 0; t < 4; t++) {
    int j = tid + t * 256;
    v[t] = (j < kNM1) ? __expf(v[t] - mx) : 0.f;
    s += v[t];
  }
#pragma unroll
  for (int o = 32; o; o >>= 1) s += __shfl_down(s, o);
  if ((tid & 63) == 0) red[tid >> 6] = s;
  __syncthreads();
  s = red[0] + red[1] + red[2] + red[3];
  float inv = 1.0f / s;
  float* orow = attn_out + (size_t)m * kN;
  short* brow = attn_bf + ((size_t)b * kNP + i) * kNP;
#pragma unroll
  for (int t = 0; t < 4; t++) {
    int j = tid + t * 256;
    if (j < kNM1) {
      int dst = j + (j >= i);
      float p = v[t] * inv;
      orow[dst] = p;
      brow[dst] = f2bf(p);
    }
  }
  if (tid == 0) { orow[i] = 0.f; brow[i] = 0; }
  if (tid < kNP - kN) brow[kN + tid] = 0;           // pad cols 1000..1023
  if (tid < 3) rp[(size_t)m * kRP + 2 + tid] = anchors[(size_t)i * kRP + 2 + tid];
}

// ---------------- MFMA bf16 GEMM: 256x256 tile, BK=32, 8 waves --------------
// Counted-vmcnt ring pipeline (T3/T4): 4-deep LDS ring (4 x 32KB), one raw
// s_barrier per K-step, vmcnt(8) in steady state.
// MODE 0: scores = baf @ attnw^T (+attn_b), f32 out [16000][999]
// MODE 1: attf = attn_bf @ bafT^T, bf16 out [16][1000][2560]
template <int MODE>
__global__ __launch_bounds__(512, 2) void k_gemm8(
    const short* __restrict__ A,
    const short* __restrict__ Bt,
    const float* __restrict__ bias,
    void* __restrict__ Cout) {
  extern __shared__ char dls[];                // 128 KB: 4 bufs x (A 16K + B 16K)
  constexpr int K   = (MODE == 0) ? kD : kNP;  // 2560 / 1024
  constexpr int NT  = K / 32;                  // 80 / 32
  constexpr int lda = (MODE == 0) ? kD : kNP;
  constexpr int ldb = (MODE == 0) ? kD : kNP;
  int tid = threadIdx.x, lane = tid & 63, wv = tid >> 6;
  int bid = blockIdx.x;
  int m0, n0, bz = 0;
  const short* Ap = A;
  const short* Bp = Bt;
  if (MODE == 0) {
    int xcd = bid & 7, s = bid >> 3;
    m0 = (xcd * 8 + (s & 7)) * 256;            // 0..16128
    n0 = (s >> 3) * 256;                       // 0..768
  } else {
    int half = bid / 320, rem = bid % 320;
    bz = (rem & 7) + 8 * half;
    int inner = rem >> 3;                      // 0..39
    m0 = (inner & 3) * 256;                    // m fastest
    n0 = (inner >> 2) * 256;
    Ap = A + (size_t)bz * kNP * kNP;
    Bp = Bt + (size_t)bz * kD * kNP;
  }
  int wm = (wv & 1) * 128, wn = (wv >> 1) * 64;
  f32x4 acc[8][4] = {};

  // per-thread staging geometry: chunk ci in [0,1024) per operand, 2 per thread
  int r0  = tid >> 2;            // ci row for g=0 (ci = tid)
  int r1  = (512 + tid) >> 2;    // row for g=1
  int ko  = (tid & 3) * 8;       // k element offset within BK=32
  int ar0 = (MODE == 0) ? min(m0 + r0, kM - 1) : (m0 + r0);
  int ar1 = (MODE == 0) ? min(m0 + r1, kM - 1) : (m0 + r1);
  const short* gA0 = Ap + (size_t)ar0 * lda + ko;
  const short* gA1 = Ap + (size_t)ar1 * lda + ko;
  const short* gB0 = Bp + (size_t)(n0 + r0) * ldb + ko;
  const short* gB1 = Bp + (size_t)(n0 + r1) * ldb + ko;

  auto STAGE = [&](int tt) {
    char* buf = dls + (size_t)(tt & 3) * 32768;
    int k0 = tt * 32;
    GLOAD_LDS16(gA0 + k0, buf + wv * 1024);
    GLOAD_LDS16(gA1 + k0, buf + 8192 + wv * 1024);
    GLOAD_LDS16(gB0 + k0, buf + 16384 + wv * 1024);
    GLOAD_LDS16(gB1 + k0, buf + 24576 + wv * 1024);
  };

  STAGE(0); STAGE(1); STAGE(2);
  for (int t = 0; t < NT; t++) {
    if (t < NT - 2)       asm volatile("s_waitcnt vmcnt(8)" ::: "memory");
    else if (t == NT - 2) asm volatile("s_waitcnt vmcnt(4)" ::: "memory");
    else                  asm volatile("s_waitcnt vmcnt(0)" ::: "memory");
    __builtin_amdgcn_s_barrier();
    __builtin_amdgcn_sched_barrier(0);
    if (t + 3 < NT) STAGE(t + 3);
    const char* bufA = dls + (size_t)(t & 3) * 32768;
    const char* bufB = bufA + 16384;
    bf16x8 af[8], bg[4];
#pragma unroll
    for (int i = 0; i < 8; i++)
      af[i] = *(const bf16x8*)(bufA + (wm + i * 16 + (lane & 15)) * 64 + (lane >> 4) * 16);
#pragma unroll
    for (int j = 0; j < 4; j++)
      bg[j] = *(const bf16x8*)(bufB + (wn + j * 16 + (lane & 15)) * 64 + (lane >> 4) * 16);
#pragma unroll
    for (int i = 0; i < 8; i++)
#pragma unroll
      for (int j = 0; j < 4; j++)
        acc[i][j] = __builtin_amdgcn_mfma_f32_16x16x32_bf16(af[i], bg[j], acc[i][j], 0, 0, 0);
  }

  // epilogue
#pragma unroll
  for (int i = 0; i < 8; i++) {
#pragma unroll
    for (int j = 0; j < 4; j++) {
#pragma unroll
      for (int r = 0; r < 4; r++) {
        int row = m0 + wm + i * 16 + (lane >> 4) * 4 + r;
        int col = n0 + wn + j * 16 + (lane & 15);
        float v = acc[i][j][r];
        if (MODE == 0) {
          if (row < kM && col < kNM1)
            ((float*)Cout)[(size_t)row * kNM1 + col] = v + bias[col];
        } else {
          if (row < kN)
            ((short*)Cout)[((size_t)bz * kN + row) * kD + col] = f2bf(v);
        }
      }
    }
  }
}

// ---------------- head GEMM: ring pipeline, BM=128, BN=384, split-K=4 -------
// Same counted-vmcnt 4-deep ring as k_gemm8. 8 waves (2m x 4n), wave tile
// 64x96, acc[4][6]. Each ks chunk (1280) lies wholly in attf (ks<2) or baf:
// A pointer fixed per block. Grid ks-major so concurrent blocks share the
// 983KB whead K-chunk (L2-resident). bf16 partials out.
__global__ __launch_bounds__(512, 2) void k_head8(
    const short* __restrict__ attf,  // [16000][2560]
    const short* __restrict__ baf,   // [16000][2560]
    const short* __restrict__ Bt,    // whead [384][5120]
    short* __restrict__ part) {
  extern __shared__ char dls[];      // 128 KB: 4 bufs x (A 8K + B 24K)
  constexpr int NT = (kK2 / kKS) / 32;  // 40
  int tid = threadIdx.x, lane = tid & 63, wv = tid >> 6;
  int bid = blockIdx.x;
  int ks = bid / (kM / 128);         // 0..3 (ks-major)
  int mt = bid % (kM / 128);
  int m0 = mt * 128;
  int kbase = ks * (kK2 / kKS);      // 0,1280,2560,3840
  const short* Ap = (ks < 2) ? (attf + kbase) : (baf + (kbase - kD));

  int wm = (wv & 1) * 64, wn = (wv >> 1) * 96;
  f32x4 acc[4][6] = {};

  // staging: A 512 chunks (1/thread), B 1536 chunks (3/thread)
  int rA = tid >> 2;                 // 0..127
  int ko = (tid & 3) * 8;
  const short* gA  = Ap + (size_t)(m0 + rA) * kD + ko;
  const short* gB0 = Bt + (size_t)((tid) >> 2) * kK2 + kbase + ko;          // rows 0..127
  const short* gB1 = Bt + (size_t)((512 + tid) >> 2) * kK2 + kbase + ko;    // rows 128..255
  const short* gB2 = Bt + (size_t)((1024 + tid) >> 2) * kK2 + kbase + ko;   // rows 256..383

  auto STAGE = [&](int tt) {
    char* buf = dls + (size_t)(tt & 3) * 32768;
    int k0 = tt * 32;
    GLOAD_LDS16(gA + k0,  buf + wv * 1024);
    GLOAD_LDS16(gB0 + k0, buf + 8192 + wv * 1024);
    GLOAD_LDS16(gB1 + k0, buf + 16384 + wv * 1024);
    GLOAD_LDS16(gB2 + k0, buf + 24576 + wv * 1024);
  };

  STAGE(0); STAGE(1); STAGE(2);
  for (int t = 0; t < NT; t++) {
    if (t < NT - 2)       asm volatile("s_waitcnt vmcnt(8)" ::: "memory");
    else if (t == NT - 2) asm volatile("s_waitcnt vmcnt(4)" ::: "memory");
    else                  asm volatile("s_waitcnt vmcnt(0)" ::: "memory");
    __builtin_amdgcn_s_barrier();
    __builtin_amdgcn_sched_barrier(0);
    if (t + 3 < NT) STAGE(t + 3);
    const char* bufA = dls + (size_t)(t & 3) * 32768;
    const char* bufB = bufA + 8192;
    bf16x8 af[4], bg[6];
#pragma unroll
    for (int i = 0; i < 4; i++)
      af[i] = *(const bf16x8*)(bufA + (wm + i * 16 + (lane & 15)) * 64 + (lane >> 4) * 16);
#pragma unroll
    for (int j = 0; j < 6; j++)
      bg[j] = *(const bf16x8*)(bufB + (wn + j * 16 + (lane & 15)) * 64 + (lane >> 4) * 16);
#pragma unroll
    for (int i = 0; i < 4; i++)
#pragma unroll
      for (int j = 0; j < 6; j++)
        acc[i][j] = __builtin_amdgcn_mfma_f32_16x16x32_bf16(af[i], bg[j], acc[i][j], 0, 0, 0);
  }

  short* pbase = part + (size_t)ks * kM * 384;
#pragma unroll
  for (int i = 0; i < 4; i++) {
#pragma unroll
    for (int j = 0; j < 6; j++) {
#pragma unroll
      for (int r = 0; r < 4; r++) {
        int row = m0 + wm + i * 16 + (lane >> 4) * 4 + r;
        int col = wn + j * 16 + (lane & 15);
        pbase[(size_t)row * 384 + col] = f2bf(acc[i][j][r]);
      }
    }
  }
}

// ---------------- head reduce: sum 4 bf16 partials + epilogue -> rp ---------
__global__ __launch_bounds__(256) void k_head_reduce(
    const short* __restrict__ part,
    const float* __restrict__ reg_b, const float* __restrict__ cls_b,
    const float* __restrict__ anchors, float* __restrict__ rp) {
  int idx = blockIdx.x * 256 + threadIdx.x;
  if (idx >= kM * 384) return;
  int row = idx / 384, col = idx % 384;
  size_t stride = (size_t)kM * 384;
  float v = bf2f(part[idx]) + bf2f(part[stride + idx]) +
            bf2f(part[2 * stride + idx]) + bf2f(part[3 * stride + idx]);
  int n = row % kN;
  if (col < 3 * kS) {
    float tv = v + reg_b[col];
    if (col >= 2 * kS) tv = 1.0f / (1.0f + __expf(-tv));
    rp[(size_t)row * kRP + 5 + col] = anchors[(size_t)n * kRP + 5 + col] + tv;
  } else if (col < 3 * kS + kNC) {
    rp[(size_t)row * kRP + (col - 3 * kS)] = v + cls_b[col - 3 * kS];
  }
}

extern "C" void kernel_launch(void* const* d_in, const int* in_sizes, int n_in,
                              void* d_out, int out_size, void* d_ws, size_t ws_size,
                              hipStream_t stream) {
  const float* bf      = (const float*)d_in[0];
  const float* conv_w  = (const float*)d_in[1];
  const float* conv_b  = (const float*)d_in[2];
  const int*   cut     = (const int*)d_in[3];
  const void*  mask    = d_in[4];
  const float* anchors = (const float*)d_in[5];
  const float* attn_w  = (const float*)d_in[6];
  const float* attn_b  = (const float*)d_in[7];
  const float* cls_w   = (const float*)d_in[8];
  const float* cls_b   = (const float*)d_in[9];
  const float* reg_w   = (const float*)d_in[10];
  const float* reg_b   = (const float*)d_in[11];

  float* out    = (float*)d_out;
  float* rp     = out + OFF_RP;
  float* attn_o = out + OFF_ATTN;
  float* feats  = out + OFF_FEAT;

  char*  ws      = (char*)d_ws;
  short* baf     = (short*)(ws + WB_BAF);
  short* bafT    = (short*)(ws + WB_BAFT);
  short* attf    = (short*)(ws + WB_ATTF);
  short* attnw   = (short*)(ws + WB_ATTNW);
  short* whead   = (short*)(ws + WB_WHEAD);
  short* attn_bf = (short*)(ws + WB_ATTNB);
  float* scores  = (float*)(ws + WB_SCORE);
  short* part    = (short*)(ws + WB_PART);
  int*   flag    = (int*)(ws + WB_FLAG);

  k_detect<<<1, 256, 0, stream>>>((const unsigned char*)mask, flag);
  k_conv<<<(kB * kHW) / 256, 256, 0, stream>>>(bf, conv_w, conv_b, feats);
  // gather: one block per (b,h); 2560 blocks
  k_gather<<<kB * kH, 256, 0, stream>>>(feats, cut, mask, flag, baf);
  {
    dim3 g(kD / 64, 16, kB);  // d-tiles, n-tiles, batch
    k_transpose<<<g, 256, 0, stream>>>(baf, bafT);
  }
  k_cvt_attnw<<<kNP, 256, 0, stream>>>(attn_w, attnw);
  k_cvt_whead<<<384, 256, 0, stream>>>(reg_w, cls_w, whead);
  // scores GEMM: 256 blocks (64 m-tiles x 4 n-tiles, XCD owns 8 m-tiles)
  k_gemm8<0><<<256, 512, 131072, stream>>>(baf, attnw, attn_b, scores);
  k_softmax<<<kM, 256, 0, stream>>>(scores, anchors, attn_o, attn_bf, rp);
  // att GEMM: 640 blocks (16 b x 4 m x 10 n; XCD = batch, two passes)
  k_gemm8<1><<<640, 512, 131072, stream>>>(attn_bf, bafT, nullptr, attf);
  // head GEMM: ring pipeline, 500 blocks (4 ks x 125 m-tiles, ks-major)
  k_head8<<<kKS * (kM / 128), 512, 131072, stream>>>(attf, baf, whead, part);
  k_head_reduce<<<(kM * 384) / 256, 256, 0, stream>>>(part, reg_b, cls_b,
                                                      anchors, rp);
}

// Round 11
// 465.033 us; speedup vs baseline: 1.7344x; 1.2325x over previous
//
#include <hip/hip_runtime.h>
#include <cmath>

// Problem constants
static constexpr int kB   = 16;
static constexpr int kC   = 64;
static constexpr int kH   = 160;
static constexpr int kW   = 192;
static constexpr int kN   = 1000;
static constexpr int kAFC = 16;
static constexpr int kS   = 96;
static constexpr int kNC  = 2;
static constexpr int kD   = kAFC * kH;     // 2560
static constexpr int kHW  = kH * kW;       // 30720
static constexpr int kNM1 = kN - 1;        // 999
static constexpr int kM   = kB * kN;       // 16000
static constexpr int kRP  = kNC + 3 + 3 * kS; // 293
static constexpr int kK2  = 2 * kD;        // 5120
static constexpr int kNP  = 1024;          // padded N

// Internal feature ordering is d' = h*16 + a (h-major); all internal tensors
// and repacked weights use d' consistently.
//
// Reassociation: head = attn@(baf@W1^T) + baf@W2^T  (W1|W2 = whead halves).
// P-GEMM computes both X1=baf@W1^T (written transposed per batch) and
// X2=baf@W2^T (row-major); F-GEMM computes attn@X1 + X2 + epilogue -> rp.

// d_out layout (floats)
static constexpr size_t OFF_RP   = 0;
static constexpr size_t OFF_ATTN = (size_t)kB * kN * kRP;
static constexpr size_t OFF_FEAT = OFF_ATTN + (size_t)kB * kN * kN;

// ws layout (bytes)
static constexpr size_t WB_BAF   = 0;                                    // bf16 [16000][2560]
static constexpr size_t WB_ATTNW = WB_BAF   + (size_t)kM * kD * 2;       // bf16 [1024][2560]
static constexpr size_t WB_WHEAD = WB_ATTNW + (size_t)kNP * kD * 2;      // bf16 [384][5120]
static constexpr size_t WB_ATTNB = WB_WHEAD + (size_t)384 * kK2 * 2;     // bf16 [16][1024][1024]
static constexpr size_t WB_SCORE = WB_ATTNB + (size_t)kB * kNP * kNP * 2;// f32  [16000][999]
static constexpr size_t WB_P1T   = WB_SCORE + (size_t)kM * kNM1 * 4;     // bf16 [16][384][1024]
static constexpr size_t WB_P2    = WB_P1T   + (size_t)kB * 384 * kNP * 2;// bf16 [16000][384]
static constexpr size_t WB_FLAG  = WB_P2    + (size_t)kM * 384 * 2;      // int

typedef __attribute__((ext_vector_type(8))) short bf16x8;
typedef __attribute__((ext_vector_type(4))) float f32x4;

static __device__ inline short f2bf(float f) {
  union { float f; unsigned u; } x; x.f = f;
  unsigned r = (x.u + 0x7FFFu + ((x.u >> 16) & 1u)) >> 16;
  return (short)r;
}
static __device__ inline float bf2f(short s) {
  union { unsigned u; float f; } x; x.u = ((unsigned)(unsigned short)s) << 16;
  return x.f;
}

#define GLOAD_LDS16(gp, lp) __builtin_amdgcn_global_load_lds( \
    (const __attribute__((address_space(1))) void*)(gp),      \
    (__attribute__((address_space(3))) void*)(lp), 16, 0, 0)

// ---------------- mask dtype detection ----------------
__global__ void k_detect(const unsigned char* __restrict__ m, int* __restrict__ flag) {
  __shared__ int c1, c2, c3;
  if (threadIdx.x == 0) { c1 = 0; c2 = 0; c3 = 0; }
  __syncthreads();
  int l1 = 0, l2 = 0, l3 = 0;
  for (int g = threadIdx.x; g < (kN * kH) / 4; g += blockDim.x) {
    l1 += (m[4 * g + 1] != 0);
    l2 += (m[4 * g + 2] != 0);
    l3 += (m[4 * g + 3] != 0);
  }
  atomicAdd(&c1, l1); atomicAdd(&c2, l2); atomicAdd(&c3, l3);
  __syncthreads();
  if (threadIdx.x == 0) {
    int f;
    if (c1 > 0)            f = 1;  // uint8 bools
    else if (c2 | c3)      f = 2;  // float32 bools
    else                   f = 0;  // int32 bools
    *flag = f;
  }
}

// ---------------- 1x1 conv (fp32, feats is an output) ----------------
__global__ __launch_bounds__(256) void k_conv(const float* __restrict__ bf,
                                              const float* __restrict__ cw,
                                              const float* __restrict__ cb,
                                              float* __restrict__ feats) {
  __shared__ float w[kAFC * kC];
  __shared__ float bsh[kAFC];
  for (int i = threadIdx.x; i < kAFC * kC; i += 256) w[i] = cw[i];
  if (threadIdx.x < kAFC) bsh[threadIdx.x] = cb[threadIdx.x];
  __syncthreads();
  int idx = blockIdx.x * 256 + threadIdx.x;
  if (idx >= kB * kHW) return;
  int b = idx / kHW, p = idx % kHW;
  float acc[kAFC];
#pragma unroll
  for (int o = 0; o < kAFC; o++) acc[o] = bsh[o];
  const float* src = bf + (size_t)b * kC * kHW + p;
#pragma unroll 4
  for (int c = 0; c < kC; c++) {
    float v = src[(size_t)c * kHW];
#pragma unroll
    for (int o = 0; o < kAFC; o++) acc[o] += v * w[o * kC + c];
  }
  float* dst = feats + (size_t)b * kAFC * kHW + p;
#pragma unroll
  for (int o = 0; o < kAFC; o++) dst[(size_t)o * kHW] = acc[o];
}

// ---------------- gather rois -> baf (bf16, d'=h*16+a layout) ---------------
__global__ __launch_bounds__(256) void k_gather(const float* __restrict__ feats,
                                                const int* __restrict__ cut,
                                                const void* __restrict__ mask,
                                                const int* __restrict__ flag,
                                                short* __restrict__ baf) {
  __shared__ float lf[kAFC * 193];   // pad 192->193 to rotate banks per a
  int bid = blockIdx.x;
  int b = bid & 15, h = bid >> 4;
  const float* fbase = feats + (size_t)b * kAFC * kHW + (size_t)h * kW;
  for (int i = threadIdx.x; i < kAFC * kW; i += 256) {
    int a = i / kW, x = i % kW;
    lf[a * 193 + x] = fbase[(size_t)a * kHW + x];
  }
  __syncthreads();
  int f = *flag;
  for (int n = threadIdx.x; n < kN; n += 256) {
    int r = n * kH + h;
    bool inv;
    if (f == 0)      inv = ((const int*)mask)[r] != 0;
    else if (f == 1) inv = ((const unsigned char*)mask)[r] != 0;
    else             inv = ((const float*)mask)[r] != 0.0f;
    bf16x8 v0 = {}, v1 = {};
    if (!inv) {
      int x = cut[r];
#pragma unroll
      for (int a = 0; a < 8; a++)  v0[a] = f2bf(lf[a * 193 + x]);
#pragma unroll
      for (int a = 0; a < 8; a++)  v1[a] = f2bf(lf[(a + 8) * 193 + x]);
    }
    short* dst = baf + (size_t)(b * kN + n) * kD + h * kAFC;
    *(bf16x8*)dst = v0;
    *(bf16x8*)(dst + 8) = v1;
  }
}

// ---- convert attn_w -> bf16 [1024][2560] in d' order (per-row transpose) ---
__global__ __launch_bounds__(256) void k_cvt_attnw(const float* __restrict__ w,
                                                   short* __restrict__ o) {
  __shared__ float lw[kAFC * (kH + 1)];   // 16x161
  int j = blockIdx.x;                      // 0..1023
  short* dst = o + (size_t)j * kD;
  if (j < kNM1) {
    const float* src = w + (size_t)j * kD;
    for (int i = threadIdx.x; i < kD; i += 256) {
      int a = i / kH, h = i % kH;
      lw[a * (kH + 1) + h] = src[i];
    }
    __syncthreads();
    for (int dp = threadIdx.x; dp < kD; dp += 256) {
      int h = dp >> 4, a = dp & 15;
      dst[dp] = f2bf(lw[a * (kH + 1) + h]);
    }
  } else {
    for (int dp = threadIdx.x; dp < kD; dp += 256) dst[dp] = 0;
  }
}

// ---- build head weight bf16 [384][5120], both K-halves in d' order ---------
__global__ __launch_bounds__(256) void k_cvt_whead(const float* __restrict__ reg_w,
                                                   const float* __restrict__ cls_w,
                                                   short* __restrict__ o) {
  __shared__ float lw[2 * kAFC * (kH + 1)];  // 2 x 16 x 161
  int j = blockIdx.x;                        // 0..383
  const float* src = nullptr;
  if (j < 3 * kS)                 src = reg_w + (size_t)j * kK2;
  else if (j < 3 * kS + kNC)      src = cls_w + (size_t)(j - 3 * kS) * kK2;
  short* dst = o + (size_t)j * kK2;
  if (src) {
    for (int i = threadIdx.x; i < kK2; i += 256) {
      int half = i / kD, t = i % kD;
      int a = t / kH, h = t % kH;
      lw[(half * kAFC + a) * (kH + 1) + h] = src[i];
    }
    __syncthreads();
    for (int kp = threadIdx.x; kp < kK2; kp += 256) {
      int half = kp / kD, t = kp % kD;
      int h = t >> 4, a = t & 15;
      dst[kp] = f2bf(lw[(half * kAFC + a) * (kH + 1) + h]);
    }
  } else {
    for (int kp = threadIdx.x; kp < kK2; kp += 256) dst[kp] = 0;
  }
}

// ---------------- softmax: scores -> attn_mat (f32 out) + attn bf16 padded --
__global__ __launch_bounds__(256) void k_softmax(const float* __restrict__ scores,
                                                 const float* __restrict__ anchors,
                                                 float* __restrict__ attn_out,
                                                 short* __restrict__ attn_bf,
                                                 float* __restrict__ rp) {
  int m = blockIdx.x;           // 0..15999
  int b = m / kN;
  int i = m % kN;
  const float* srow = scores + (size_t)m * kNM1;
  int tid = threadIdx.x;
  __shared__ float red[4];
  float v[4];
  float mx = -INFINITY;
#pragma unroll
  for (int t = 0; t < 4; t++) {
    int j = tid + t * 256;
    v[t] = (j < kNM1) ? srow[j] : -INFINITY;
    mx = fmaxf(mx, v[t]);
  }
#pragma unroll
  for (int o = 32; o; o >>= 1) mx = fmaxf(mx, __shfl_down(mx, o));
  if ((tid & 63) == 0) red[tid >> 6] = mx;
  __syncthreads();
  mx = fmaxf(fmaxf(red[0], red[1]), fmaxf(red[2], red[3]));
  __syncthreads();
  float s = 0.f;
#pragma unroll
  for (int t = 0; t < 4; t++) {
    int j = tid + t * 256;
    v[t] = (j < kNM1) ? __expf(v[t] - mx) : 0.f;
    s += v[t];
  }
#pragma unroll
  for (int o = 32; o; o >>= 1) s += __shfl_down(s, o);
  if ((tid & 63) == 0) red[tid >> 6] = s;
  __syncthreads();
  s = red[0] + red[1] + red[2] + red[3];
  float inv = 1.0f / s;
  float* orow = attn_out + (size_t)m * kN;
  short* brow = attn_bf + ((size_t)b * kNP + i) * kNP;
#pragma unroll
  for (int t = 0; t < 4; t++) {
    int j = tid + t * 256;
    if (j < kNM1) {
      int dst = j + (j >= i);
      float p = v[t] * inv;
      orow[dst] = p;
      brow[dst] = f2bf(p);
    }
  }
  if (tid == 0) { orow[i] = 0.f; brow[i] = 0; }
  if (tid < kNP - kN) brow[kN + tid] = 0;           // pad cols 1000..1023
  if (tid < 3) rp[(size_t)m * kRP + 2 + tid] = anchors[(size_t)i * kRP + 2 + tid];
}

// ---------------- scores GEMM: 256x256 tile, BK=32, 8 waves, ring ----------
// Counted-vmcnt ring pipeline: 4-deep LDS ring (4 x 32KB), one raw s_barrier
// per K-step, vmcnt(8) in steady state.
__global__ __launch_bounds__(512, 2) void k_sgemm(
    const short* __restrict__ A,
    const short* __restrict__ Bt,
    const float* __restrict__ bias,
    float* __restrict__ Cout) {
  extern __shared__ char dls[];                // 128 KB: 4 bufs x (A 16K + B 16K)
  constexpr int NT = kD / 32;                  // 80
  int tid = threadIdx.x, lane = tid & 63, wv = tid >> 6;
  int bid = blockIdx.x;
  int xcd = bid & 7, s = bid >> 3;
  int m0 = (xcd * 8 + (s & 7)) * 256;          // 0..16128 (M padded via clamp)
  int n0 = (s >> 3) * 256;                     // 0..768
  int wm = (wv & 1) * 128, wn = (wv >> 1) * 64;
  f32x4 acc[8][4] = {};

  int r0  = tid >> 2;
  int r1  = (512 + tid) >> 2;
  int ko  = (tid & 3) * 8;
  int ar0 = min(m0 + r0, kM - 1);
  int ar1 = min(m0 + r1, kM - 1);
  const short* gA0 = A + (size_t)ar0 * kD + ko;
  const short* gA1 = A + (size_t)ar1 * kD + ko;
  const short* gB0 = Bt + (size_t)(n0 + r0) * kD + ko;
  const short* gB1 = Bt + (size_t)(n0 + r1) * kD + ko;

  auto STAGE = [&](int tt) {
    char* buf = dls + (size_t)(tt & 3) * 32768;
    int k0 = tt * 32;
    GLOAD_LDS16(gA0 + k0, buf + wv * 1024);
    GLOAD_LDS16(gA1 + k0, buf + 8192 + wv * 1024);
    GLOAD_LDS16(gB0 + k0, buf + 16384 + wv * 1024);
    GLOAD_LDS16(gB1 + k0, buf + 24576 + wv * 1024);
  };

  STAGE(0); STAGE(1); STAGE(2);
  for (int t = 0; t < NT; t++) {
    if (t < NT - 2)       asm volatile("s_waitcnt vmcnt(8)" ::: "memory");
    else if (t == NT - 2) asm volatile("s_waitcnt vmcnt(4)" ::: "memory");
    else                  asm volatile("s_waitcnt vmcnt(0)" ::: "memory");
    __builtin_amdgcn_s_barrier();
    __builtin_amdgcn_sched_barrier(0);
    if (t + 3 < NT) STAGE(t + 3);
    const char* bufA = dls + (size_t)(t & 3) * 32768;
    const char* bufB = bufA + 16384;
    bf16x8 af[8], bg[4];
#pragma unroll
    for (int i = 0; i < 8; i++)
      af[i] = *(const bf16x8*)(bufA + (wm + i * 16 + (lane & 15)) * 64 + (lane >> 4) * 16);
#pragma unroll
    for (int j = 0; j < 4; j++)
      bg[j] = *(const bf16x8*)(bufB + (wn + j * 16 + (lane & 15)) * 64 + (lane >> 4) * 16);
#pragma unroll
    for (int i = 0; i < 8; i++)
#pragma unroll
      for (int j = 0; j < 4; j++)
        acc[i][j] = __builtin_amdgcn_mfma_f32_16x16x32_bf16(af[i], bg[j], acc[i][j], 0, 0, 0);
  }

#pragma unroll
  for (int i = 0; i < 8; i++) {
#pragma unroll
    for (int j = 0; j < 4; j++) {
#pragma unroll
      for (int r = 0; r < 4; r++) {
        int row = m0 + wm + i * 16 + (lane >> 4) * 4 + r;
        int col = n0 + wn + j * 16 + (lane & 15);
        if (row < kM && col < kNM1)
          Cout[(size_t)row * kNM1 + col] = acc[i][j][r] + bias[col];
      }
    }
  }
}

// ---------------- P-GEMM: X = baf @ Wstk^T, ring, BM=128, BN=384 ------------
// nb=0: W1 (whead cols 0:2560) -> p1t[b][col][n] (transposed, bf16)
// nb=1: W2 (whead cols 2560:5120) -> p2[row][col] (row-major, bf16)
__global__ __launch_bounds__(512, 2) void k_pgemm(
    const short* __restrict__ baf,   // [16000][2560]
    const short* __restrict__ Bt,    // whead [384][5120]
    short* __restrict__ p1t,         // [16][384][1024]
    short* __restrict__ p2) {        // [16000][384]
  extern __shared__ char dls[];      // 128 KB: 4 bufs x (A 8K + B 24K)
  constexpr int NT = kD / 32;        // 80
  int tid = threadIdx.x, lane = tid & 63, wv = tid >> 6;
  int bid = blockIdx.x;
  int nb = bid & 1, mt = bid >> 1;
  int m0 = mt * 128;
  int kofs = nb * kD;

  int wm = (wv & 1) * 64, wn = (wv >> 1) * 96;
  f32x4 acc[4][6] = {};

  int rA = tid >> 2;
  int ko = (tid & 3) * 8;
  const short* gA  = baf + (size_t)(m0 + rA) * kD + ko;
  const short* gB0 = Bt + (size_t)(tid >> 2) * kK2 + kofs + ko;
  const short* gB1 = Bt + (size_t)((512 + tid) >> 2) * kK2 + kofs + ko;
  const short* gB2 = Bt + (size_t)((1024 + tid) >> 2) * kK2 + kofs + ko;

  auto STAGE = [&](int tt) {
    char* buf = dls + (size_t)(tt & 3) * 32768;
    int k0 = tt * 32;
    GLOAD_LDS16(gA + k0,  buf + wv * 1024);
    GLOAD_LDS16(gB0 + k0, buf + 8192 + wv * 1024);
    GLOAD_LDS16(gB1 + k0, buf + 16384 + wv * 1024);
    GLOAD_LDS16(gB2 + k0, buf + 24576 + wv * 1024);
  };

  STAGE(0); STAGE(1); STAGE(2);
  for (int t = 0; t < NT; t++) {
    if (t < NT - 2)       asm volatile("s_waitcnt vmcnt(8)" ::: "memory");
    else if (t == NT - 2) asm volatile("s_waitcnt vmcnt(4)" ::: "memory");
    else                  asm volatile("s_waitcnt vmcnt(0)" ::: "memory");
    __builtin_amdgcn_s_barrier();
    __builtin_amdgcn_sched_barrier(0);
    if (t + 3 < NT) STAGE(t + 3);
    const char* bufA = dls + (size_t)(t & 3) * 32768;
    const char* bufB = bufA + 8192;
    bf16x8 af[4], bg[6];
#pragma unroll
    for (int i = 0; i < 4; i++)
      af[i] = *(const bf16x8*)(bufA + (wm + i * 16 + (lane & 15)) * 64 + (lane >> 4) * 16);
#pragma unroll
    for (int j = 0; j < 6; j++)
      bg[j] = *(const bf16x8*)(bufB + (wn + j * 16 + (lane & 15)) * 64 + (lane >> 4) * 16);
#pragma unroll
    for (int i = 0; i < 4; i++)
#pragma unroll
      for (int j = 0; j < 6; j++)
        acc[i][j] = __builtin_amdgcn_mfma_f32_16x16x32_bf16(af[i], bg[j], acc[i][j], 0, 0, 0);
  }

#pragma unroll
  for (int i = 0; i < 4; i++) {
#pragma unroll
    for (int j = 0; j < 6; j++) {
#pragma unroll
      for (int r = 0; r < 4; r++) {
        int row = m0 + wm + i * 16 + (lane >> 4) * 4 + r;
        int col = wn + j * 16 + (lane & 15);
        short v = f2bf(acc[i][j][r]);
        if (nb == 0) {
          int b = row / kN, n = row - b * kN;
          p1t[((size_t)b * 384 + col) * kNP + n] = v;
        } else {
          p2[(size_t)row * 384 + col] = v;
        }
      }
    }
  }
}

// ---------------- F-GEMM: Y[b] = attn_bf[b] @ p1t[b]^T + p2 + epilogue ------
// BM=64, BN=384, K=1024; 256 blocks = 1/CU; ring 4 x 28KB = 112 KB.
// Uniform 4 loads/thread (A region duplicated across wave halves; benign
// identical-write race) so counted vmcnt stays per-wave-uniform.
__global__ __launch_bounds__(512, 2) void k_fgemm(
    const short* __restrict__ attn_bf,  // [16][1024][1024]
    const short* __restrict__ p1t,      // [16][384][1024]
    const short* __restrict__ p2,       // [16000][384]
    const float* __restrict__ reg_b, const float* __restrict__ cls_b,
    const float* __restrict__ anchors, float* __restrict__ rp) {
  extern __shared__ char dls[];      // 112 KB: 4 bufs x (A 4K + B 24K)
  constexpr int NT = kNP / 32;       // 32
  int tid = threadIdx.x, lane = tid & 63, wv = tid >> 6;
  int bid = blockIdx.x;
  int b = bid & 15, mt = bid >> 4;   // XCD = bid&7 -> b in {x, x+8}: p1t L2-hot
  int m0 = mt * 64;
  const short* Ap = attn_bf + (size_t)b * kNP * kNP;
  const short* Bp = p1t + (size_t)b * 384 * kNP;

  int wm = (wv & 1) * 32, wn = (wv >> 1) * 96;
  f32x4 acc[2][6] = {};

  int ciA = tid & 255;
  const short* gA  = Ap + (size_t)(m0 + (ciA >> 2)) * kNP + (ciA & 3) * 8;
  int ko = (tid & 3) * 8;
  const short* gB0 = Bp + (size_t)(tid >> 2) * kNP + ko;
  const short* gB1 = Bp + (size_t)((512 + tid) >> 2) * kNP + ko;
  const short* gB2 = Bp + (size_t)((1024 + tid) >> 2) * kNP + ko;

  auto STAGE = [&](int tt) {
    char* buf = dls + (size_t)(tt & 3) * 28672;
    int k0 = tt * 32;
    GLOAD_LDS16(gA + k0,  buf + (wv & 3) * 1024);
    GLOAD_LDS16(gB0 + k0, buf + 4096 + wv * 1024);
    GLOAD_LDS16(gB1 + k0, buf + 12288 + wv * 1024);
    GLOAD_LDS16(gB2 + k0, buf + 20480 + wv * 1024);
  };

  STAGE(0); STAGE(1); STAGE(2);
  for (int t = 0; t < NT; t++) {
    if (t < NT - 2)       asm volatile("s_waitcnt vmcnt(8)" ::: "memory");
    else if (t == NT - 2) asm volatile("s_waitcnt vmcnt(4)" ::: "memory");
    else                  asm volatile("s_waitcnt vmcnt(0)" ::: "memory");
    __builtin_amdgcn_s_barrier();
    __builtin_amdgcn_sched_barrier(0);
    if (t + 3 < NT) STAGE(t + 3);
    const char* bufA = dls + (size_t)(t & 3) * 28672;
    const char* bufB = bufA + 4096;
    bf16x8 af[2], bg[6];
#pragma unroll
    for (int i = 0; i < 2; i++)
      af[i] = *(const bf16x8*)(bufA + (wm + i * 16 + (lane & 15)) * 64 + (lane >> 4) * 16);
#pragma unroll
    for (int j = 0; j < 6; j++)
      bg[j] = *(const bf16x8*)(bufB + (wn + j * 16 + (lane & 15)) * 64 + (lane >> 4) * 16);
#pragma unroll
    for (int i = 0; i < 2; i++)
#pragma unroll
      for (int j = 0; j < 6; j++)
        acc[i][j] = __builtin_amdgcn_mfma_f32_16x16x32_bf16(af[i], bg[j], acc[i][j], 0, 0, 0);
  }

#pragma unroll
  for (int i = 0; i < 2; i++) {
#pragma unroll
    for (int j = 0; j < 6; j++) {
#pragma unroll
      for (int r = 0; r < 4; r++) {
        int n = m0 + wm + i * 16 + (lane >> 4) * 4 + r;   // 0..1023
        int col = wn + j * 16 + (lane & 15);              // 0..383
        if (n < kN) {
          size_t row = (size_t)b * kN + n;
          float v = acc[i][j][r] + bf2f(p2[row * 384 + col]);
          if (col < 3 * kS) {
            float tv = v + reg_b[col];
            if (col >= 2 * kS) tv = 1.0f / (1.0f + __expf(-tv));
            rp[row * kRP + 5 + col] = anchors[(size_t)n * kRP + 5 + col] + tv;
          } else if (col < 3 * kS + kNC) {
            rp[row * kRP + (col - 3 * kS)] = v + cls_b[col - 3 * kS];
          }
        }
      }
    }
  }
}

extern "C" void kernel_launch(void* const* d_in, const int* in_sizes, int n_in,
                              void* d_out, int out_size, void* d_ws, size_t ws_size,
                              hipStream_t stream) {
  const float* bf      = (const float*)d_in[0];
  const float* conv_w  = (const float*)d_in[1];
  const float* conv_b  = (const float*)d_in[2];
  const int*   cut     = (const int*)d_in[3];
  const void*  mask    = d_in[4];
  const float* anchors = (const float*)d_in[5];
  const float* attn_w  = (const float*)d_in[6];
  const float* attn_b  = (const float*)d_in[7];
  const float* cls_w   = (const float*)d_in[8];
  const float* cls_b   = (const float*)d_in[9];
  const float* reg_w   = (const float*)d_in[10];
  const float* reg_b   = (const float*)d_in[11];

  float* out    = (float*)d_out;
  float* rp     = out + OFF_RP;
  float* attn_o = out + OFF_ATTN;
  float* feats  = out + OFF_FEAT;

  char*  ws      = (char*)d_ws;
  short* baf     = (short*)(ws + WB_BAF);
  short* attnw   = (short*)(ws + WB_ATTNW);
  short* whead   = (short*)(ws + WB_WHEAD);
  short* attn_bf = (short*)(ws + WB_ATTNB);
  float* scores  = (float*)(ws + WB_SCORE);
  short* p1t     = (short*)(ws + WB_P1T);
  short* p2      = (short*)(ws + WB_P2);
  int*   flag    = (int*)(ws + WB_FLAG);

  k_detect<<<1, 256, 0, stream>>>((const unsigned char*)mask, flag);
  k_conv<<<(kB * kHW) / 256, 256, 0, stream>>>(bf, conv_w, conv_b, feats);
  k_gather<<<kB * kH, 256, 0, stream>>>(feats, cut, mask, flag, baf);
  k_cvt_attnw<<<kNP, 256, 0, stream>>>(attn_w, attnw);
  k_cvt_whead<<<384, 256, 0, stream>>>(reg_w, cls_w, whead);
  // P-GEMM: 250 blocks (125 m-tiles x 2 n-halves)
  k_pgemm<<<2 * (kM / 128), 512, 131072, stream>>>(baf, whead, p1t, p2);
  // scores GEMM: 256 blocks (64 m-tiles x 4 n-tiles, XCD owns 8 m-tiles)
  k_sgemm<<<256, 512, 131072, stream>>>(baf, attnw, attn_b, scores);
  k_softmax<<<kM, 256, 0, stream>>>(scores, anchors, attn_o, attn_bf, rp);
  // F-GEMM: 256 blocks (16 batches x 16 m-tiles), fused head epilogue
  k_fgemm<<<256, 512, 114688, stream>>>(attn_bf, p1t, p2, reg_b, cls_b,
                                        anchors, rp);
}

// Round 12
// 460.567 us; speedup vs baseline: 1.7512x; 1.0097x over previous
//
#include <hip/hip_runtime.h>
#include <cmath>

// Problem constants
static constexpr int kB   = 16;
static constexpr int kC   = 64;
static constexpr int kH   = 160;
static constexpr int kW   = 192;
static constexpr int kN   = 1000;
static constexpr int kAFC = 16;
static constexpr int kS   = 96;
static constexpr int kNC  = 2;
static constexpr int kD   = kAFC * kH;     // 2560
static constexpr int kHW  = kH * kW;       // 30720
static constexpr int kNM1 = kN - 1;        // 999
static constexpr int kM   = kB * kN;       // 16000
static constexpr int kRP  = kNC + 3 + 3 * kS; // 293
static constexpr int kK2  = 2 * kD;        // 5120
static constexpr int kNP  = 1024;          // padded N

// Internal feature ordering is d' = h*16 + a (h-major); all internal tensors
// and repacked weights use d' consistently.
// Reassociation: head = attn@(baf@W1^T) + baf@W2^T.

// d_out layout (floats)
static constexpr size_t OFF_RP   = 0;
static constexpr size_t OFF_ATTN = (size_t)kB * kN * kRP;
static constexpr size_t OFF_FEAT = OFF_ATTN + (size_t)kB * kN * kN;

// ws layout (bytes)
static constexpr size_t WB_BAF   = 0;                                    // bf16 [16000][2560]
static constexpr size_t WB_ATTNW = WB_BAF   + (size_t)kM * kD * 2;       // bf16 [1024][2560]
static constexpr size_t WB_WHEAD = WB_ATTNW + (size_t)kNP * kD * 2;      // bf16 [384][5120]
static constexpr size_t WB_ATTNB = WB_WHEAD + (size_t)384 * kK2 * 2;     // bf16 [16][1024][1024]
static constexpr size_t WB_SCORE = WB_ATTNB + (size_t)kB * kNP * kNP * 2;// bf16 [16000][1000]
static constexpr size_t WB_P1T   = WB_SCORE + (size_t)kM * 1000 * 2;     // bf16 [16][384][1024]
static constexpr size_t WB_P2    = WB_P1T   + (size_t)kB * 384 * kNP * 2;// bf16 [16000][384]
static constexpr size_t WB_FLAG  = WB_P2    + (size_t)kM * 384 * 2;      // int

typedef __attribute__((ext_vector_type(8))) short bf16x8;
typedef __attribute__((ext_vector_type(4))) float f32x4;

static __device__ inline short f2bf(float f) {
  union { float f; unsigned u; } x; x.f = f;
  unsigned r = (x.u + 0x7FFFu + ((x.u >> 16) & 1u)) >> 16;
  return (short)r;
}
static __device__ inline float bf2f(short s) {
  union { unsigned u; float f; } x; x.u = ((unsigned)(unsigned short)s) << 16;
  return x.f;
}

#define GLOAD_LDS16(gp, lp) __builtin_amdgcn_global_load_lds( \
    (const __attribute__((address_space(1))) void*)(gp),      \
    (__attribute__((address_space(3))) void*)(lp), 16, 0, 0)

// ---------------- mask dtype detection ----------------
__global__ void k_detect(const unsigned char* __restrict__ m, int* __restrict__ flag) {
  __shared__ int c1, c2, c3;
  if (threadIdx.x == 0) { c1 = 0; c2 = 0; c3 = 0; }
  __syncthreads();
  int l1 = 0, l2 = 0, l3 = 0;
  for (int g = threadIdx.x; g < (kN * kH) / 4; g += blockDim.x) {
    l1 += (m[4 * g + 1] != 0);
    l2 += (m[4 * g + 2] != 0);
    l3 += (m[4 * g + 3] != 0);
  }
  atomicAdd(&c1, l1); atomicAdd(&c2, l2); atomicAdd(&c3, l3);
  __syncthreads();
  if (threadIdx.x == 0) {
    int f;
    if (c1 > 0)            f = 1;  // uint8 bools
    else if (c2 | c3)      f = 2;  // float32 bools
    else                   f = 0;  // int32 bools
    *flag = f;
  }
}

// ---------------- 1x1 conv (fp32, feats is an output) ----------------
__global__ __launch_bounds__(256) void k_conv(const float* __restrict__ bf,
                                              const float* __restrict__ cw,
                                              const float* __restrict__ cb,
                                              float* __restrict__ feats) {
  __shared__ float w[kAFC * kC];
  __shared__ float bsh[kAFC];
  for (int i = threadIdx.x; i < kAFC * kC; i += 256) w[i] = cw[i];
  if (threadIdx.x < kAFC) bsh[threadIdx.x] = cb[threadIdx.x];
  __syncthreads();
  int idx = blockIdx.x * 256 + threadIdx.x;
  if (idx >= kB * kHW) return;
  int b = idx / kHW, p = idx % kHW;
  float acc[kAFC];
#pragma unroll
  for (int o = 0; o < kAFC; o++) acc[o] = bsh[o];
  const float* src = bf + (size_t)b * kC * kHW + p;
#pragma unroll 4
  for (int c = 0; c < kC; c++) {
    float v = src[(size_t)c * kHW];
#pragma unroll
    for (int o = 0; o < kAFC; o++) acc[o] += v * w[o * kC + c];
  }
  float* dst = feats + (size_t)b * kAFC * kHW + p;
#pragma unroll
  for (int o = 0; o < kAFC; o++) dst[(size_t)o * kHW] = acc[o];
}

// ---------------- gather rois -> baf (bf16, d'=h*16+a layout) ---------------
__global__ __launch_bounds__(256) void k_gather(const float* __restrict__ feats,
                                                const int* __restrict__ cut,
                                                const void* __restrict__ mask,
                                                const int* __restrict__ flag,
                                                short* __restrict__ baf) {
  __shared__ float lf[kAFC * 193];   // pad 192->193 to rotate banks per a
  int bid = blockIdx.x;
  int b = bid & 15, h = bid >> 4;
  const float* fbase = feats + (size_t)b * kAFC * kHW + (size_t)h * kW;
  for (int i = threadIdx.x; i < kAFC * kW; i += 256) {
    int a = i / kW, x = i % kW;
    lf[a * 193 + x] = fbase[(size_t)a * kHW + x];
  }
  __syncthreads();
  int f = *flag;
  for (int n = threadIdx.x; n < kN; n += 256) {
    int r = n * kH + h;
    bool inv;
    if (f == 0)      inv = ((const int*)mask)[r] != 0;
    else if (f == 1) inv = ((const unsigned char*)mask)[r] != 0;
    else             inv = ((const float*)mask)[r] != 0.0f;
    bf16x8 v0 = {}, v1 = {};
    if (!inv) {
      int x = cut[r];
#pragma unroll
      for (int a = 0; a < 8; a++)  v0[a] = f2bf(lf[a * 193 + x]);
#pragma unroll
      for (int a = 0; a < 8; a++)  v1[a] = f2bf(lf[(a + 8) * 193 + x]);
    }
    short* dst = baf + (size_t)(b * kN + n) * kD + h * kAFC;
    *(bf16x8*)dst = v0;
    *(bf16x8*)(dst + 8) = v1;
  }
}

// ---- convert attn_w -> bf16 [1024][2560] in d' order (per-row transpose) ---
__global__ __launch_bounds__(256) void k_cvt_attnw(const float* __restrict__ w,
                                                   short* __restrict__ o) {
  __shared__ float lw[kAFC * (kH + 1)];   // 16x161
  int j = blockIdx.x;                      // 0..1023
  short* dst = o + (size_t)j * kD;
  if (j < kNM1) {
    const float* src = w + (size_t)j * kD;
    for (int i = threadIdx.x; i < kD; i += 256) {
      int a = i / kH, h = i % kH;
      lw[a * (kH + 1) + h] = src[i];
    }
    __syncthreads();
    for (int dp = threadIdx.x; dp < kD; dp += 256) {
      int h = dp >> 4, a = dp & 15;
      dst[dp] = f2bf(lw[a * (kH + 1) + h]);
    }
  } else {
    for (int dp = threadIdx.x; dp < kD; dp += 256) dst[dp] = 0;
  }
}

// ---- build head weight bf16 [384][5120], both K-halves in d' order ---------
__global__ __launch_bounds__(256) void k_cvt_whead(const float* __restrict__ reg_w,
                                                   const float* __restrict__ cls_w,
                                                   short* __restrict__ o) {
  __shared__ float lw[2 * kAFC * (kH + 1)];  // 2 x 16 x 161
  int j = blockIdx.x;                        // 0..383
  const float* src = nullptr;
  if (j < 3 * kS)                 src = reg_w + (size_t)j * kK2;
  else if (j < 3 * kS + kNC)      src = cls_w + (size_t)(j - 3 * kS) * kK2;
  short* dst = o + (size_t)j * kK2;
  if (src) {
    for (int i = threadIdx.x; i < kK2; i += 256) {
      int half = i / kD, t = i % kD;
      int a = t / kH, h = t % kH;
      lw[(half * kAFC + a) * (kH + 1) + h] = src[i];
    }
    __syncthreads();
    for (int kp = threadIdx.x; kp < kK2; kp += 256) {
      int half = kp / kD, t = kp % kD;
      int h = t >> 4, a = t & 15;
      dst[kp] = f2bf(lw[(half * kAFC + a) * (kH + 1) + h]);
    }
  } else {
    for (int kp = threadIdx.x; kp < kK2; kp += 256) dst[kp] = 0;
  }
}

// ---------------- softmax: bf16 scores -> attn f32 out + attn bf16 padded ---
// 4 consecutive cols per thread (aligned short4 loads, stride-1000 rows).
__global__ __launch_bounds__(256) void k_softmax(const short* __restrict__ scores,
                                                 const float* __restrict__ anchors,
                                                 float* __restrict__ attn_out,
                                                 short* __restrict__ attn_bf,
                                                 float* __restrict__ rp) {
  int m = blockIdx.x;           // 0..15999
  int b = m / kN;
  int i = m % kN;
  const short* srow = scores + (size_t)m * 1000;
  int tid = threadIdx.x;
  int j0 = tid * 4;
  __shared__ float red[4];
  float v[4];
  if (j0 < 1000) {
    short4 s4 = *(const short4*)(srow + j0);
    v[0] = bf2f(s4.x); v[1] = bf2f(s4.y); v[2] = bf2f(s4.z); v[3] = bf2f(s4.w);
  } else {
    v[0] = v[1] = v[2] = v[3] = -INFINITY;
  }
#pragma unroll
  for (int t = 0; t < 4; t++) if (j0 + t >= kNM1) v[t] = -INFINITY;
  float mx = fmaxf(fmaxf(v[0], v[1]), fmaxf(v[2], v[3]));
#pragma unroll
  for (int o = 32; o; o >>= 1) mx = fmaxf(mx, __shfl_down(mx, o));
  if ((tid & 63) == 0) red[tid >> 6] = mx;
  __syncthreads();
  mx = fmaxf(fmaxf(red[0], red[1]), fmaxf(red[2], red[3]));
  __syncthreads();
  float s = 0.f;
#pragma unroll
  for (int t = 0; t < 4; t++) {
    v[t] = (j0 + t < kNM1) ? __expf(v[t] - mx) : 0.f;
    s += v[t];
  }
#pragma unroll
  for (int o = 32; o; o >>= 1) s += __shfl_down(s, o);
  if ((tid & 63) == 0) red[tid >> 6] = s;
  __syncthreads();
  s = red[0] + red[1] + red[2] + red[3];
  float inv = 1.0f / s;
  float* orow = attn_out + (size_t)m * kN;
  short* brow = attn_bf + ((size_t)b * kNP + i) * kNP;
#pragma unroll
  for (int t = 0; t < 4; t++) {
    int j = j0 + t;
    if (j < kNM1) {
      int dst = j + (j >= i);
      float p = v[t] * inv;
      orow[dst] = p;
      brow[dst] = f2bf(p);
    }
  }
  if (tid == 0) { orow[i] = 0.f; brow[i] = 0; }
  if (tid < kNP - kN) brow[kN + tid] = 0;           // pad cols 1000..1023
  if (tid < 3) rp[(size_t)m * kRP + 2 + tid] = anchors[(size_t)i * kRP + 2 + tid];
}

// ---------------- scores GEMM: 256x256 tile, BK=32, 8 waves, ring ----------
// Counted-vmcnt ring (4 x 32KB, vmcnt(8) steady) + T5 setprio around MFMA.
// Output: bf16 scores, stride 1000.
__global__ __launch_bounds__(512, 2) void k_sgemm(
    const short* __restrict__ A,
    const short* __restrict__ Bt,
    const float* __restrict__ bias,
    short* __restrict__ Cout) {
  extern __shared__ char dls[];                // 128 KB: 4 bufs x (A 16K + B 16K)
  constexpr int NT = kD / 32;                  // 80
  int tid = threadIdx.x, lane = tid & 63, wv = tid >> 6;
  int bid = blockIdx.x;
  int xcd = bid & 7, s = bid >> 3;
  int m0 = (xcd * 8 + (s & 7)) * 256;          // 0..16128 (M padded via clamp)
  int n0 = (s >> 3) * 256;                     // 0..768
  int wm = (wv & 1) * 128, wn = (wv >> 1) * 64;
  f32x4 acc[8][4] = {};

  int r0  = tid >> 2;
  int r1  = (512 + tid) >> 2;
  int ko  = (tid & 3) * 8;
  int ar0 = min(m0 + r0, kM - 1);
  int ar1 = min(m0 + r1, kM - 1);
  const short* gA0 = A + (size_t)ar0 * kD + ko;
  const short* gA1 = A + (size_t)ar1 * kD + ko;
  const short* gB0 = Bt + (size_t)(n0 + r0) * kD + ko;
  const short* gB1 = Bt + (size_t)(n0 + r1) * kD + ko;

  auto STAGE = [&](int tt) {
    char* buf = dls + (size_t)(tt & 3) * 32768;
    int k0 = tt * 32;
    GLOAD_LDS16(gA0 + k0, buf + wv * 1024);
    GLOAD_LDS16(gA1 + k0, buf + 8192 + wv * 1024);
    GLOAD_LDS16(gB0 + k0, buf + 16384 + wv * 1024);
    GLOAD_LDS16(gB1 + k0, buf + 24576 + wv * 1024);
  };

  STAGE(0); STAGE(1); STAGE(2);
  for (int t = 0; t < NT; t++) {
    if (t < NT - 2)       asm volatile("s_waitcnt vmcnt(8)" ::: "memory");
    else if (t == NT - 2) asm volatile("s_waitcnt vmcnt(4)" ::: "memory");
    else                  asm volatile("s_waitcnt vmcnt(0)" ::: "memory");
    __builtin_amdgcn_s_barrier();
    __builtin_amdgcn_sched_barrier(0);
    if (t + 3 < NT) STAGE(t + 3);
    const char* bufA = dls + (size_t)(t & 3) * 32768;
    const char* bufB = bufA + 16384;
    bf16x8 af[8], bg[4];
#pragma unroll
    for (int i = 0; i < 8; i++)
      af[i] = *(const bf16x8*)(bufA + (wm + i * 16 + (lane & 15)) * 64 + (lane >> 4) * 16);
#pragma unroll
    for (int j = 0; j < 4; j++)
      bg[j] = *(const bf16x8*)(bufB + (wn + j * 16 + (lane & 15)) * 64 + (lane >> 4) * 16);
    __builtin_amdgcn_s_setprio(1);
#pragma unroll
    for (int i = 0; i < 8; i++)
#pragma unroll
      for (int j = 0; j < 4; j++)
        acc[i][j] = __builtin_amdgcn_mfma_f32_16x16x32_bf16(af[i], bg[j], acc[i][j], 0, 0, 0);
    __builtin_amdgcn_s_setprio(0);
  }

#pragma unroll
  for (int i = 0; i < 8; i++) {
#pragma unroll
    for (int j = 0; j < 4; j++) {
#pragma unroll
      for (int r = 0; r < 4; r++) {
        int row = m0 + wm + i * 16 + (lane >> 4) * 4 + r;
        int col = n0 + wn + j * 16 + (lane & 15);
        if (row < kM && col < kNM1)
          Cout[(size_t)row * 1000 + col] = f2bf(acc[i][j][r] + bias[col]);
      }
    }
  }
}

// ---------------- P-GEMM: X = baf @ Wstk^T, ring, BM=128, BN=384 ------------
// nb=0: W1 -> p1t[b][col][n] (transposed); nb=1: W2 -> p2 (row-major)
__global__ __launch_bounds__(512, 2) void k_pgemm(
    const short* __restrict__ baf,   // [16000][2560]
    const short* __restrict__ Bt,    // whead [384][5120]
    short* __restrict__ p1t,         // [16][384][1024]
    short* __restrict__ p2) {        // [16000][384]
  extern __shared__ char dls[];      // 128 KB: 4 bufs x (A 8K + B 24K)
  constexpr int NT = kD / 32;        // 80
  int tid = threadIdx.x, lane = tid & 63, wv = tid >> 6;
  int bid = blockIdx.x;
  int nb = bid & 1, mt = bid >> 1;
  int m0 = mt * 128;
  int kofs = nb * kD;

  int wm = (wv & 1) * 64, wn = (wv >> 1) * 96;
  f32x4 acc[4][6] = {};

  int rA = tid >> 2;
  int ko = (tid & 3) * 8;
  const short* gA  = baf + (size_t)(m0 + rA) * kD + ko;
  const short* gB0 = Bt + (size_t)(tid >> 2) * kK2 + kofs + ko;
  const short* gB1 = Bt + (size_t)((512 + tid) >> 2) * kK2 + kofs + ko;
  const short* gB2 = Bt + (size_t)((1024 + tid) >> 2) * kK2 + kofs + ko;

  auto STAGE = [&](int tt) {
    char* buf = dls + (size_t)(tt & 3) * 32768;
    int k0 = tt * 32;
    GLOAD_LDS16(gA + k0,  buf + wv * 1024);
    GLOAD_LDS16(gB0 + k0, buf + 8192 + wv * 1024);
    GLOAD_LDS16(gB1 + k0, buf + 16384 + wv * 1024);
    GLOAD_LDS16(gB2 + k0, buf + 24576 + wv * 1024);
  };

  STAGE(0); STAGE(1); STAGE(2);
  for (int t = 0; t < NT; t++) {
    if (t < NT - 2)       asm volatile("s_waitcnt vmcnt(8)" ::: "memory");
    else if (t == NT - 2) asm volatile("s_waitcnt vmcnt(4)" ::: "memory");
    else                  asm volatile("s_waitcnt vmcnt(0)" ::: "memory");
    __builtin_amdgcn_s_barrier();
    __builtin_amdgcn_sched_barrier(0);
    if (t + 3 < NT) STAGE(t + 3);
    const char* bufA = dls + (size_t)(t & 3) * 32768;
    const char* bufB = bufA + 8192;
    bf16x8 af[4], bg[6];
#pragma unroll
    for (int i = 0; i < 4; i++)
      af[i] = *(const bf16x8*)(bufA + (wm + i * 16 + (lane & 15)) * 64 + (lane >> 4) * 16);
#pragma unroll
    for (int j = 0; j < 6; j++)
      bg[j] = *(const bf16x8*)(bufB + (wn + j * 16 + (lane & 15)) * 64 + (lane >> 4) * 16);
    __builtin_amdgcn_s_setprio(1);
#pragma unroll
    for (int i = 0; i < 4; i++)
#pragma unroll
      for (int j = 0; j < 6; j++)
        acc[i][j] = __builtin_amdgcn_mfma_f32_16x16x32_bf16(af[i], bg[j], acc[i][j], 0, 0, 0);
    __builtin_amdgcn_s_setprio(0);
  }

#pragma unroll
  for (int i = 0; i < 4; i++) {
#pragma unroll
    for (int j = 0; j < 6; j++) {
#pragma unroll
      for (int r = 0; r < 4; r++) {
        int row = m0 + wm + i * 16 + (lane >> 4) * 4 + r;
        int col = wn + j * 16 + (lane & 15);
        short v = f2bf(acc[i][j][r]);
        if (nb == 0) {
          int b = row / kN, n = row - b * kN;
          p1t[((size_t)b * 384 + col) * kNP + n] = v;
        } else {
          p2[(size_t)row * 384 + col] = v;
        }
      }
    }
  }
}

// ---------------- F-GEMM: Y[b] = attn_bf[b] @ p1t[b]^T + p2 + epilogue ------
__global__ __launch_bounds__(512, 2) void k_fgemm(
    const short* __restrict__ attn_bf,  // [16][1024][1024]
    const short* __restrict__ p1t,      // [16][384][1024]
    const short* __restrict__ p2,       // [16000][384]
    const float* __restrict__ reg_b, const float* __restrict__ cls_b,
    const float* __restrict__ anchors, float* __restrict__ rp) {
  extern __shared__ char dls[];      // 112 KB: 4 bufs x (A 4K + B 24K)
  constexpr int NT = kNP / 32;       // 32
  int tid = threadIdx.x, lane = tid & 63, wv = tid >> 6;
  int bid = blockIdx.x;
  int b = bid & 15, mt = bid >> 4;   // XCD = bid&7 -> b in {x, x+8}: p1t L2-hot
  int m0 = mt * 64;
  const short* Ap = attn_bf + (size_t)b * kNP * kNP;
  const short* Bp = p1t + (size_t)b * 384 * kNP;

  int wm = (wv & 1) * 32, wn = (wv >> 1) * 96;
  f32x4 acc[2][6] = {};

  int ciA = tid & 255;
  const short* gA  = Ap + (size_t)(m0 + (ciA >> 2)) * kNP + (ciA & 3) * 8;
  int ko = (tid & 3) * 8;
  const short* gB0 = Bp + (size_t)(tid >> 2) * kNP + ko;
  const short* gB1 = Bp + (size_t)((512 + tid) >> 2) * kNP + ko;
  const short* gB2 = Bp + (size_t)((1024 + tid) >> 2) * kNP + ko;

  auto STAGE = [&](int tt) {
    char* buf = dls + (size_t)(tt & 3) * 28672;
    int k0 = tt * 32;
    GLOAD_LDS16(gA + k0,  buf + (wv & 3) * 1024);
    GLOAD_LDS16(gB0 + k0, buf + 4096 + wv * 1024);
    GLOAD_LDS16(gB1 + k0, buf + 12288 + wv * 1024);
    GLOAD_LDS16(gB2 + k0, buf + 20480 + wv * 1024);
  };

  STAGE(0); STAGE(1); STAGE(2);
  for (int t = 0; t < NT; t++) {
    if (t < NT - 2)       asm volatile("s_waitcnt vmcnt(8)" ::: "memory");
    else if (t == NT - 2) asm volatile("s_waitcnt vmcnt(4)" ::: "memory");
    else                  asm volatile("s_waitcnt vmcnt(0)" ::: "memory");
    __builtin_amdgcn_s_barrier();
    __builtin_amdgcn_sched_barrier(0);
    if (t + 3 < NT) STAGE(t + 3);
    const char* bufA = dls + (size_t)(t & 3) * 28672;
    const char* bufB = bufA + 4096;
    bf16x8 af[2], bg[6];
#pragma unroll
    for (int i = 0; i < 2; i++)
      af[i] = *(const bf16x8*)(bufA + (wm + i * 16 + (lane & 15)) * 64 + (lane >> 4) * 16);
#pragma unroll
    for (int j = 0; j < 6; j++)
      bg[j] = *(const bf16x8*)(bufB + (wn + j * 16 + (lane & 15)) * 64 + (lane >> 4) * 16);
    __builtin_amdgcn_s_setprio(1);
#pragma unroll
    for (int i = 0; i < 2; i++)
#pragma unroll
      for (int j = 0; j < 6; j++)
        acc[i][j] = __builtin_amdgcn_mfma_f32_16x16x32_bf16(af[i], bg[j], acc[i][j], 0, 0, 0);
    __builtin_amdgcn_s_setprio(0);
  }

#pragma unroll
  for (int i = 0; i < 2; i++) {
#pragma unroll
    for (int j = 0; j < 6; j++) {
#pragma unroll
      for (int r = 0; r < 4; r++) {
        int n = m0 + wm + i * 16 + (lane >> 4) * 4 + r;   // 0..1023
        int col = wn + j * 16 + (lane & 15);              // 0..383
        if (n < kN) {
          size_t row = (size_t)b * kN + n;
          float v = acc[i][j][r] + bf2f(p2[row * 384 + col]);
          if (col < 3 * kS) {
            float tv = v + reg_b[col];
            if (col >= 2 * kS) tv = 1.0f / (1.0f + __expf(-tv));
            rp[row * kRP + 5 + col] = anchors[(size_t)n * kRP + 5 + col] + tv;
          } else if (col < 3 * kS + kNC) {
            rp[row * kRP + (col - 3 * kS)] = v + cls_b[col - 3 * kS];
          }
        }
      }
    }
  }
}

extern "C" void kernel_launch(void* const* d_in, const int* in_sizes, int n_in,
                              void* d_out, int out_size, void* d_ws, size_t ws_size,
                              hipStream_t stream) {
  const float* bf      = (const float*)d_in[0];
  const float* conv_w  = (const float*)d_in[1];
  const float* conv_b  = (const float*)d_in[2];
  const int*   cut     = (const int*)d_in[3];
  const void*  mask    = d_in[4];
  const float* anchors = (const float*)d_in[5];
  const float* attn_w  = (const float*)d_in[6];
  const float* attn_b  = (const float*)d_in[7];
  const float* cls_w   = (const float*)d_in[8];
  const float* cls_b   = (const float*)d_in[9];
  const float* reg_w   = (const float*)d_in[10];
  const float* reg_b   = (const float*)d_in[11];

  float* out    = (float*)d_out;
  float* rp     = out + OFF_RP;
  float* attn_o = out + OFF_ATTN;
  float* feats  = out + OFF_FEAT;

  char*  ws      = (char*)d_ws;
  short* baf     = (short*)(ws + WB_BAF);
  short* attnw   = (short*)(ws + WB_ATTNW);
  short* whead   = (short*)(ws + WB_WHEAD);
  short* attn_bf = (short*)(ws + WB_ATTNB);
  short* scores  = (short*)(ws + WB_SCORE);
  short* p1t     = (short*)(ws + WB_P1T);
  short* p2      = (short*)(ws + WB_P2);
  int*   flag    = (int*)(ws + WB_FLAG);

  k_detect<<<1, 256, 0, stream>>>((const unsigned char*)mask, flag);
  k_conv<<<(kB * kHW) / 256, 256, 0, stream>>>(bf, conv_w, conv_b, feats);
  k_gather<<<kB * kH, 256, 0, stream>>>(feats, cut, mask, flag, baf);
  k_cvt_attnw<<<kNP, 256, 0, stream>>>(attn_w, attnw);
  k_cvt_whead<<<384, 256, 0, stream>>>(reg_w, cls_w, whead);
  // P-GEMM: 250 blocks (125 m-tiles x 2 n-halves)
  k_pgemm<<<2 * (kM / 128), 512, 131072, stream>>>(baf, whead, p1t, p2);
  // scores GEMM: 256 blocks (64 m-tiles x 4 n-tiles, XCD owns 8 m-tiles)
  k_sgemm<<<256, 512, 131072, stream>>>(baf, attnw, attn_b, scores);
  k_softmax<<<kM, 256, 0, stream>>>(scores, anchors, attn_o, attn_bf, rp);
  // F-GEMM: 256 blocks (16 batches x 16 m-tiles), fused head epilogue
  k_fgemm<<<256, 512, 114688, stream>>>(attn_bf, p1t, p2, reg_b, cls_b,
                                        anchors, rp);
}

// Round 13
// 453.019 us; speedup vs baseline: 1.7804x; 1.0167x over previous
//
#include <hip/hip_runtime.h>
#include <cmath>

// Problem constants
static constexpr int kB   = 16;
static constexpr int kC   = 64;
static constexpr int kH   = 160;
static constexpr int kW   = 192;
static constexpr int kN   = 1000;
static constexpr int kAFC = 16;
static constexpr int kS   = 96;
static constexpr int kNC  = 2;
static constexpr int kD   = kAFC * kH;     // 2560
static constexpr int kHW  = kH * kW;       // 30720
static constexpr int kNM1 = kN - 1;        // 999
static constexpr int kM   = kB * kN;       // 16000
static constexpr int kRP  = kNC + 3 + 3 * kS; // 293
static constexpr int kK2  = 2 * kD;        // 5120
static constexpr int kNP  = 1024;          // padded N

// Internal feature ordering is d' = h*16 + a (h-major); all internal tensors
// and repacked weights use d' consistently.
// Reassociation: head = attn@(baf@W1^T) + baf@W2^T.
//
// Ring-kernel LDS swizzle (T2, both-sides per rule #21): LDS byte (row, c)
// holds global k-chunk (c/16) ^ ((row>>1)&3). Staging keeps dest linear and
// pre-swizzles the GLOBAL k-offset; ds_read swizzles the column. Kills the
// 8-way bank conflict of the unswizzled row*64 layout (slots 0,4 only).

// d_out layout (floats)
static constexpr size_t OFF_RP   = 0;
static constexpr size_t OFF_ATTN = (size_t)kB * kN * kRP;
static constexpr size_t OFF_FEAT = OFF_ATTN + (size_t)kB * kN * kN;

// ws layout (bytes)
static constexpr size_t WB_BAF   = 0;                                    // bf16 [16000][2560]
static constexpr size_t WB_ATTNW = WB_BAF   + (size_t)kM * kD * 2;       // bf16 [1024][2560]
static constexpr size_t WB_WHEAD = WB_ATTNW + (size_t)kNP * kD * 2;      // bf16 [384][5120]
static constexpr size_t WB_ATTNB = WB_WHEAD + (size_t)384 * kK2 * 2;     // bf16 [16][1024][1024]
static constexpr size_t WB_SCORE = WB_ATTNB + (size_t)kB * kNP * kNP * 2;// bf16 [16000][1000]
static constexpr size_t WB_P1T   = WB_SCORE + (size_t)kM * 1000 * 2;     // bf16 [16][384][1024]
static constexpr size_t WB_P2    = WB_P1T   + (size_t)kB * 384 * kNP * 2;// bf16 [16000][384]
static constexpr size_t WB_FLAG  = WB_P2    + (size_t)kM * 384 * 2;      // int

typedef __attribute__((ext_vector_type(8))) short bf16x8;
typedef __attribute__((ext_vector_type(4))) float f32x4;

static __device__ inline short f2bf(float f) {
  union { float f; unsigned u; } x; x.f = f;
  unsigned r = (x.u + 0x7FFFu + ((x.u >> 16) & 1u)) >> 16;
  return (short)r;
}
static __device__ inline float bf2f(short s) {
  union { unsigned u; float f; } x; x.u = ((unsigned)(unsigned short)s) << 16;
  return x.f;
}

#define GLOAD_LDS16(gp, lp) __builtin_amdgcn_global_load_lds( \
    (const __attribute__((address_space(1))) void*)(gp),      \
    (__attribute__((address_space(3))) void*)(lp), 16, 0, 0)

// ---------------- mask dtype detection ----------------
__global__ void k_detect(const unsigned char* __restrict__ m, int* __restrict__ flag) {
  __shared__ int c1, c2, c3;
  if (threadIdx.x == 0) { c1 = 0; c2 = 0; c3 = 0; }
  __syncthreads();
  int l1 = 0, l2 = 0, l3 = 0;
  for (int g = threadIdx.x; g < (kN * kH) / 4; g += blockDim.x) {
    l1 += (m[4 * g + 1] != 0);
    l2 += (m[4 * g + 2] != 0);
    l3 += (m[4 * g + 3] != 0);
  }
  atomicAdd(&c1, l1); atomicAdd(&c2, l2); atomicAdd(&c3, l3);
  __syncthreads();
  if (threadIdx.x == 0) {
    int f;
    if (c1 > 0)            f = 1;  // uint8 bools
    else if (c2 | c3)      f = 2;  // float32 bools
    else                   f = 0;  // int32 bools
    *flag = f;
  }
}

// ---------------- 1x1 conv (fp32, feats is an output) ----------------
__global__ __launch_bounds__(256) void k_conv(const float* __restrict__ bf,
                                              const float* __restrict__ cw,
                                              const float* __restrict__ cb,
                                              float* __restrict__ feats) {
  __shared__ float w[kAFC * kC];
  __shared__ float bsh[kAFC];
  for (int i = threadIdx.x; i < kAFC * kC; i += 256) w[i] = cw[i];
  if (threadIdx.x < kAFC) bsh[threadIdx.x] = cb[threadIdx.x];
  __syncthreads();
  int idx = blockIdx.x * 256 + threadIdx.x;
  if (idx >= kB * kHW) return;
  int b = idx / kHW, p = idx % kHW;
  float acc[kAFC];
#pragma unroll
  for (int o = 0; o < kAFC; o++) acc[o] = bsh[o];
  const float* src = bf + (size_t)b * kC * kHW + p;
#pragma unroll 4
  for (int c = 0; c < kC; c++) {
    float v = src[(size_t)c * kHW];
#pragma unroll
    for (int o = 0; o < kAFC; o++) acc[o] += v * w[o * kC + c];
  }
  float* dst = feats + (size_t)b * kAFC * kHW + p;
#pragma unroll
  for (int o = 0; o < kAFC; o++) dst[(size_t)o * kHW] = acc[o];
}

// ---------------- gather rois -> baf (bf16, d'=h*16+a layout) ---------------
__global__ __launch_bounds__(256) void k_gather(const float* __restrict__ feats,
                                                const int* __restrict__ cut,
                                                const void* __restrict__ mask,
                                                const int* __restrict__ flag,
                                                short* __restrict__ baf) {
  __shared__ float lf[kAFC * 193];   // pad 192->193 to rotate banks per a
  int bid = blockIdx.x;
  int b = bid & 15, h = bid >> 4;
  const float* fbase = feats + (size_t)b * kAFC * kHW + (size_t)h * kW;
  for (int i = threadIdx.x; i < kAFC * kW; i += 256) {
    int a = i / kW, x = i % kW;
    lf[a * 193 + x] = fbase[(size_t)a * kHW + x];
  }
  __syncthreads();
  int f = *flag;
  for (int n = threadIdx.x; n < kN; n += 256) {
    int r = n * kH + h;
    bool inv;
    if (f == 0)      inv = ((const int*)mask)[r] != 0;
    else if (f == 1) inv = ((const unsigned char*)mask)[r] != 0;
    else             inv = ((const float*)mask)[r] != 0.0f;
    bf16x8 v0 = {}, v1 = {};
    if (!inv) {
      int x = cut[r];
#pragma unroll
      for (int a = 0; a < 8; a++)  v0[a] = f2bf(lf[a * 193 + x]);
#pragma unroll
      for (int a = 0; a < 8; a++)  v1[a] = f2bf(lf[(a + 8) * 193 + x]);
    }
    short* dst = baf + (size_t)(b * kN + n) * kD + h * kAFC;
    *(bf16x8*)dst = v0;
    *(bf16x8*)(dst + 8) = v1;
  }
}

// ---- convert attn_w -> bf16 [1024][2560] in d' order (per-row transpose) ---
__global__ __launch_bounds__(256) void k_cvt_attnw(const float* __restrict__ w,
                                                   short* __restrict__ o) {
  __shared__ float lw[kAFC * (kH + 1)];   // 16x161
  int j = blockIdx.x;                      // 0..1023
  short* dst = o + (size_t)j * kD;
  if (j < kNM1) {
    const float* src = w + (size_t)j * kD;
    for (int i = threadIdx.x; i < kD; i += 256) {
      int a = i / kH, h = i % kH;
      lw[a * (kH + 1) + h] = src[i];
    }
    __syncthreads();
    for (int dp = threadIdx.x; dp < kD; dp += 256) {
      int h = dp >> 4, a = dp & 15;
      dst[dp] = f2bf(lw[a * (kH + 1) + h]);
    }
  } else {
    for (int dp = threadIdx.x; dp < kD; dp += 256) dst[dp] = 0;
  }
}

// ---- build head weight bf16 [384][5120], both K-halves in d' order ---------
__global__ __launch_bounds__(256) void k_cvt_whead(const float* __restrict__ reg_w,
                                                   const float* __restrict__ cls_w,
                                                   short* __restrict__ o) {
  __shared__ float lw[2 * kAFC * (kH + 1)];  // 2 x 16 x 161
  int j = blockIdx.x;                        // 0..383
  const float* src = nullptr;
  if (j < 3 * kS)                 src = reg_w + (size_t)j * kK2;
  else if (j < 3 * kS + kNC)      src = cls_w + (size_t)(j - 3 * kS) * kK2;
  short* dst = o + (size_t)j * kK2;
  if (src) {
    for (int i = threadIdx.x; i < kK2; i += 256) {
      int half = i / kD, t = i % kD;
      int a = t / kH, h = t % kH;
      lw[(half * kAFC + a) * (kH + 1) + h] = src[i];
    }
    __syncthreads();
    for (int kp = threadIdx.x; kp < kK2; kp += 256) {
      int half = kp / kD, t = kp % kD;
      int h = t >> 4, a = t & 15;
      dst[kp] = f2bf(lw[(half * kAFC + a) * (kH + 1) + h]);
    }
  } else {
    for (int kp = threadIdx.x; kp < kK2; kp += 256) dst[kp] = 0;
  }
}

// ---------------- softmax: bf16 scores -> attn f32 out + attn bf16 padded ---
__global__ __launch_bounds__(256) void k_softmax(const short* __restrict__ scores,
                                                 const float* __restrict__ anchors,
                                                 float* __restrict__ attn_out,
                                                 short* __restrict__ attn_bf,
                                                 float* __restrict__ rp) {
  int m = blockIdx.x;           // 0..15999
  int b = m / kN;
  int i = m % kN;
  const short* srow = scores + (size_t)m * 1000;
  int tid = threadIdx.x;
  int j0 = tid * 4;
  __shared__ float red[4];
  float v[4];
  if (j0 < 1000) {
    short4 s4 = *(const short4*)(srow + j0);
    v[0] = bf2f(s4.x); v[1] = bf2f(s4.y); v[2] = bf2f(s4.z); v[3] = bf2f(s4.w);
  } else {
    v[0] = v[1] = v[2] = v[3] = -INFINITY;
  }
#pragma unroll
  for (int t = 0; t < 4; t++) if (j0 + t >= kNM1) v[t] = -INFINITY;
  float mx = fmaxf(fmaxf(v[0], v[1]), fmaxf(v[2], v[3]));
#pragma unroll
  for (int o = 32; o; o >>= 1) mx = fmaxf(mx, __shfl_down(mx, o));
  if ((tid & 63) == 0) red[tid >> 6] = mx;
  __syncthreads();
  mx = fmaxf(fmaxf(red[0], red[1]), fmaxf(red[2], red[3]));
  __syncthreads();
  float s = 0.f;
#pragma unroll
  for (int t = 0; t < 4; t++) {
    v[t] = (j0 + t < kNM1) ? __expf(v[t] - mx) : 0.f;
    s += v[t];
  }
#pragma unroll
  for (int o = 32; o; o >>= 1) s += __shfl_down(s, o);
  if ((tid & 63) == 0) red[tid >> 6] = s;
  __syncthreads();
  s = red[0] + red[1] + red[2] + red[3];
  float inv = 1.0f / s;
  float* orow = attn_out + (size_t)m * kN;
  short* brow = attn_bf + ((size_t)b * kNP + i) * kNP;
#pragma unroll
  for (int t = 0; t < 4; t++) {
    int j = j0 + t;
    if (j < kNM1) {
      int dst = j + (j >= i);
      float p = v[t] * inv;
      orow[dst] = p;
      brow[dst] = f2bf(p);
    }
  }
  if (tid == 0) { orow[i] = 0.f; brow[i] = 0; }
  if (tid < kNP - kN) brow[kN + tid] = 0;           // pad cols 1000..1023
  if (tid < 3) rp[(size_t)m * kRP + 2 + tid] = anchors[(size_t)i * kRP + 2 + tid];
}

// ---------------- scores GEMM: 256x256 tile, BK=32, 8 waves, ring ----------
// Counted-vmcnt ring (4 x 32KB, vmcnt(8) steady) + LDS XOR-swizzle.
__global__ __launch_bounds__(512, 2) void k_sgemm(
    const short* __restrict__ A,
    const short* __restrict__ Bt,
    const float* __restrict__ bias,
    short* __restrict__ Cout) {
  extern __shared__ char dls[];                // 128 KB: 4 bufs x (A 16K + B 16K)
  constexpr int NT = kD / 32;                  // 80
  int tid = threadIdx.x, lane = tid & 63, wv = tid >> 6;
  int bid = blockIdx.x;
  int xcd = bid & 7, s = bid >> 3;
  int m0 = (xcd * 8 + (s & 7)) * 256;          // 0..16128 (M padded via clamp)
  int n0 = (s >> 3) * 256;                     // 0..768
  int wm = (wv & 1) * 128, wn = (wv >> 1) * 64;
  f32x4 acc[8][4] = {};

  int r0  = tid >> 2;
  int r1  = (512 + tid) >> 2;
  int swzko = (((tid & 3) ^ ((tid >> 3) & 3)) * 8);   // pre-swizzled k-offset
  int ar0 = min(m0 + r0, kM - 1);
  int ar1 = min(m0 + r1, kM - 1);
  const short* gA0 = A + (size_t)ar0 * kD + swzko;
  const short* gA1 = A + (size_t)ar1 * kD + swzko;
  const short* gB0 = Bt + (size_t)(n0 + r0) * kD + swzko;
  const short* gB1 = Bt + (size_t)(n0 + r1) * kD + swzko;

  auto STAGE = [&](int tt) {
    char* buf = dls + (size_t)(tt & 3) * 32768;
    int k0 = tt * 32;
    GLOAD_LDS16(gA0 + k0, buf + wv * 1024);
    GLOAD_LDS16(gA1 + k0, buf + 8192 + wv * 1024);
    GLOAD_LDS16(gB0 + k0, buf + 16384 + wv * 1024);
    GLOAD_LDS16(gB1 + k0, buf + 24576 + wv * 1024);
  };

  int cswz = (((lane >> 4) ^ ((lane >> 1) & 3)) * 16); // swizzled read column

  STAGE(0); STAGE(1); STAGE(2);
  for (int t = 0; t < NT; t++) {
    if (t < NT - 2)       asm volatile("s_waitcnt vmcnt(8)" ::: "memory");
    else if (t == NT - 2) asm volatile("s_waitcnt vmcnt(4)" ::: "memory");
    else                  asm volatile("s_waitcnt vmcnt(0)" ::: "memory");
    __builtin_amdgcn_s_barrier();
    __builtin_amdgcn_sched_barrier(0);
    if (t + 3 < NT) STAGE(t + 3);
    const char* bufA = dls + (size_t)(t & 3) * 32768;
    const char* bufB = bufA + 16384;
    bf16x8 af[8], bg[4];
#pragma unroll
    for (int i = 0; i < 8; i++)
      af[i] = *(const bf16x8*)(bufA + (wm + i * 16 + (lane & 15)) * 64 + cswz);
#pragma unroll
    for (int j = 0; j < 4; j++)
      bg[j] = *(const bf16x8*)(bufB + (wn + j * 16 + (lane & 15)) * 64 + cswz);
    __builtin_amdgcn_s_setprio(1);
#pragma unroll
    for (int i = 0; i < 8; i++)
#pragma unroll
      for (int j = 0; j < 4; j++)
        acc[i][j] = __builtin_amdgcn_mfma_f32_16x16x32_bf16(af[i], bg[j], acc[i][j], 0, 0, 0);
    __builtin_amdgcn_s_setprio(0);
  }

#pragma unroll
  for (int i = 0; i < 8; i++) {
#pragma unroll
    for (int j = 0; j < 4; j++) {
#pragma unroll
      for (int r = 0; r < 4; r++) {
        int row = m0 + wm + i * 16 + (lane >> 4) * 4 + r;
        int col = n0 + wn + j * 16 + (lane & 15);
        if (row < kM && col < kNM1)
          Cout[(size_t)row * 1000 + col] = f2bf(acc[i][j][r] + bias[col]);
      }
    }
  }
}

// ---------------- P-GEMM: X = baf @ Wstk^T, ring, BM=128, BN=384 ------------
// nb=0: W1 -> p1t[b][col][n] (transposed); nb=1: W2 -> p2 (row-major)
__global__ __launch_bounds__(512, 2) void k_pgemm(
    const short* __restrict__ baf,   // [16000][2560]
    const short* __restrict__ Bt,    // whead [384][5120]
    short* __restrict__ p1t,         // [16][384][1024]
    short* __restrict__ p2) {        // [16000][384]
  extern __shared__ char dls[];      // 128 KB: 4 bufs x (A 8K + B 24K)
  constexpr int NT = kD / 32;        // 80
  int tid = threadIdx.x, lane = tid & 63, wv = tid >> 6;
  int bid = blockIdx.x;
  int nb = bid & 1, mt = bid >> 1;
  int m0 = mt * 128;
  int kofs = nb * kD;

  int wm = (wv & 1) * 64, wn = (wv >> 1) * 96;
  f32x4 acc[4][6] = {};

  int rA = tid >> 2;
  int swzko = (((tid & 3) ^ ((tid >> 3) & 3)) * 8);
  const short* gA  = baf + (size_t)(m0 + rA) * kD + swzko;
  const short* gB0 = Bt + (size_t)(tid >> 2) * kK2 + kofs + swzko;
  const short* gB1 = Bt + (size_t)((512 + tid) >> 2) * kK2 + kofs + swzko;
  const short* gB2 = Bt + (size_t)((1024 + tid) >> 2) * kK2 + kofs + swzko;

  auto STAGE = [&](int tt) {
    char* buf = dls + (size_t)(tt & 3) * 32768;
    int k0 = tt * 32;
    GLOAD_LDS16(gA + k0,  buf + wv * 1024);
    GLOAD_LDS16(gB0 + k0, buf + 8192 + wv * 1024);
    GLOAD_LDS16(gB1 + k0, buf + 16384 + wv * 1024);
    GLOAD_LDS16(gB2 + k0, buf + 24576 + wv * 1024);
  };

  int cswz = (((lane >> 4) ^ ((lane >> 1) & 3)) * 16);

  STAGE(0); STAGE(1); STAGE(2);
  for (int t = 0; t < NT; t++) {
    if (t < NT - 2)       asm volatile("s_waitcnt vmcnt(8)" ::: "memory");
    else if (t == NT - 2) asm volatile("s_waitcnt vmcnt(4)" ::: "memory");
    else                  asm volatile("s_waitcnt vmcnt(0)" ::: "memory");
    __builtin_amdgcn_s_barrier();
    __builtin_amdgcn_sched_barrier(0);
    if (t + 3 < NT) STAGE(t + 3);
    const char* bufA = dls + (size_t)(t & 3) * 32768;
    const char* bufB = bufA + 8192;
    bf16x8 af[4], bg[6];
#pragma unroll
    for (int i = 0; i < 4; i++)
      af[i] = *(const bf16x8*)(bufA + (wm + i * 16 + (lane & 15)) * 64 + cswz);
#pragma unroll
    for (int j = 0; j < 6; j++)
      bg[j] = *(const bf16x8*)(bufB + (wn + j * 16 + (lane & 15)) * 64 + cswz);
    __builtin_amdgcn_s_setprio(1);
#pragma unroll
    for (int i = 0; i < 4; i++)
#pragma unroll
      for (int j = 0; j < 6; j++)
        acc[i][j] = __builtin_amdgcn_mfma_f32_16x16x32_bf16(af[i], bg[j], acc[i][j], 0, 0, 0);
    __builtin_amdgcn_s_setprio(0);
  }

#pragma unroll
  for (int i = 0; i < 4; i++) {
#pragma unroll
    for (int j = 0; j < 6; j++) {
#pragma unroll
      for (int r = 0; r < 4; r++) {
        int row = m0 + wm + i * 16 + (lane >> 4) * 4 + r;
        int col = wn + j * 16 + (lane & 15);
        short v = f2bf(acc[i][j][r]);
        if (nb == 0) {
          int b = row / kN, n = row - b * kN;
          p1t[((size_t)b * 384 + col) * kNP + n] = v;
        } else {
          p2[(size_t)row * 384 + col] = v;
        }
      }
    }
  }
}

// ---------------- F-GEMM: Y[b] = attn_bf[b] @ p1t[b]^T + p2 + epilogue ------
__global__ __launch_bounds__(512, 2) void k_fgemm(
    const short* __restrict__ attn_bf,  // [16][1024][1024]
    const short* __restrict__ p1t,      // [16][384][1024]
    const short* __restrict__ p2,       // [16000][384]
    const float* __restrict__ reg_b, const float* __restrict__ cls_b,
    const float* __restrict__ anchors, float* __restrict__ rp) {
  extern __shared__ char dls[];      // 112 KB: 4 bufs x (A 4K + B 24K)
  constexpr int NT = kNP / 32;       // 32
  int tid = threadIdx.x, lane = tid & 63, wv = tid >> 6;
  int bid = blockIdx.x;
  int b = bid & 15, mt = bid >> 4;   // XCD = bid&7 -> b in {x, x+8}: p1t L2-hot
  int m0 = mt * 64;
  const short* Ap = attn_bf + (size_t)b * kNP * kNP;
  const short* Bp = p1t + (size_t)b * 384 * kNP;

  int wm = (wv & 1) * 32, wn = (wv >> 1) * 96;
  f32x4 acc[2][6] = {};

  int ciA = tid & 255;
  int swzkoA = (((ciA & 3) ^ ((ciA >> 3) & 3)) * 8);
  int swzko  = (((tid & 3) ^ ((tid >> 3) & 3)) * 8);
  const short* gA  = Ap + (size_t)(m0 + (ciA >> 2)) * kNP + swzkoA;
  const short* gB0 = Bp + (size_t)(tid >> 2) * kNP + swzko;
  const short* gB1 = Bp + (size_t)((512 + tid) >> 2) * kNP + swzko;
  const short* gB2 = Bp + (size_t)((1024 + tid) >> 2) * kNP + swzko;

  auto STAGE = [&](int tt) {
    char* buf = dls + (size_t)(tt & 3) * 28672;
    int k0 = tt * 32;
    GLOAD_LDS16(gA + k0,  buf + (wv & 3) * 1024);
    GLOAD_LDS16(gB0 + k0, buf + 4096 + wv * 1024);
    GLOAD_LDS16(gB1 + k0, buf + 12288 + wv * 1024);
    GLOAD_LDS16(gB2 + k0, buf + 20480 + wv * 1024);
  };

  int cswz = (((lane >> 4) ^ ((lane >> 1) & 3)) * 16);

  STAGE(0); STAGE(1); STAGE(2);
  for (int t = 0; t < NT; t++) {
    if (t < NT - 2)       asm volatile("s_waitcnt vmcnt(8)" ::: "memory");
    else if (t == NT - 2) asm volatile("s_waitcnt vmcnt(4)" ::: "memory");
    else                  asm volatile("s_waitcnt vmcnt(0)" ::: "memory");
    __builtin_amdgcn_s_barrier();
    __builtin_amdgcn_sched_barrier(0);
    if (t + 3 < NT) STAGE(t + 3);
    const char* bufA = dls + (size_t)(t & 3) * 28672;
    const char* bufB = bufA + 4096;
    bf16x8 af[2], bg[6];
#pragma unroll
    for (int i = 0; i < 2; i++)
      af[i] = *(const bf16x8*)(bufA + (wm + i * 16 + (lane & 15)) * 64 + cswz);
#pragma unroll
    for (int j = 0; j < 6; j++)
      bg[j] = *(const bf16x8*)(bufB + (wn + j * 16 + (lane & 15)) * 64 + cswz);
    __builtin_amdgcn_s_setprio(1);
#pragma unroll
    for (int i = 0; i < 2; i++)
#pragma unroll
      for (int j = 0; j < 6; j++)
        acc[i][j] = __builtin_amdgcn_mfma_f32_16x16x32_bf16(af[i], bg[j], acc[i][j], 0, 0, 0);
    __builtin_amdgcn_s_setprio(0);
  }

#pragma unroll
  for (int i = 0; i < 2; i++) {
#pragma unroll
    for (int j = 0; j < 6; j++) {
#pragma unroll
      for (int r = 0; r < 4; r++) {
        int n = m0 + wm + i * 16 + (lane >> 4) * 4 + r;   // 0..1023
        int col = wn + j * 16 + (lane & 15);              // 0..383
        if (n < kN) {
          size_t row = (size_t)b * kN + n;
          float v = acc[i][j][r] + bf2f(p2[row * 384 + col]);
          if (col < 3 * kS) {
            float tv = v + reg_b[col];
            if (col >= 2 * kS) tv = 1.0f / (1.0f + __expf(-tv));
            rp[row * kRP + 5 + col] = anchors[(size_t)n * kRP + 5 + col] + tv;
          } else if (col < 3 * kS + kNC) {
            rp[row * kRP + (col - 3 * kS)] = v + cls_b[col - 3 * kS];
          }
        }
      }
    }
  }
}

extern "C" void kernel_launch(void* const* d_in, const int* in_sizes, int n_in,
                              void* d_out, int out_size, void* d_ws, size_t ws_size,
                              hipStream_t stream) {
  const float* bf      = (const float*)d_in[0];
  const float* conv_w  = (const float*)d_in[1];
  const float* conv_b  = (const float*)d_in[2];
  const int*   cut     = (const int*)d_in[3];
  const void*  mask    = d_in[4];
  const float* anchors = (const float*)d_in[5];
  const float* attn_w  = (const float*)d_in[6];
  const float* attn_b  = (const float*)d_in[7];
  const float* cls_w   = (const float*)d_in[8];
  const float* cls_b   = (const float*)d_in[9];
  const float* reg_w   = (const float*)d_in[10];
  const float* reg_b   = (const float*)d_in[11];

  float* out    = (float*)d_out;
  float* rp     = out + OFF_RP;
  float* attn_o = out + OFF_ATTN;
  float* feats  = out + OFF_FEAT;

  char*  ws      = (char*)d_ws;
  short* baf     = (short*)(ws + WB_BAF);
  short* attnw   = (short*)(ws + WB_ATTNW);
  short* whead   = (short*)(ws + WB_WHEAD);
  short* attn_bf = (short*)(ws + WB_ATTNB);
  short* scores  = (short*)(ws + WB_SCORE);
  short* p1t     = (short*)(ws + WB_P1T);
  short* p2      = (short*)(ws + WB_P2);
  int*   flag    = (int*)(ws + WB_FLAG);

  k_detect<<<1, 256, 0, stream>>>((const unsigned char*)mask, flag);
  k_conv<<<(kB * kHW) / 256, 256, 0, stream>>>(bf, conv_w, conv_b, feats);
  k_gather<<<kB * kH, 256, 0, stream>>>(feats, cut, mask, flag, baf);
  k_cvt_attnw<<<kNP, 256, 0, stream>>>(attn_w, attnw);
  k_cvt_whead<<<384, 256, 0, stream>>>(reg_w, cls_w, whead);
  // P-GEMM: 250 blocks (125 m-tiles x 2 n-halves)
  k_pgemm<<<2 * (kM / 128), 512, 131072, stream>>>(baf, whead, p1t, p2);
  // scores GEMM: 256 blocks (64 m-tiles x 4 n-tiles, XCD owns 8 m-tiles)
  k_sgemm<<<256, 512, 131072, stream>>>(baf, attnw, attn_b, scores);
  k_softmax<<<kM, 256, 0, stream>>>(scores, anchors, attn_o, attn_bf, rp);
  // F-GEMM: 256 blocks (16 batches x 16 m-tiles), fused head epilogue
  k_fgemm<<<256, 512, 114688, stream>>>(attn_bf, p1t, p2, reg_b, cls_b,
                                        anchors, rp);
}

// Round 14
// 419.430 us; speedup vs baseline: 1.9230x; 1.0801x over previous
//
#include <hip/hip_runtime.h>
#include <cmath>

// Problem constants
static constexpr int kB   = 16;
static constexpr int kC   = 64;
static constexpr int kH   = 160;
static constexpr int kW   = 192;
static constexpr int kN   = 1000;
static constexpr int kAFC = 16;
static constexpr int kS   = 96;
static constexpr int kNC  = 2;
static constexpr int kD   = kAFC * kH;     // 2560
static constexpr int kHW  = kH * kW;       // 30720
static constexpr int kNM1 = kN - 1;        // 999
static constexpr int kM   = kB * kN;       // 16000
static constexpr int kRP  = kNC + 3 + 3 * kS; // 293
static constexpr int kK2  = 2 * kD;        // 5120
static constexpr int kNP  = 1024;          // padded N

// Internal feature ordering is d' = h*16 + a (h-major); all internal tensors
// and repacked weights use d' consistently.
// Reassociation: head = attn@(baf@W1^T) + baf@W2^T.
// Ring-kernel LDS swizzle: pre-swizzled global src + swizzled read col
// (verified round 13: SQ_LDS_BANK_CONFLICT 7.86M -> 0).

// d_out layout (floats)
static constexpr size_t OFF_RP   = 0;
static constexpr size_t OFF_ATTN = (size_t)kB * kN * kRP;
static constexpr size_t OFF_FEAT = OFF_ATTN + (size_t)kB * kN * kN;

// ws layout (bytes)
static constexpr size_t WB_BAF   = 0;                                    // bf16 [16000][2560]
static constexpr size_t WB_ATTNW = WB_BAF   + (size_t)kM * kD * 2;       // bf16 [1024][2560]
static constexpr size_t WB_WHEAD = WB_ATTNW + (size_t)kNP * kD * 2;      // bf16 [384][5120]
static constexpr size_t WB_ATTNB = WB_WHEAD + (size_t)384 * kK2 * 2;     // bf16 [16][1024][1024]
static constexpr size_t WB_SCORE = WB_ATTNB + (size_t)kB * kNP * kNP * 2;// bf16 [16000][1000]
static constexpr size_t WB_P1T   = WB_SCORE + (size_t)kM * 1000 * 2;     // bf16 [16][384][1024]
static constexpr size_t WB_P2    = WB_P1T   + (size_t)kB * 384 * kNP * 2;// bf16 [16000][384]
static constexpr size_t WB_FLAG  = WB_P2    + (size_t)kM * 384 * 2;      // int

typedef __attribute__((ext_vector_type(8))) short bf16x8;
typedef __attribute__((ext_vector_type(4))) float f32x4;

static __device__ inline short f2bf(float f) {
  union { float f; unsigned u; } x; x.f = f;
  unsigned r = (x.u + 0x7FFFu + ((x.u >> 16) & 1u)) >> 16;
  return (short)r;
}
static __device__ inline float bf2f(short s) {
  union { unsigned u; float f; } x; x.u = ((unsigned)(unsigned short)s) << 16;
  return x.f;
}

#define GLOAD_LDS16(gp, lp) __builtin_amdgcn_global_load_lds( \
    (const __attribute__((address_space(1))) void*)(gp),      \
    (__attribute__((address_space(3))) void*)(lp), 16, 0, 0)

// ---------------- mask dtype detection ----------------
__global__ void k_detect(const unsigned char* __restrict__ m, int* __restrict__ flag) {
  __shared__ int c1, c2, c3;
  if (threadIdx.x == 0) { c1 = 0; c2 = 0; c3 = 0; }
  __syncthreads();
  int l1 = 0, l2 = 0, l3 = 0;
  for (int g = threadIdx.x; g < (kN * kH) / 4; g += blockDim.x) {
    l1 += (m[4 * g + 1] != 0);
    l2 += (m[4 * g + 2] != 0);
    l3 += (m[4 * g + 3] != 0);
  }
  atomicAdd(&c1, l1); atomicAdd(&c2, l2); atomicAdd(&c3, l3);
  __syncthreads();
  if (threadIdx.x == 0) {
    int f;
    if (c1 > 0)            f = 1;  // uint8 bools
    else if (c2 | c3)      f = 2;  // float32 bools
    else                   f = 0;  // int32 bools
    *flag = f;
  }
}

// ---------------- 1x1 conv (fp32, float4 x 4 pixels/thread) -----------------
__global__ __launch_bounds__(256) void k_conv(const float* __restrict__ bf,
                                              const float* __restrict__ cw,
                                              const float* __restrict__ cb,
                                              float* __restrict__ feats) {
  __shared__ float w[kAFC * kC];
  __shared__ float bsh[kAFC];
  for (int i = threadIdx.x; i < kAFC * kC; i += 256) w[i] = cw[i];
  if (threadIdx.x < kAFC) bsh[threadIdx.x] = cb[threadIdx.x];
  __syncthreads();
  int idx = blockIdx.x * 256 + threadIdx.x;     // pixel-quad index
  if (idx >= kB * (kHW / 4)) return;
  int b = idx / (kHW / 4), p = (idx % (kHW / 4)) * 4;
  float acc[kAFC][4];
#pragma unroll
  for (int o = 0; o < kAFC; o++) {
    float bv = bsh[o];
    acc[o][0] = bv; acc[o][1] = bv; acc[o][2] = bv; acc[o][3] = bv;
  }
  const float* src = bf + (size_t)b * kC * kHW + p;
#pragma unroll 4
  for (int c = 0; c < kC; c++) {
    float4 v = *(const float4*)(src + (size_t)c * kHW);
#pragma unroll
    for (int o = 0; o < kAFC; o++) {
      float wc = w[o * kC + c];
      acc[o][0] = fmaf(v.x, wc, acc[o][0]);
      acc[o][1] = fmaf(v.y, wc, acc[o][1]);
      acc[o][2] = fmaf(v.z, wc, acc[o][2]);
      acc[o][3] = fmaf(v.w, wc, acc[o][3]);
    }
  }
  float* dst = feats + (size_t)b * kAFC * kHW + p;
#pragma unroll
  for (int o = 0; o < kAFC; o++)
    *(float4*)(dst + (size_t)o * kHW) =
        make_float4(acc[o][0], acc[o][1], acc[o][2], acc[o][3]);
}

// ---------------- gather rois -> baf (bf16, d'=h*16+a layout) ---------------
__global__ __launch_bounds__(256) void k_gather(const float* __restrict__ feats,
                                                const int* __restrict__ cut,
                                                const void* __restrict__ mask,
                                                const int* __restrict__ flag,
                                                short* __restrict__ baf) {
  __shared__ float lf[kAFC * 193];   // pad 192->193 to rotate banks per a
  int bid = blockIdx.x;
  int b = bid & 15, h = bid >> 4;
  const float* fbase = feats + (size_t)b * kAFC * kHW + (size_t)h * kW;
  for (int i = threadIdx.x; i < kAFC * kW; i += 256) {
    int a = i / kW, x = i % kW;
    lf[a * 193 + x] = fbase[(size_t)a * kHW + x];
  }
  __syncthreads();
  int f = *flag;
  for (int n = threadIdx.x; n < kN; n += 256) {
    int r = n * kH + h;
    bool inv;
    if (f == 0)      inv = ((const int*)mask)[r] != 0;
    else if (f == 1) inv = ((const unsigned char*)mask)[r] != 0;
    else             inv = ((const float*)mask)[r] != 0.0f;
    bf16x8 v0 = {}, v1 = {};
    if (!inv) {
      int x = cut[r];
#pragma unroll
      for (int a = 0; a < 8; a++)  v0[a] = f2bf(lf[a * 193 + x]);
#pragma unroll
      for (int a = 0; a < 8; a++)  v1[a] = f2bf(lf[(a + 8) * 193 + x]);
    }
    short* dst = baf + (size_t)(b * kN + n) * kD + h * kAFC;
    *(bf16x8*)dst = v0;
    *(bf16x8*)(dst + 8) = v1;
  }
}

// ---- convert attn_w -> bf16 [1024][2560] in d' order (per-row transpose) ---
__global__ __launch_bounds__(256) void k_cvt_attnw(const float* __restrict__ w,
                                                   short* __restrict__ o) {
  __shared__ float lw[kAFC * (kH + 1)];   // 16x161
  int j = blockIdx.x;                      // 0..1023
  short* dst = o + (size_t)j * kD;
  if (j < kNM1) {
    const float* src = w + (size_t)j * kD;
    for (int i = threadIdx.x; i < kD; i += 256) {
      int a = i / kH, h = i % kH;
      lw[a * (kH + 1) + h] = src[i];
    }
    __syncthreads();
    for (int dp = threadIdx.x; dp < kD; dp += 256) {
      int h = dp >> 4, a = dp & 15;
      dst[dp] = f2bf(lw[a * (kH + 1) + h]);
    }
  } else {
    for (int dp = threadIdx.x; dp < kD; dp += 256) dst[dp] = 0;
  }
}

// ---- build head weight bf16 [384][5120], both K-halves in d' order ---------
__global__ __launch_bounds__(256) void k_cvt_whead(const float* __restrict__ reg_w,
                                                   const float* __restrict__ cls_w,
                                                   short* __restrict__ o) {
  __shared__ float lw[2 * kAFC * (kH + 1)];  // 2 x 16 x 161
  int j = blockIdx.x;                        // 0..383
  const float* src = nullptr;
  if (j < 3 * kS)                 src = reg_w + (size_t)j * kK2;
  else if (j < 3 * kS + kNC)      src = cls_w + (size_t)(j - 3 * kS) * kK2;
  short* dst = o + (size_t)j * kK2;
  if (src) {
    for (int i = threadIdx.x; i < kK2; i += 256) {
      int half = i / kD, t = i % kD;
      int a = t / kH, h = t % kH;
      lw[(half * kAFC + a) * (kH + 1) + h] = src[i];
    }
    __syncthreads();
    for (int kp = threadIdx.x; kp < kK2; kp += 256) {
      int half = kp / kD, t = kp % kD;
      int h = t >> 4, a = t & 15;
      dst[kp] = f2bf(lw[(half * kAFC + a) * (kH + 1) + h]);
    }
  } else {
    for (int kp = threadIdx.x; kp < kK2; kp += 256) dst[kp] = 0;
  }
}

// ---------------- softmax: bf16 scores -> attn f32 out + attn bf16 padded ---
__global__ __launch_bounds__(256) void k_softmax(const short* __restrict__ scores,
                                                 const float* __restrict__ anchors,
                                                 float* __restrict__ attn_out,
                                                 short* __restrict__ attn_bf,
                                                 float* __restrict__ rp) {
  int m = blockIdx.x;           // 0..15999
  int b = m / kN;
  int i = m % kN;
  const short* srow = scores + (size_t)m * 1000;
  int tid = threadIdx.x;
  int j0 = tid * 4;
  __shared__ float red[4];
  float v[4];
  if (j0 < 1000) {
    short4 s4 = *(const short4*)(srow + j0);
    v[0] = bf2f(s4.x); v[1] = bf2f(s4.y); v[2] = bf2f(s4.z); v[3] = bf2f(s4.w);
  } else {
    v[0] = v[1] = v[2] = v[3] = -INFINITY;
  }
#pragma unroll
  for (int t = 0; t < 4; t++) if (j0 + t >= kNM1) v[t] = -INFINITY;
  float mx = fmaxf(fmaxf(v[0], v[1]), fmaxf(v[2], v[3]));
#pragma unroll
  for (int o = 32; o; o >>= 1) mx = fmaxf(mx, __shfl_down(mx, o));
  if ((tid & 63) == 0) red[tid >> 6] = mx;
  __syncthreads();
  mx = fmaxf(fmaxf(red[0], red[1]), fmaxf(red[2], red[3]));
  __syncthreads();
  float s = 0.f;
#pragma unroll
  for (int t = 0; t < 4; t++) {
    v[t] = (j0 + t < kNM1) ? __expf(v[t] - mx) : 0.f;
    s += v[t];
  }
#pragma unroll
  for (int o = 32; o; o >>= 1) s += __shfl_down(s, o);
  if ((tid & 63) == 0) red[tid >> 6] = s;
  __syncthreads();
  s = red[0] + red[1] + red[2] + red[3];
  float inv = 1.0f / s;
  float* orow = attn_out + (size_t)m * kN;
  short* brow = attn_bf + ((size_t)b * kNP + i) * kNP;
  if (j0 + 3 < i && j0 + 3 < kNM1) {
    // fully below the diagonal: dst=j, aligned vector stores
    float p0 = v[0] * inv, p1 = v[1] * inv, p2v = v[2] * inv, p3 = v[3] * inv;
    *(float4*)(orow + j0) = make_float4(p0, p1, p2v, p3);
    *(short4*)(brow + j0) = make_short4(f2bf(p0), f2bf(p1), f2bf(p2v), f2bf(p3));
  } else {
#pragma unroll
    for (int t = 0; t < 4; t++) {
      int j = j0 + t;
      if (j < kNM1) {
        int dst = j + (j >= i);
        float p = v[t] * inv;
        orow[dst] = p;
        brow[dst] = f2bf(p);
      }
    }
  }
  if (tid == 0) { orow[i] = 0.f; brow[i] = 0; }
  if (tid < kNP - kN) brow[kN + tid] = 0;           // pad cols 1000..1023
  if (tid < 3) rp[(size_t)m * kRP + 2 + tid] = anchors[(size_t)i * kRP + 2 + tid];
}

// ---------------- scores GEMM: 256x256 tile, BK=32, 8 waves, ring ----------
__global__ __launch_bounds__(512, 2) void k_sgemm(
    const short* __restrict__ A,
    const short* __restrict__ Bt,
    const float* __restrict__ bias,
    short* __restrict__ Cout) {
  extern __shared__ char dls[];                // 128 KB: 4 bufs x (A 16K + B 16K)
  constexpr int NT = kD / 32;                  // 80
  int tid = threadIdx.x, lane = tid & 63, wv = tid >> 6;
  int bid = blockIdx.x;
  int xcd = bid & 7, s = bid >> 3;
  int m0 = (xcd * 8 + (s & 7)) * 256;          // 0..16128 (M padded via clamp)
  int n0 = (s >> 3) * 256;                     // 0..768
  int wm = (wv & 1) * 128, wn = (wv >> 1) * 64;
  f32x4 acc[8][4] = {};

  int r0  = tid >> 2;
  int r1  = (512 + tid) >> 2;
  int swzko = (((tid & 3) ^ ((tid >> 3) & 3)) * 8);   // pre-swizzled k-offset
  int ar0 = min(m0 + r0, kM - 1);
  int ar1 = min(m0 + r1, kM - 1);
  const short* gA0 = A + (size_t)ar0 * kD + swzko;
  const short* gA1 = A + (size_t)ar1 * kD + swzko;
  const short* gB0 = Bt + (size_t)(n0 + r0) * kD + swzko;
  const short* gB1 = Bt + (size_t)(n0 + r1) * kD + swzko;

  auto STAGE = [&](int tt) {
    char* buf = dls + (size_t)(tt & 3) * 32768;
    int k0 = tt * 32;
    GLOAD_LDS16(gA0 + k0, buf + wv * 1024);
    GLOAD_LDS16(gA1 + k0, buf + 8192 + wv * 1024);
    GLOAD_LDS16(gB0 + k0, buf + 16384 + wv * 1024);
    GLOAD_LDS16(gB1 + k0, buf + 24576 + wv * 1024);
  };

  int cswz = (((lane >> 4) ^ ((lane >> 1) & 3)) * 16); // swizzled read column

  STAGE(0); STAGE(1); STAGE(2);
  for (int t = 0; t < NT; t++) {
    if (t < NT - 2)       asm volatile("s_waitcnt vmcnt(8)" ::: "memory");
    else if (t == NT - 2) asm volatile("s_waitcnt vmcnt(4)" ::: "memory");
    else                  asm volatile("s_waitcnt vmcnt(0)" ::: "memory");
    __builtin_amdgcn_s_barrier();
    __builtin_amdgcn_sched_barrier(0);
    if (t + 3 < NT) STAGE(t + 3);
    const char* bufA = dls + (size_t)(t & 3) * 32768;
    const char* bufB = bufA + 16384;
    bf16x8 af[8], bg[4];
#pragma unroll
    for (int i = 0; i < 8; i++)
      af[i] = *(const bf16x8*)(bufA + (wm + i * 16 + (lane & 15)) * 64 + cswz);
#pragma unroll
    for (int j = 0; j < 4; j++)
      bg[j] = *(const bf16x8*)(bufB + (wn + j * 16 + (lane & 15)) * 64 + cswz);
    __builtin_amdgcn_s_setprio(1);
#pragma unroll
    for (int i = 0; i < 8; i++)
#pragma unroll
      for (int j = 0; j < 4; j++)
        acc[i][j] = __builtin_amdgcn_mfma_f32_16x16x32_bf16(af[i], bg[j], acc[i][j], 0, 0, 0);
    __builtin_amdgcn_s_setprio(0);
  }

#pragma unroll
  for (int i = 0; i < 8; i++) {
#pragma unroll
    for (int j = 0; j < 4; j++) {
#pragma unroll
      for (int r = 0; r < 4; r++) {
        int row = m0 + wm + i * 16 + (lane >> 4) * 4 + r;
        int col = n0 + wn + j * 16 + (lane & 15);
        if (row < kM && col < kNM1)
          Cout[(size_t)row * 1000 + col] = f2bf(acc[i][j][r] + bias[col]);
      }
    }
  }
}

// ---------------- P-GEMM: X = baf @ Wstk^T, ring, BM=128, BN=384 ------------
// nb=0: W1 -> p1t[b][col][n] via LDS-transposed coalesced epilogue
// nb=1: W2 -> p2 (row-major direct)
__global__ __launch_bounds__(512, 2) void k_pgemm(
    const short* __restrict__ baf,   // [16000][2560]
    const short* __restrict__ Bt,    // whead [384][5120]
    short* __restrict__ p1t,         // [16][384][1024]
    short* __restrict__ p2) {        // [16000][384]
  extern __shared__ char dls[];      // 128 KB: 4 bufs x (A 8K + B 24K)
  constexpr int NT = kD / 32;        // 80
  int tid = threadIdx.x, lane = tid & 63, wv = tid >> 6;
  int bid = blockIdx.x;
  int nb = bid & 1, mt = bid >> 1;
  int m0 = mt * 128;
  int kofs = nb * kD;

  int wm = (wv & 1) * 64, wn = (wv >> 1) * 96;
  f32x4 acc[4][6] = {};

  int rA = tid >> 2;
  int swzko = (((tid & 3) ^ ((tid >> 3) & 3)) * 8);
  const short* gA  = baf + (size_t)(m0 + rA) * kD + swzko;
  const short* gB0 = Bt + (size_t)(tid >> 2) * kK2 + kofs + swzko;
  const short* gB1 = Bt + (size_t)((512 + tid) >> 2) * kK2 + kofs + swzko;
  const short* gB2 = Bt + (size_t)((1024 + tid) >> 2) * kK2 + kofs + swzko;

  auto STAGE = [&](int tt) {
    char* buf = dls + (size_t)(tt & 3) * 32768;
    int k0 = tt * 32;
    GLOAD_LDS16(gA + k0,  buf + wv * 1024);
    GLOAD_LDS16(gB0 + k0, buf + 8192 + wv * 1024);
    GLOAD_LDS16(gB1 + k0, buf + 16384 + wv * 1024);
    GLOAD_LDS16(gB2 + k0, buf + 24576 + wv * 1024);
  };

  int cswz = (((lane >> 4) ^ ((lane >> 1) & 3)) * 16);

  STAGE(0); STAGE(1); STAGE(2);
  for (int t = 0; t < NT; t++) {
    if (t < NT - 2)       asm volatile("s_waitcnt vmcnt(8)" ::: "memory");
    else if (t == NT - 2) asm volatile("s_waitcnt vmcnt(4)" ::: "memory");
    else                  asm volatile("s_waitcnt vmcnt(0)" ::: "memory");
    __builtin_amdgcn_s_barrier();
    __builtin_amdgcn_sched_barrier(0);
    if (t + 3 < NT) STAGE(t + 3);
    const char* bufA = dls + (size_t)(t & 3) * 32768;
    const char* bufB = bufA + 8192;
    bf16x8 af[4], bg[6];
#pragma unroll
    for (int i = 0; i < 4; i++)
      af[i] = *(const bf16x8*)(bufA + (wm + i * 16 + (lane & 15)) * 64 + cswz);
#pragma unroll
    for (int j = 0; j < 6; j++)
      bg[j] = *(const bf16x8*)(bufB + (wn + j * 16 + (lane & 15)) * 64 + cswz);
    __builtin_amdgcn_s_setprio(1);
#pragma unroll
    for (int i = 0; i < 4; i++)
#pragma unroll
      for (int j = 0; j < 6; j++)
        acc[i][j] = __builtin_amdgcn_mfma_f32_16x16x32_bf16(af[i], bg[j], acc[i][j], 0, 0, 0);
    __builtin_amdgcn_s_setprio(0);
  }

  if (nb == 0) {
    // LDS-transposed epilogue: lds2[col][row], stride 136 (bank-rotating pad)
    __syncthreads();                 // all waves done with ring ds_reads
    short* lds2 = (short*)dls;       // 384*136*2 = 104448 B <= 128 KB
#pragma unroll
    for (int i = 0; i < 4; i++) {
#pragma unroll
      for (int j = 0; j < 6; j++) {
#pragma unroll
        for (int r = 0; r < 4; r++) {
          int row = wm + i * 16 + (lane >> 4) * 4 + r;   // 0..127
          int col = wn + j * 16 + (lane & 15);           // 0..383
          lds2[col * 136 + row] = f2bf(acc[i][j][r]);
        }
      }
    }
    __syncthreads();
    // coalesced writes: 384 cols x 16 octets of 8 rows; batch boundaries
    // are octet-aligned (1000 % 8 == 0), so each octet is one batch.
    for (int u = tid; u < 384 * 16; u += 512) {
      int col = u >> 4, oct = u & 15;
      int grow = m0 + oct * 8;
      int b = grow / kN;
      int n = grow - b * kN;
      bf16x8 val = *(const bf16x8*)(lds2 + col * 136 + oct * 8);
      *(bf16x8*)(p1t + ((size_t)b * 384 + col) * kNP + n) = val;
    }
  } else {
#pragma unroll
    for (int i = 0; i < 4; i++) {
#pragma unroll
      for (int j = 0; j < 6; j++) {
#pragma unroll
        for (int r = 0; r < 4; r++) {
          int row = m0 + wm + i * 16 + (lane >> 4) * 4 + r;
          int col = wn + j * 16 + (lane & 15);
          p2[(size_t)row * 384 + col] = f2bf(acc[i][j][r]);
        }
      }
    }
  }
}

// ---------------- F-GEMM: Y[b] = attn_bf[b] @ p1t[b]^T + p2 + epilogue ------
__global__ __launch_bounds__(512, 2) void k_fgemm(
    const short* __restrict__ attn_bf,  // [16][1024][1024]
    const short* __restrict__ p1t,      // [16][384][1024]
    const short* __restrict__ p2,       // [16000][384]
    const float* __restrict__ reg_b, const float* __restrict__ cls_b,
    const float* __restrict__ anchors, float* __restrict__ rp) {
  extern __shared__ char dls[];      // 112 KB: 4 bufs x (A 4K + B 24K)
  constexpr int NT = kNP / 32;       // 32
  int tid = threadIdx.x, lane = tid & 63, wv = tid >> 6;
  int bid = blockIdx.x;
  int b = bid & 15, mt = bid >> 4;   // XCD = bid&7 -> b in {x, x+8}: p1t L2-hot
  int m0 = mt * 64;
  const short* Ap = attn_bf + (size_t)b * kNP * kNP;
  const short* Bp = p1t + (size_t)b * 384 * kNP;

  int wm = (wv & 1) * 32, wn = (wv >> 1) * 96;
  f32x4 acc[2][6] = {};

  int ciA = tid & 255;
  int swzkoA = (((ciA & 3) ^ ((ciA >> 3) & 3)) * 8);
  int swzko  = (((tid & 3) ^ ((tid >> 3) & 3)) * 8);
  const short* gA  = Ap + (size_t)(m0 + (ciA >> 2)) * kNP + swzkoA;
  const short* gB0 = Bp + (size_t)(tid >> 2) * kNP + swzko;
  const short* gB1 = Bp + (size_t)((512 + tid) >> 2) * kNP + swzko;
  const short* gB2 = Bp + (size_t)((1024 + tid) >> 2) * kNP + swzko;

  auto STAGE = [&](int tt) {
    char* buf = dls + (size_t)(tt & 3) * 28672;
    int k0 = tt * 32;
    GLOAD_LDS16(gA + k0,  buf + (wv & 3) * 1024);
    GLOAD_LDS16(gB0 + k0, buf + 4096 + wv * 1024);
    GLOAD_LDS16(gB1 + k0, buf + 12288 + wv * 1024);
    GLOAD_LDS16(gB2 + k0, buf + 20480 + wv * 1024);
  };

  int cswz = (((lane >> 4) ^ ((lane >> 1) & 3)) * 16);

  STAGE(0); STAGE(1); STAGE(2);
  for (int t = 0; t < NT; t++) {
    if (t < NT - 2)       asm volatile("s_waitcnt vmcnt(8)" ::: "memory");
    else if (t == NT - 2) asm volatile("s_waitcnt vmcnt(4)" ::: "memory");
    else                  asm volatile("s_waitcnt vmcnt(0)" ::: "memory");
    __builtin_amdgcn_s_barrier();
    __builtin_amdgcn_sched_barrier(0);
    if (t + 3 < NT) STAGE(t + 3);
    const char* bufA = dls + (size_t)(t & 3) * 28672;
    const char* bufB = bufA + 4096;
    bf16x8 af[2], bg[6];
#pragma unroll
    for (int i = 0; i < 2; i++)
      af[i] = *(const bf16x8*)(bufA + (wm + i * 16 + (lane & 15)) * 64 + cswz);
#pragma unroll
    for (int j = 0; j < 6; j++)
      bg[j] = *(const bf16x8*)(bufB + (wn + j * 16 + (lane & 15)) * 64 + cswz);
    __builtin_amdgcn_s_setprio(1);
#pragma unroll
    for (int i = 0; i < 2; i++)
#pragma unroll
      for (int j = 0; j < 6; j++)
        acc[i][j] = __builtin_amdgcn_mfma_f32_16x16x32_bf16(af[i], bg[j], acc[i][j], 0, 0, 0);
    __builtin_amdgcn_s_setprio(0);
  }

#pragma unroll
  for (int i = 0; i < 2; i++) {
#pragma unroll
    for (int j = 0; j < 6; j++) {
#pragma unroll
      for (int r = 0; r < 4; r++) {
        int n = m0 + wm + i * 16 + (lane >> 4) * 4 + r;   // 0..1023
        int col = wn + j * 16 + (lane & 15);              // 0..383
        if (n < kN) {
          size_t row = (size_t)b * kN + n;
          float v = acc[i][j][r] + bf2f(p2[row * 384 + col]);
          if (col < 3 * kS) {
            float tv = v + reg_b[col];
            if (col >= 2 * kS) tv = 1.0f / (1.0f + __expf(-tv));
            rp[row * kRP + 5 + col] = anchors[(size_t)n * kRP + 5 + col] + tv;
          } else if (col < 3 * kS + kNC) {
            rp[row * kRP + (col - 3 * kS)] = v + cls_b[col - 3 * kS];
          }
        }
      }
    }
  }
}

extern "C" void kernel_launch(void* const* d_in, const int* in_sizes, int n_in,
                              void* d_out, int out_size, void* d_ws, size_t ws_size,
                              hipStream_t stream) {
  const float* bf      = (const float*)d_in[0];
  const float* conv_w  = (const float*)d_in[1];
  const float* conv_b  = (const float*)d_in[2];
  const int*   cut     = (const int*)d_in[3];
  const void*  mask    = d_in[4];
  const float* anchors = (const float*)d_in[5];
  const float* attn_w  = (const float*)d_in[6];
  const float* attn_b  = (const float*)d_in[7];
  const float* cls_w   = (const float*)d_in[8];
  const float* cls_b   = (const float*)d_in[9];
  const float* reg_w   = (const float*)d_in[10];
  const float* reg_b   = (const float*)d_in[11];

  float* out    = (float*)d_out;
  float* rp     = out + OFF_RP;
  float* attn_o = out + OFF_ATTN;
  float* feats  = out + OFF_FEAT;

  char*  ws      = (char*)d_ws;
  short* baf     = (short*)(ws + WB_BAF);
  short* attnw   = (short*)(ws + WB_ATTNW);
  short* whead   = (short*)(ws + WB_WHEAD);
  short* attn_bf = (short*)(ws + WB_ATTNB);
  short* scores  = (short*)(ws + WB_SCORE);
  short* p1t     = (short*)(ws + WB_P1T);
  short* p2      = (short*)(ws + WB_P2);
  int*   flag    = (int*)(ws + WB_FLAG);

  k_detect<<<1, 256, 0, stream>>>((const unsigned char*)mask, flag);
  k_conv<<<(kB * kHW / 4 + 255) / 256, 256, 0, stream>>>(bf, conv_w, conv_b, feats);
  k_gather<<<kB * kH, 256, 0, stream>>>(feats, cut, mask, flag, baf);
  k_cvt_attnw<<<kNP, 256, 0, stream>>>(attn_w, attnw);
  k_cvt_whead<<<384, 256, 0, stream>>>(reg_w, cls_w, whead);
  // P-GEMM: 250 blocks (125 m-tiles x 2 n-halves)
  k_pgemm<<<2 * (kM / 128), 512, 131072, stream>>>(baf, whead, p1t, p2);
  // scores GEMM: 256 blocks (64 m-tiles x 4 n-tiles, XCD owns 8 m-tiles)
  k_sgemm<<<256, 512, 131072, stream>>>(baf, attnw, attn_b, scores);
  k_softmax<<<kM, 256, 0, stream>>>(scores, anchors, attn_o, attn_bf, rp);
  // F-GEMM: 256 blocks (16 batches x 16 m-tiles), fused head epilogue
  k_fgemm<<<256, 512, 114688, stream>>>(attn_bf, p1t, p2, reg_b, cls_b,
                                        anchors, rp);
}

// Round 16
// 403.047 us; speedup vs baseline: 2.0012x; 1.0406x over previous
//
#include <hip/hip_runtime.h>
#include <cmath>

// Problem constants
static constexpr int kB   = 16;
static constexpr int kC   = 64;
static constexpr int kH   = 160;
static constexpr int kW   = 192;
static constexpr int kN   = 1000;
static constexpr int kAFC = 16;
static constexpr int kS   = 96;
static constexpr int kNC  = 2;
static constexpr int kD   = kAFC * kH;     // 2560
static constexpr int kHW  = kH * kW;       // 30720
static constexpr int kNM1 = kN - 1;        // 999
static constexpr int kM   = kB * kN;       // 16000
static constexpr int kRP  = kNC + 3 + 3 * kS; // 293
static constexpr int kK2  = 2 * kD;        // 5120
static constexpr int kNP  = 1024;          // padded N
static constexpr int kNW  = 1792;          // wcomb rows: 1024 attnw + 384 W1 + 384 W2

// Internal feature ordering is d' = h*16 + a (h-major); all internal tensors
// and repacked weights use d' consistently.
// Reassociation: head = attn@(baf@W1^T) + baf@W2^T.
// Merged GEMM: C = baf @ wcomb^T, wcomb = [attnw | W1 | W2]; epilogue routes
// n-tiles 0-3 -> scores, tile 4 + pass0 of 5 -> p1t (LDS transpose),
// rest of 5 + all of 6 -> p2 (direct). Tile 6 MUST skip the transpose path
// (round-15 bug: unguarded jw>=384 write-out corrupted p2).

// d_out layout (floats)
static constexpr size_t OFF_RP   = 0;
static constexpr size_t OFF_ATTN = (size_t)kB * kN * kRP;
static constexpr size_t OFF_FEAT = OFF_ATTN + (size_t)kB * kN * kN;

// ws layout (bytes)
static constexpr size_t WB_BAF   = 0;                                    // bf16 [16000][2560]
static constexpr size_t WB_WCOMB = WB_BAF   + (size_t)kM * kD * 2;       // bf16 [1792][2560]
static constexpr size_t WB_ATTNB = WB_WCOMB + (size_t)kNW * kD * 2;      // bf16 [16][1024][1024]
static constexpr size_t WB_SCORE = WB_ATTNB + (size_t)kB * kNP * kNP * 2;// bf16 [16000][1000]
static constexpr size_t WB_P1T   = WB_SCORE + (size_t)kM * 1000 * 2;     // bf16 [16][384][1024]
static constexpr size_t WB_P2    = WB_P1T   + (size_t)kB * 384 * kNP * 2;// bf16 [16000][384]
static constexpr size_t WB_FLAG  = WB_P2    + (size_t)kM * 384 * 2;      // int

typedef __attribute__((ext_vector_type(8))) short bf16x8;
typedef __attribute__((ext_vector_type(4))) float f32x4;

static __device__ inline short f2bf(float f) {
  union { float f; unsigned u; } x; x.f = f;
  unsigned r = (x.u + 0x7FFFu + ((x.u >> 16) & 1u)) >> 16;
  return (short)r;
}
static __device__ inline float bf2f(short s) {
  union { unsigned u; float f; } x; x.u = ((unsigned)(unsigned short)s) << 16;
  return x.f;
}

#define GLOAD_LDS16(gp, lp) __builtin_amdgcn_global_load_lds( \
    (const __attribute__((address_space(1))) void*)(gp),      \
    (__attribute__((address_space(3))) void*)(lp), 16, 0, 0)

// ---------------- mask dtype detection ----------------
__global__ void k_detect(const unsigned char* __restrict__ m, int* __restrict__ flag) {
  __shared__ int c1, c2, c3;
  if (threadIdx.x == 0) { c1 = 0; c2 = 0; c3 = 0; }
  __syncthreads();
  int l1 = 0, l2 = 0, l3 = 0;
  for (int g = threadIdx.x; g < (kN * kH) / 4; g += blockDim.x) {
    l1 += (m[4 * g + 1] != 0);
    l2 += (m[4 * g + 2] != 0);
    l3 += (m[4 * g + 3] != 0);
  }
  atomicAdd(&c1, l1); atomicAdd(&c2, l2); atomicAdd(&c3, l3);
  __syncthreads();
  if (threadIdx.x == 0) {
    int f;
    if (c1 > 0)            f = 1;  // uint8 bools
    else if (c2 | c3)      f = 2;  // float32 bools
    else                   f = 0;  // int32 bools
    *flag = f;
  }
}

// ---------------- 1x1 conv (fp32, float4 x 4 pixels/thread) -----------------
__global__ __launch_bounds__(256) void k_conv(const float* __restrict__ bf,
                                              const float* __restrict__ cw,
                                              const float* __restrict__ cb,
                                              float* __restrict__ feats) {
  __shared__ float w[kAFC * kC];
  __shared__ float bsh[kAFC];
  for (int i = threadIdx.x; i < kAFC * kC; i += 256) w[i] = cw[i];
  if (threadIdx.x < kAFC) bsh[threadIdx.x] = cb[threadIdx.x];
  __syncthreads();
  int idx = blockIdx.x * 256 + threadIdx.x;     // pixel-quad index
  if (idx >= kB * (kHW / 4)) return;
  int b = idx / (kHW / 4), p = (idx % (kHW / 4)) * 4;
  float acc[kAFC][4];
#pragma unroll
  for (int o = 0; o < kAFC; o++) {
    float bv = bsh[o];
    acc[o][0] = bv; acc[o][1] = bv; acc[o][2] = bv; acc[o][3] = bv;
  }
  const float* src = bf + (size_t)b * kC * kHW + p;
#pragma unroll 4
  for (int c = 0; c < kC; c++) {
    float4 v = *(const float4*)(src + (size_t)c * kHW);
#pragma unroll
    for (int o = 0; o < kAFC; o++) {
      float wc = w[o * kC + c];
      acc[o][0] = fmaf(v.x, wc, acc[o][0]);
      acc[o][1] = fmaf(v.y, wc, acc[o][1]);
      acc[o][2] = fmaf(v.z, wc, acc[o][2]);
      acc[o][3] = fmaf(v.w, wc, acc[o][3]);
    }
  }
  float* dst = feats + (size_t)b * kAFC * kHW + p;
#pragma unroll
  for (int o = 0; o < kAFC; o++)
    *(float4*)(dst + (size_t)o * kHW) =
        make_float4(acc[o][0], acc[o][1], acc[o][2], acc[o][3]);
}

// ---------------- gather rois -> baf (bf16, d'=h*16+a layout) ---------------
__global__ __launch_bounds__(256) void k_gather(const float* __restrict__ feats,
                                                const int* __restrict__ cut,
                                                const void* __restrict__ mask,
                                                const int* __restrict__ flag,
                                                short* __restrict__ baf) {
  __shared__ float lf[kAFC * 193];   // pad 192->193 to rotate banks per a
  int bid = blockIdx.x;
  int b = bid & 15, h = bid >> 4;
  const float* fbase = feats + (size_t)b * kAFC * kHW + (size_t)h * kW;
  for (int i = threadIdx.x; i < kAFC * kW; i += 256) {
    int a = i / kW, x = i % kW;
    lf[a * 193 + x] = fbase[(size_t)a * kHW + x];
  }
  __syncthreads();
  int f = *flag;
  for (int n = threadIdx.x; n < kN; n += 256) {
    int r = n * kH + h;
    bool inv;
    if (f == 0)      inv = ((const int*)mask)[r] != 0;
    else if (f == 1) inv = ((const unsigned char*)mask)[r] != 0;
    else             inv = ((const float*)mask)[r] != 0.0f;
    bf16x8 v0 = {}, v1 = {};
    if (!inv) {
      int x = cut[r];
#pragma unroll
      for (int a = 0; a < 8; a++)  v0[a] = f2bf(lf[a * 193 + x]);
#pragma unroll
      for (int a = 0; a < 8; a++)  v1[a] = f2bf(lf[(a + 8) * 193 + x]);
    }
    short* dst = baf + (size_t)(b * kN + n) * kD + h * kAFC;
    *(bf16x8*)dst = v0;
    *(bf16x8*)(dst + 8) = v1;
  }
}

// ---- build combined weight wcomb [1792][2560] in d' order ------------------
// rows [0,1024): attnw (attn_w rows, zero-padded >= 999)
// rows [1024,1408): W1 = whead[:, 0:2560]; rows [1408,1792): W2 = [:, 2560:]
__global__ __launch_bounds__(256) void k_cvt_wcomb(const float* __restrict__ attn_w,
                                                   const float* __restrict__ reg_w,
                                                   const float* __restrict__ cls_w,
                                                   short* __restrict__ wcomb) {
  __shared__ float lw[2 * kAFC * (kH + 1)];  // 2 x 16 x 161
  int j = blockIdx.x;                        // 0..1407
  if (j < kNP) {
    short* dst = wcomb + (size_t)j * kD;
    if (j < kNM1) {
      const float* src = attn_w + (size_t)j * kD;
      for (int i = threadIdx.x; i < kD; i += 256) {
        int a = i / kH, h = i % kH;
        lw[a * (kH + 1) + h] = src[i];
      }
      __syncthreads();
      for (int dp = threadIdx.x; dp < kD; dp += 256) {
        int h = dp >> 4, a = dp & 15;
        dst[dp] = f2bf(lw[a * (kH + 1) + h]);
      }
    } else {
      for (int dp = threadIdx.x; dp < kD; dp += 256) dst[dp] = 0;
    }
  } else {
    int jp = j - kNP;                        // 0..383
    const float* src = nullptr;
    if (jp < 3 * kS)                src = reg_w + (size_t)jp * kK2;
    else if (jp < 3 * kS + kNC)     src = cls_w + (size_t)(jp - 3 * kS) * kK2;
    short* d0 = wcomb + (size_t)(kNP + jp) * kD;
    short* d1 = wcomb + (size_t)(kNP + 384 + jp) * kD;
    if (src) {
      for (int i = threadIdx.x; i < kK2; i += 256) {
        int half = i / kD, t = i % kD;
        int a = t / kH, h = t % kH;
        lw[(half * kAFC + a) * (kH + 1) + h] = src[i];
      }
      __syncthreads();
      for (int kp = threadIdx.x; kp < kD; kp += 256) {
        int h = kp >> 4, a = kp & 15;
        d0[kp] = f2bf(lw[a * (kH + 1) + h]);
        d1[kp] = f2bf(lw[(kAFC + a) * (kH + 1) + h]);
      }
    } else {
      for (int kp = threadIdx.x; kp < kD; kp += 256) { d0[kp] = 0; d1[kp] = 0; }
    }
  }
}

// ---------------- softmax: bf16 scores -> attn f32 out + attn bf16 padded ---
__global__ __launch_bounds__(256) void k_softmax(const short* __restrict__ scores,
                                                 const float* __restrict__ anchors,
                                                 float* __restrict__ attn_out,
                                                 short* __restrict__ attn_bf,
                                                 float* __restrict__ rp) {
  int m = blockIdx.x;           // 0..15999
  int b = m / kN;
  int i = m % kN;
  const short* srow = scores + (size_t)m * 1000;
  int tid = threadIdx.x;
  int j0 = tid * 4;
  __shared__ float red[4];
  float v[4];
  if (j0 < 1000) {
    short4 s4 = *(const short4*)(srow + j0);
    v[0] = bf2f(s4.x); v[1] = bf2f(s4.y); v[2] = bf2f(s4.z); v[3] = bf2f(s4.w);
  } else {
    v[0] = v[1] = v[2] = v[3] = -INFINITY;
  }
#pragma unroll
  for (int t = 0; t < 4; t++) if (j0 + t >= kNM1) v[t] = -INFINITY;
  float mx = fmaxf(fmaxf(v[0], v[1]), fmaxf(v[2], v[3]));
#pragma unroll
  for (int o = 32; o; o >>= 1) mx = fmaxf(mx, __shfl_down(mx, o));
  if ((tid & 63) == 0) red[tid >> 6] = mx;
  __syncthreads();
  mx = fmaxf(fmaxf(red[0], red[1]), fmaxf(red[2], red[3]));
  __syncthreads();
  float s = 0.f;
#pragma unroll
  for (int t = 0; t < 4; t++) {
    v[t] = (j0 + t < kNM1) ? __expf(v[t] - mx) : 0.f;
    s += v[t];
  }
#pragma unroll
  for (int o = 32; o; o >>= 1) s += __shfl_down(s, o);
  if ((tid & 63) == 0) red[tid >> 6] = s;
  __syncthreads();
  s = red[0] + red[1] + red[2] + red[3];
  float inv = 1.0f / s;
  float* orow = attn_out + (size_t)m * kN;
  short* brow = attn_bf + ((size_t)b * kNP + i) * kNP;
  if (j0 + 3 < i && j0 + 3 < kNM1) {
    float p0 = v[0] * inv, p1 = v[1] * inv, p2v = v[2] * inv, p3 = v[3] * inv;
    *(float4*)(orow + j0) = make_float4(p0, p1, p2v, p3);
    *(short4*)(brow + j0) = make_short4(f2bf(p0), f2bf(p1), f2bf(p2v), f2bf(p3));
  } else {
#pragma unroll
    for (int t = 0; t < 4; t++) {
      int j = j0 + t;
      if (j < kNM1) {
        int dst = j + (j >= i);
        float p = v[t] * inv;
        orow[dst] = p;
        brow[dst] = f2bf(p);
      }
    }
  }
  if (tid == 0) { orow[i] = 0.f; brow[i] = 0; }
  if (tid < kNP - kN) brow[kN + tid] = 0;           // pad cols 1000..1023
  if (tid < 3) rp[(size_t)m * kRP + 2 + tid] = anchors[(size_t)i * kRP + 2 + tid];
}

// ---------------- merged GEMM: C = baf @ wcomb^T, 256x256 tile, ring --------
// n-tiles 0-3 -> scores (+bias, bf16, stride 1000)
// n-tile 4 + pass0 of 5 -> p1t (LDS-transposed coalesced epilogue)
// rest of 5 + tile 6 -> p2 (direct); tile 6 skips the transpose path.
__global__ __launch_bounds__(512, 2) void k_mgemm(
    const short* __restrict__ A,
    const short* __restrict__ Bt,     // wcomb [1792][2560]
    const float* __restrict__ bias,
    short* __restrict__ scores,
    short* __restrict__ p1t,
    short* __restrict__ p2) {
  extern __shared__ char dls[];                // 128 KB: 4 bufs x (A 16K + B 16K)
  constexpr int NT = kD / 32;                  // 80
  int tid = threadIdx.x, lane = tid & 63, wv = tid >> 6;
  int bid = blockIdx.x;
  int xcd = bid & 7, s = bid >> 3;             // s: 0..55
  int m0 = (xcd * 8 + (s & 7)) * 256;          // 0..16128 (M padded via clamp)
  int n0t = s >> 3;                            // 0..6
  int n0 = n0t * 256;
  int wm = (wv & 1) * 128, wn = (wv >> 1) * 64;
  f32x4 acc[8][4] = {};

  int r0  = tid >> 2;
  int r1  = (512 + tid) >> 2;
  int swzko = (((tid & 3) ^ ((tid >> 3) & 3)) * 8);   // pre-swizzled k-offset
  int ar0 = min(m0 + r0, kM - 1);
  int ar1 = min(m0 + r1, kM - 1);
  const short* gA0 = A + (size_t)ar0 * kD + swzko;
  const short* gA1 = A + (size_t)ar1 * kD + swzko;
  const short* gB0 = Bt + (size_t)(n0 + r0) * kD + swzko;
  const short* gB1 = Bt + (size_t)(n0 + r1) * kD + swzko;

  auto STAGE = [&](int tt) {
    char* buf = dls + (size_t)(tt & 3) * 32768;
    int k0 = tt * 32;
    GLOAD_LDS16(gA0 + k0, buf + wv * 1024);
    GLOAD_LDS16(gA1 + k0, buf + 8192 + wv * 1024);
    GLOAD_LDS16(gB0 + k0, buf + 16384 + wv * 1024);
    GLOAD_LDS16(gB1 + k0, buf + 24576 + wv * 1024);
  };

  int cswz = (((lane >> 4) ^ ((lane >> 1) & 3)) * 16); // swizzled read column

  STAGE(0); STAGE(1); STAGE(2);
  for (int t = 0; t < NT; t++) {
    if (t < NT - 2)       asm volatile("s_waitcnt vmcnt(8)" ::: "memory");
    else if (t == NT - 2) asm volatile("s_waitcnt vmcnt(4)" ::: "memory");
    else                  asm volatile("s_waitcnt vmcnt(0)" ::: "memory");
    __builtin_amdgcn_s_barrier();
    __builtin_amdgcn_sched_barrier(0);
    if (t + 3 < NT) STAGE(t + 3);
    const char* bufA = dls + (size_t)(t & 3) * 32768;
    const char* bufB = bufA + 16384;
    bf16x8 af[8], bg[4];
#pragma unroll
    for (int i = 0; i < 8; i++)
      af[i] = *(const bf16x8*)(bufA + (wm + i * 16 + (lane & 15)) * 64 + cswz);
#pragma unroll
    for (int j = 0; j < 4; j++)
      bg[j] = *(const bf16x8*)(bufB + (wn + j * 16 + (lane & 15)) * 64 + cswz);
    __builtin_amdgcn_s_setprio(1);
#pragma unroll
    for (int i = 0; i < 8; i++)
#pragma unroll
      for (int j = 0; j < 4; j++)
        acc[i][j] = __builtin_amdgcn_mfma_f32_16x16x32_bf16(af[i], bg[j], acc[i][j], 0, 0, 0);
    __builtin_amdgcn_s_setprio(0);
  }

  if (n0t < 4) {
    // scores region
#pragma unroll
    for (int i = 0; i < 8; i++) {
#pragma unroll
      for (int j = 0; j < 4; j++) {
#pragma unroll
        for (int r = 0; r < 4; r++) {
          int row = m0 + wm + i * 16 + (lane >> 4) * 4 + r;
          int col = n0 + wn + j * 16 + (lane & 15);
          if (row < kM && col < kNM1)
            scores[(size_t)row * 1000 + col] = f2bf(acc[i][j][r] + bias[col]);
        }
      }
    }
  } else {
    int base = n0 - 1024;              // w-space col offset: 0 / 256 / 512
    // direct p2 region: tile 6 all; tile 5 local cols >= 128 (jw >= 384)
    if (n0t >= 5) {
#pragma unroll
      for (int i = 0; i < 8; i++) {
#pragma unroll
        for (int j = 0; j < 4; j++) {
#pragma unroll
          for (int r = 0; r < 4; r++) {
            int row = m0 + wm + i * 16 + (lane >> 4) * 4 + r;
            int cl = wn + j * 16 + (lane & 15);
            int jw = base + cl;
            if (jw >= 384 && row < kM)
              p2[(size_t)row * 384 + (jw - 384)] = f2bf(acc[i][j][r]);
          }
        }
      }
    }
    // transpose region -> p1t: ONLY tiles 4 (both passes) and 5 (pass 0).
    // Tile 6 must skip (all its cols are p2; unguarded write-out was the
    // round-15 corruption bug). lds2 (66 KB) overlays ring slots 0-2; last
    // K-step reads slot 3 only and earlier reads retired at its barrier.
    if (n0t <= 5) {
      short* lds2 = (short*)dls;       // [128 cols][264]
      int npass = (n0t == 4) ? 2 : 1;
      for (int pass = 0; pass < npass; pass++) {
        if ((wn < 128) == (pass == 0)) {
#pragma unroll
          for (int i = 0; i < 8; i++) {
#pragma unroll
            for (int j = 0; j < 4; j++) {
#pragma unroll
              for (int r = 0; r < 4; r++) {
                int rowl = wm + i * 16 + (lane >> 4) * 4 + r;      // 0..255
                int cl = (wn + j * 16 + (lane & 15)) - pass * 128; // 0..127
                lds2[cl * 264 + rowl] = f2bf(acc[i][j][r]);
              }
            }
          }
        }
        __syncthreads();
        for (int u = tid; u < 128 * 32; u += 512) {
          int c = u >> 5, oct = u & 31;
          int jw = base + pass * 128 + c;          // p1t row, < 384 for tiles 4/5p0
          int grow = m0 + oct * 8;
          if (grow < kM && jw < 384) {
            int b = grow / kN, n = grow - b * kN;
            *(bf16x8*)(p1t + ((size_t)b * 384 + jw) * kNP + n) =
                *(const bf16x8*)(lds2 + c * 264 + oct * 8);
          }
        }
        __syncthreads();
      }
    }
  }
}

// ---------------- F-GEMM: Y[b] = attn_bf[b] @ p1t[b]^T + p2 + epilogue ------
__global__ __launch_bounds__(512, 2) void k_fgemm(
    const short* __restrict__ attn_bf,  // [16][1024][1024]
    const short* __restrict__ p1t,      // [16][384][1024]
    const short* __restrict__ p2,       // [16000][384]
    const float* __restrict__ reg_b, const float* __restrict__ cls_b,
    const float* __restrict__ anchors, float* __restrict__ rp) {
  extern __shared__ char dls[];      // 112 KB: 4 bufs x (A 4K + B 24K)
  constexpr int NT = kNP / 32;       // 32
  int tid = threadIdx.x, lane = tid & 63, wv = tid >> 6;
  int bid = blockIdx.x;
  int b = bid & 15, mt = bid >> 4;   // XCD = bid&7 -> b in {x, x+8}: p1t L2-hot
  int m0 = mt * 64;
  const short* Ap = attn_bf + (size_t)b * kNP * kNP;
  const short* Bp = p1t + (size_t)b * 384 * kNP;

  int wm = (wv & 1) * 32, wn = (wv >> 1) * 96;
  f32x4 acc[2][6] = {};

  int ciA = tid & 255;
  int swzkoA = (((ciA & 3) ^ ((ciA >> 3) & 3)) * 8);
  int swzko  = (((tid & 3) ^ ((tid >> 3) & 3)) * 8);
  const short* gA  = Ap + (size_t)(m0 + (ciA >> 2)) * kNP + swzkoA;
  const short* gB0 = Bp + (size_t)(tid >> 2) * kNP + swzko;
  const short* gB1 = Bp + (size_t)((512 + tid) >> 2) * kNP + swzko;
  const short* gB2 = Bp + (size_t)((1024 + tid) >> 2) * kNP + swzko;

  auto STAGE = [&](int tt) {
    char* buf = dls + (size_t)(tt & 3) * 28672;
    int k0 = tt * 32;
    GLOAD_LDS16(gA + k0,  buf + (wv & 3) * 1024);
    GLOAD_LDS16(gB0 + k0, buf + 4096 + wv * 1024);
    GLOAD_LDS16(gB1 + k0, buf + 12288 + wv * 1024);
    GLOAD_LDS16(gB2 + k0, buf + 20480 + wv * 1024);
  };

  int cswz = (((lane >> 4) ^ ((lane >> 1) & 3)) * 16);

  STAGE(0); STAGE(1); STAGE(2);
  for (int t = 0; t < NT; t++) {
    if (t < NT - 2)       asm volatile("s_waitcnt vmcnt(8)" ::: "memory");
    else if (t == NT - 2) asm volatile("s_waitcnt vmcnt(4)" ::: "memory");
    else                  asm volatile("s_waitcnt vmcnt(0)" ::: "memory");
    __builtin_amdgcn_s_barrier();
    __builtin_amdgcn_sched_barrier(0);
    if (t + 3 < NT) STAGE(t + 3);
    const char* bufA = dls + (size_t)(t & 3) * 28672;
    const char* bufB = bufA + 4096;
    bf16x8 af[2], bg[6];
#pragma unroll
    for (int i = 0; i < 2; i++)
      af[i] = *(const bf16x8*)(bufA + (wm + i * 16 + (lane & 15)) * 64 + cswz);
#pragma unroll
    for (int j = 0; j < 6; j++)
      bg[j] = *(const bf16x8*)(bufB + (wn + j * 16 + (lane & 15)) * 64 + cswz);
    __builtin_amdgcn_s_setprio(1);
#pragma unroll
    for (int i = 0; i < 2; i++)
#pragma unroll
      for (int j = 0; j < 6; j++)
        acc[i][j] = __builtin_amdgcn_mfma_f32_16x16x32_bf16(af[i], bg[j], acc[i][j], 0, 0, 0);
    __builtin_amdgcn_s_setprio(0);
  }

#pragma unroll
  for (int i = 0; i < 2; i++) {
#pragma unroll
    for (int j = 0; j < 6; j++) {
#pragma unroll
      for (int r = 0; r < 4; r++) {
        int n = m0 + wm + i * 16 + (lane >> 4) * 4 + r;   // 0..1023
        int col = wn + j * 16 + (lane & 15);              // 0..383
        if (n < kN) {
          size_t row = (size_t)b * kN + n;
          float v = acc[i][j][r] + bf2f(p2[row * 384 + col]);
          if (col < 3 * kS) {
            float tv = v + reg_b[col];
            if (col >= 2 * kS) tv = 1.0f / (1.0f + __expf(-tv));
            rp[row * kRP + 5 + col] = anchors[(size_t)n * kRP + 5 + col] + tv;
          } else if (col < 3 * kS + kNC) {
            rp[row * kRP + (col - 3 * kS)] = v + cls_b[col - 3 * kS];
          }
        }
      }
    }
  }
}

extern "C" void kernel_launch(void* const* d_in, const int* in_sizes, int n_in,
                              void* d_out, int out_size, void* d_ws, size_t ws_size,
                              hipStream_t stream) {
  const float* bf      = (const float*)d_in[0];
  const float* conv_w  = (const float*)d_in[1];
  const float* conv_b  = (const float*)d_in[2];
  const int*   cut     = (const int*)d_in[3];
  const void*  mask    = d_in[4];
  const float* anchors = (const float*)d_in[5];
  const float* attn_w  = (const float*)d_in[6];
  const float* attn_b  = (const float*)d_in[7];
  const float* cls_w   = (const float*)d_in[8];
  const float* cls_b   = (const float*)d_in[9];
  const float* reg_w   = (const float*)d_in[10];
  const float* reg_b   = (const float*)d_in[11];

  float* out    = (float*)d_out;
  float* rp     = out + OFF_RP;
  float* attn_o = out + OFF_ATTN;
  float* feats  = out + OFF_FEAT;

  char*  ws      = (char*)d_ws;
  short* baf     = (short*)(ws + WB_BAF);
  short* wcomb   = (short*)(ws + WB_WCOMB);
  short* attn_bf = (short*)(ws + WB_ATTNB);
  short* scores  = (short*)(ws + WB_SCORE);
  short* p1t     = (short*)(ws + WB_P1T);
  short* p2      = (short*)(ws + WB_P2);
  int*   flag    = (int*)(ws + WB_FLAG);

  k_detect<<<1, 256, 0, stream>>>((const unsigned char*)mask, flag);
  k_conv<<<(kB * kHW / 4 + 255) / 256, 256, 0, stream>>>(bf, conv_w, conv_b, feats);
  k_gather<<<kB * kH, 256, 0, stream>>>(feats, cut, mask, flag, baf);
  k_cvt_wcomb<<<kNP + 384, 256, 0, stream>>>(attn_w, reg_w, cls_w, wcomb);
  // merged GEMM: 448 blocks (8 XCD x 8 m x 7 n; m fastest within XCD stripe)
  k_mgemm<<<448, 512, 131072, stream>>>(baf, wcomb, attn_b, scores, p1t, p2);
  k_softmax<<<kM, 256, 0, stream>>>(scores, anchors, attn_o, attn_bf, rp);
  // F-GEMM: 256 blocks (16 batches x 16 m-tiles), fused head epilogue
  k_fgemm<<<256, 512, 114688, stream>>>(attn_bf, p1t, p2, reg_b, cls_b,
                                        anchors, rp);
}